// Round 12
// baseline (542.026 us; speedup 1.0000x reference)
//
#include <hip/hip_runtime.h>

#define N_ATOMS  80000
#define N_BLOCKS 16000
#define N_EDGES  320000
#define N_GRAPHS 128
#define HS       128

typedef unsigned short ushortT;
typedef __attribute__((ext_vector_type(8))) __bf16 bf16x8;
typedef __attribute__((ext_vector_type(8))) unsigned short ushort8;
typedef __attribute__((ext_vector_type(4))) float f32x4;

__device__ __forceinline__ unsigned short f2bf(float f){
  unsigned int u = __builtin_bit_cast(unsigned int, f);
  u = (u + 0x7FFFu + ((u >> 16) & 1u)) >> 16;
  return (unsigned short)u;
}
__device__ __forceinline__ ushortT f2bff(float f){
  __bf16 b = (__bf16)f;
  return __builtin_bit_cast(ushortT, b);
}
__device__ __forceinline__ float bf2f(ushortT u){
  unsigned int v = ((unsigned int)u) << 16;
  return __builtin_bit_cast(float, v);
}
__device__ __forceinline__ bf16x8 load8bf(const ushortT* p){
  uint4 u = *reinterpret_cast<const uint4*>(p);
  return __builtin_bit_cast(bf16x8, u);
}
__device__ __forceinline__ bf16x8 load8f_bf(const float* p){
  float4 a = *reinterpret_cast<const float4*>(p);
  float4 b = *reinterpret_cast<const float4*>(p + 4);
  ushort8 u = { f2bff(a.x), f2bff(a.y), f2bff(a.z), f2bff(a.w),
                f2bff(b.x), f2bff(b.y), f2bff(b.z), f2bff(b.w) };
  return __builtin_bit_cast(bf16x8, u);
}
// fast silu: v * rcp(1+exp(-v))
__device__ __forceinline__ float silu(float v){
  return v * __builtin_amdgcn_rcpf(1.f + __expf(-v));
}

// pi-permutation: C-fragment register (n,r) of lane-group lg holds natural col
// c = 16n + lg*4 + r; B-fragment position p = ks*32 + lg*8 + j, n = 2ks + (j>>2), r = j&3.
__device__ __forceinline__ int c_of_p(int p){
  int ks = p >> 5, lg = (p >> 3) & 3, j = p & 7;
  return 16 * (ks * 2 + (j >> 2)) + lg * 4 + (j & 3);
}

// ---- merged prep: all weight transposes + bias perm + hist zero
struct PrepParams {
  const float* ew1; const float* ew2; const float* cw1;
  const float* nw1; const float* nw2; const float* ei; const float* eo;
  const float* eb1;
  ushortT* W1atp; ushortT* W1btp; ushortT* W1ct; ushortT* W2tp; ushortT* CW1tp;
  ushortT* NW1t; ushortT* NW2t; ushortT* Eint; ushortT* Eoutt;
  float* b1p; int* hist;
};

__device__ __forceinline__ void tcvt(int idx, const float* __restrict__ src,
                                     ushortT* __restrict__ dst,
                                     int srcK, int row_off, int K, int N, int Kpad,
                                     int pn, int pk){
  int k = idx % Kpad;
  int rem = idx / Kpad;
  int n = rem % N;
  int l = rem / N;
  float v = 0.f;
  if (k < K){
    int kk = pk ? c_of_p(k) : k;
    int nn = pn ? c_of_p(n) : n;
    v = src[((size_t)l * srcK + row_off + kk) * N + nn];
  }
  dst[idx] = f2bf(v);
}

#define PREP_TOTAL (49152*5 + 12288 + 98304 + 16384*2 + 16000 + 384)

__global__ void prep_kernel(PrepParams P){
  int idx = blockIdx.x * 256 + threadIdx.x;
  if (idx < 49152){ tcvt(idx, P.ew1, P.W1atp, 273,   0, 128, 128, 128, 1, 0); return; }
  idx -= 49152;
  if (idx < 49152){ tcvt(idx, P.ew1, P.W1btp, 273, 128, 128, 128, 128, 1, 0); return; }
  idx -= 49152;
  if (idx < 12288){ tcvt(idx, P.ew1, P.W1ct,  273, 256,  17, 128,  32, 0, 0); return; }
  idx -= 12288;
  if (idx < 49152){ tcvt(idx, P.ew2, P.W2tp,  128,   0, 128, 128, 128, 0, 1); return; }
  idx -= 49152;
  if (idx < 49152){ tcvt(idx, P.cw1, P.CW1tp, 128,   0, 128, 128, 128, 0, 1); return; }
  idx -= 49152;
  if (idx < 98304){ tcvt(idx, P.nw1, P.NW1t,  256,   0, 256, 128, 256, 0, 0); return; }
  idx -= 98304;
  if (idx < 49152){ tcvt(idx, P.nw2, P.NW2t,  128,   0, 128, 128, 128, 0, 0); return; }
  idx -= 49152;
  if (idx < 16384){ tcvt(idx, P.ei,  P.Eint,  128,   0, 128, 128, 128, 0, 0); return; }
  idx -= 16384;
  if (idx < 16384){ tcvt(idx, P.eo,  P.Eoutt, 128,   0, 128, 128, 128, 0, 0); return; }
  idx -= 16384;
  if (idx < 16000){ P.hist[idx] = 0; return; }
  idx -= 16000;
  if (idx < 384){ int l = idx >> 7, p = idx & 127; P.b1p[idx] = P.eb1[l * 128 + c_of_p(p)]; }
}

// ---- hist + block_start merged
__global__ void hist_bstart_kernel(const int* __restrict__ edges, int* __restrict__ hist,
                                   const int* __restrict__ bid, int* __restrict__ bstart){
  int b = blockIdx.x;
  if (b < N_EDGES / 256){
    int e = b * 256 + threadIdx.x;
    atomicAdd(&hist[edges[e]], 1);
  } else {
    int i = (b - N_EDGES / 256) * 256 + threadIdx.x;
    if (i <= N_BLOCKS){
      int lo = 0, hi = N_ATOMS;
      while (lo < hi){ int mid = (lo + hi) >> 1; if (bid[mid] < i) lo = mid + 1; else hi = mid; }
      bstart[i] = lo;
    }
  }
}

__global__ __launch_bounds__(1024) void scan_kernel(const int* __restrict__ hist,
                                                    int* __restrict__ estart,
                                                    int* __restrict__ ecur){
  __shared__ int ps[1024];
  int t = threadIdx.x;
  const int chunk = (N_BLOCKS + 1023) / 1024;
  int lo = t * chunk, hi = lo + chunk;
  if (hi > N_BLOCKS) hi = N_BLOCKS;
  if (lo > N_BLOCKS) lo = N_BLOCKS;
  int s = 0;
  for (int i = lo; i < hi; i++) s += hist[i];
  ps[t] = s;
  __syncthreads();
  for (int off = 1; off < 1024; off <<= 1){
    int v = (t >= off) ? ps[t - off] : 0;
    __syncthreads();
    ps[t] += v;
    __syncthreads();
  }
  int base = (t == 0) ? 0 : ps[t - 1];
  for (int i = lo; i < hi; i++){ estart[i] = base; ecur[i] = base; base += hist[i]; }
  if (t == 1023) estart[N_BLOCKS] = base;
}

// scatter into sorted order; sattr padded: 32 u16/edge = [0, attr0..15, 0 x15]
__global__ void scatter_kernel(const int* __restrict__ edges, const float* __restrict__ attr,
                               int* __restrict__ ecur,
                               int* __restrict__ srow, int* __restrict__ scol,
                               ushortT* __restrict__ sattr){
  int e = blockIdx.x * 256 + threadIdx.x;
  if (e >= N_EDGES) return;
  int r = edges[e], c = edges[N_EDGES + e];
  int p = atomicAdd(&ecur[r], 1);
  srow[p] = r; scol[p] = c;
  ushortT buf[32];
  buf[0] = 0;
#pragma unroll
  for (int k = 0; k < 16; k++) buf[k + 1] = f2bf(attr[(size_t)e * 16 + k]);
#pragma unroll
  for (int k = 17; k < 32; k++) buf[k] = 0;
#pragma unroll
  for (int k = 0; k < 16; k++)
    reinterpret_cast<uint*>(sattr + (size_t)p * 32)[k] = reinterpret_cast<uint*>(buf)[k];
}

__global__ void pool_kernel(const float* __restrict__ H, const float* __restrict__ Z,
                            const int* __restrict__ start,
                            float* __restrict__ Hm, float* __restrict__ x,
                            float* __restrict__ gsum){
  int b = blockIdx.x;
  int t = threadIdx.x;            // 128 threads
  if (b < 128) gsum[b * 128 + t] = 0.f;
  int s = start[b], e = start[b + 1];
  float inv = 1.f / (float)((e - s) > 0 ? (e - s) : 1);
  float sum = 0.f;
  for (int a = s; a < e; a++) sum += H[(size_t)a * HS + t];
  Hm[(size_t)b * HS + t] = sum * inv;
  if (t < 3){
    float sz = 0.f;
    for (int a = s; a < e; a++) sz += Z[a * 3 + t];
    x[b * 3 + t] = sz * inv;
  }
}

// ---- fused emb_in GEMM + layer-0 P/Q + zero agg/xacc slices (1-wave blocks, 1000)
__global__ __launch_bounds__(64) void gemm_pq_kernel(
    const float* __restrict__ A,
    const ushortT* __restrict__ Wt, const float* __restrict__ bias,
    float* __restrict__ Cf,
    const ushortT* __restrict__ Wa, const ushortT* __restrict__ Wb,
    const float* __restrict__ b1p,
    ushortT* __restrict__ Pbf, ushortT* __restrict__ Qbf,
    float* __restrict__ agg, float* __restrict__ xacc){
  __shared__ __align__(16) ushortT T1[2048];
  int lane = threadIdx.x;
  int l15 = lane & 15, lg = lane >> 4;
  int base = blockIdx.x * 16;
  int row = base + l15;
  {
    float4 z4 = {0.f, 0.f, 0.f, 0.f};
    float4* aggp = reinterpret_cast<float4*>(agg + (size_t)blockIdx.x * 16 * HS);
#pragma unroll
    for (int i = 0; i < 8; i++) aggp[lane + 64 * i] = z4;
    if (lane < 48) xacc[blockIdx.x * 48 + lane] = 0.f;
  }
  f32x4 zero = {0.f, 0.f, 0.f, 0.f};
  f32x4 acc[8];
#pragma unroll
  for (int n = 0; n < 8; n++) acc[n] = zero;
#pragma unroll
  for (int ks = 0; ks < 4; ks++){
    int k0 = ks * 32 + lg * 8;
    bf16x8 af = load8f_bf(A + (size_t)row * HS + k0);
#pragma unroll
    for (int n = 0; n < 8; n++){
      bf16x8 bf = load8bf(Wt + (size_t)(16 * n + l15) * HS + k0);
      acc[n] = __builtin_amdgcn_mfma_f32_16x16x32_bf16(af, bf, acc[n], 0, 0, 0);
    }
  }
#pragma unroll
  for (int n = 0; n < 8; n++){
    int col = 16 * n + l15;
    float bv = bias[col];
#pragma unroll
    for (int r = 0; r < 4; r++){
      int ro = base + lg * 4 + r;
      int er = lg * 4 + r;
      float hv = acc[n][r] + bv;
      Cf[(size_t)ro * HS + col] = hv;
      T1[(er * 128 + col) ^ ((er & 7) << 3)] = f2bff(hv);
    }
  }
  f32x4 accp[8], accq[8];
#pragma unroll
  for (int n = 0; n < 8; n++){ accp[n] = zero; accq[n] = zero; }
#pragma unroll
  for (int ks = 0; ks < 4; ks++){
    int k0 = ks * 32 + lg * 8;
    bf16x8 af = load8bf(&T1[(l15 * 128 + k0) ^ ((l15 & 7) << 3)]);
#pragma unroll
    for (int n = 0; n < 8; n++){
      accp[n] = __builtin_amdgcn_mfma_f32_16x16x32_bf16(af, load8bf(Wa + (size_t)(16 * n + l15) * HS + k0), accp[n], 0, 0, 0);
      accq[n] = __builtin_amdgcn_mfma_f32_16x16x32_bf16(af, load8bf(Wb + (size_t)(16 * n + l15) * HS + k0), accq[n], 0, 0, 0);
    }
  }
#pragma unroll
  for (int n = 0; n < 8; n++){
    int col = 16 * n + l15;
    float bv = b1p[col];
#pragma unroll
    for (int r = 0; r < 4; r++){
      int ro = base + lg * 4 + r;
      Pbf[(size_t)ro * HS + col] = f2bff(accp[n][r] + bv);
      Qbf[(size_t)ro * HS + col] = f2bff(accq[n][r]);
    }
  }
}

// ---- fused node MLP + x_update + zero-next + next-layer P/Q (1-wave blocks, 1000)
__global__ __launch_bounds__(64) void node_pq_kernel(
    float* __restrict__ h, float* __restrict__ agg,
    const ushortT* __restrict__ W1t, const ushortT* __restrict__ W2t,
    const float* __restrict__ b1, const float* __restrict__ b2,
    const ushortT* __restrict__ Wa, const ushortT* __restrict__ Wb,
    const float* __restrict__ b1p,
    ushortT* __restrict__ Pbf, ushortT* __restrict__ Qbf,
    float* __restrict__ x, float* __restrict__ xacc, const int* __restrict__ estart){
  __shared__ __align__(16) ushortT T1[2048];
  int lane = threadIdx.x;
  int l15 = lane & 15, lg = lane >> 4;
  int base = blockIdx.x * 16;
  int row = base + l15;
  f32x4 zero = {0.f, 0.f, 0.f, 0.f};

  if (lane < 48){
    int i = blockIdx.x * 48 + lane;
    int b = i / 3;
    int cnt = estart[b + 1] - estart[b];
    x[i] += xacc[i] / (float)(cnt > 0 ? cnt : 1);
    xacc[i] = 0.f;
  }

  f32x4 acc[8];
#pragma unroll
  for (int n = 0; n < 8; n++) acc[n] = zero;
#pragma unroll
  for (int ks = 0; ks < 8; ks++){
    int k0 = ks * 32 + lg * 8;
    bf16x8 af = (k0 < 128) ? load8f_bf(h + (size_t)row * HS + k0)
                           : load8f_bf(agg + (size_t)row * HS + (k0 - 128));
#pragma unroll
    for (int n = 0; n < 8; n++){
      acc[n] = __builtin_amdgcn_mfma_f32_16x16x32_bf16(af, load8bf(W1t + (size_t)(16 * n + l15) * 256 + k0), acc[n], 0, 0, 0);
    }
  }
  // drain agg reads then zero this block's agg slice
  __syncthreads();
  {
    float4 z4 = {0.f, 0.f, 0.f, 0.f};
    float4* aggp = reinterpret_cast<float4*>(agg + (size_t)blockIdx.x * 16 * HS);
#pragma unroll
    for (int i = 0; i < 8; i++) aggp[lane + 64 * i] = z4;
  }
#pragma unroll
  for (int n = 0; n < 8; n++){
    int col = 16 * n + l15;
    float bv = b1[col];
#pragma unroll
    for (int r = 0; r < 4; r++){
      int er = lg * 4 + r;
      T1[(er * 128 + col) ^ ((er & 7) << 3)] = f2bff(silu(acc[n][r] + bv));
    }
  }
#pragma unroll
  for (int n = 0; n < 8; n++) acc[n] = zero;
#pragma unroll
  for (int ks = 0; ks < 4; ks++){
    int k0 = ks * 32 + lg * 8;
    bf16x8 af = load8bf(&T1[(l15 * 128 + k0) ^ ((l15 & 7) << 3)]);
#pragma unroll
    for (int n = 0; n < 8; n++){
      acc[n] = __builtin_amdgcn_mfma_f32_16x16x32_bf16(af, load8bf(W2t + (size_t)(16 * n + l15) * HS + k0), acc[n], 0, 0, 0);
    }
  }
#pragma unroll
  for (int n = 0; n < 8; n++){
    int col = 16 * n + l15;
    float bv = b2[col];
#pragma unroll
    for (int r = 0; r < 4; r++){
      int ro = base + lg * 4 + r;
      int er = lg * 4 + r;
      float hv = h[(size_t)ro * HS + col] + acc[n][r] + bv;
      h[(size_t)ro * HS + col] = hv;
      T1[(er * 128 + col) ^ ((er & 7) << 3)] = f2bff(hv);
    }
  }
  // next-layer P/Q from T1
  f32x4 accp[8], accq[8];
#pragma unroll
  for (int n = 0; n < 8; n++){ accp[n] = zero; accq[n] = zero; }
#pragma unroll
  for (int ks = 0; ks < 4; ks++){
    int k0 = ks * 32 + lg * 8;
    bf16x8 af = load8bf(&T1[(l15 * 128 + k0) ^ ((l15 & 7) << 3)]);
#pragma unroll
    for (int n = 0; n < 8; n++){
      accp[n] = __builtin_amdgcn_mfma_f32_16x16x32_bf16(af, load8bf(Wa + (size_t)(16 * n + l15) * HS + k0), accp[n], 0, 0, 0);
      accq[n] = __builtin_amdgcn_mfma_f32_16x16x32_bf16(af, load8bf(Wb + (size_t)(16 * n + l15) * HS + k0), accq[n], 0, 0, 0);
    }
  }
#pragma unroll
  for (int n = 0; n < 8; n++){
    int col = 16 * n + l15;
    float bv = b1p[col];
#pragma unroll
    for (int r = 0; r < 4; r++){
      int ro = base + lg * 4 + r;
      Pbf[(size_t)ro * HS + col] = f2bff(accp[n][r] + bv);
      Qbf[(size_t)ro * HS + col] = f2bff(accq[n][r]);
    }
  }
}

// ---- fused final node MLP + emb_out GEMM + normalize + graph accumulate (1-wave, 1000)
__global__ __launch_bounds__(64) void node_emb_kernel(
    const float* __restrict__ h, const float* __restrict__ agg,
    const ushortT* __restrict__ W1t, const ushortT* __restrict__ W2t,
    const float* __restrict__ b1, const float* __restrict__ b2,
    const ushortT* __restrict__ Eoutt, const float* __restrict__ eob,
    const int* __restrict__ batch_id,
    float* __restrict__ brep, float* __restrict__ gsum){
  __shared__ __align__(16) ushortT T1[2048];
  int lane = threadIdx.x;
  int l15 = lane & 15, lg = lane >> 4;
  int base = blockIdx.x * 16;
  int row = base + l15;
  f32x4 zero = {0.f, 0.f, 0.f, 0.f};

  f32x4 acc[8];
#pragma unroll
  for (int n = 0; n < 8; n++) acc[n] = zero;
#pragma unroll
  for (int ks = 0; ks < 8; ks++){
    int k0 = ks * 32 + lg * 8;
    bf16x8 af = (k0 < 128) ? load8f_bf(h + (size_t)row * HS + k0)
                           : load8f_bf(agg + (size_t)row * HS + (k0 - 128));
#pragma unroll
    for (int n = 0; n < 8; n++){
      acc[n] = __builtin_amdgcn_mfma_f32_16x16x32_bf16(af, load8bf(W1t + (size_t)(16 * n + l15) * 256 + k0), acc[n], 0, 0, 0);
    }
  }
#pragma unroll
  for (int n = 0; n < 8; n++){
    int col = 16 * n + l15;
    float bv = b1[col];
#pragma unroll
    for (int r = 0; r < 4; r++){
      int er = lg * 4 + r;
      T1[(er * 128 + col) ^ ((er & 7) << 3)] = f2bff(silu(acc[n][r] + bv));
    }
  }
#pragma unroll
  for (int n = 0; n < 8; n++) acc[n] = zero;
#pragma unroll
  for (int ks = 0; ks < 4; ks++){
    int k0 = ks * 32 + lg * 8;
    bf16x8 af = load8bf(&T1[(l15 * 128 + k0) ^ ((l15 & 7) << 3)]);
#pragma unroll
    for (int n = 0; n < 8; n++){
      acc[n] = __builtin_amdgcn_mfma_f32_16x16x32_bf16(af, load8bf(W2t + (size_t)(16 * n + l15) * HS + k0), acc[n], 0, 0, 0);
    }
  }
  // h_final = h + acc + b2 -> T1 (bf16)
#pragma unroll
  for (int n = 0; n < 8; n++){
    int col = 16 * n + l15;
    float bv = b2[col];
#pragma unroll
    for (int r = 0; r < 4; r++){
      int ro = base + lg * 4 + r;
      int er = lg * 4 + r;
      float hv = h[(size_t)ro * HS + col] + acc[n][r] + bv;
      T1[(er * 128 + col) ^ ((er & 7) << 3)] = f2bff(hv);
    }
  }
  // emb_out GEMM from T1
#pragma unroll
  for (int n = 0; n < 8; n++) acc[n] = zero;
#pragma unroll
  for (int ks = 0; ks < 4; ks++){
    int k0 = ks * 32 + lg * 8;
    bf16x8 af = load8bf(&T1[(l15 * 128 + k0) ^ ((l15 & 7) << 3)]);
#pragma unroll
    for (int n = 0; n < 8; n++){
      acc[n] = __builtin_amdgcn_mfma_f32_16x16x32_bf16(af, load8bf(Eoutt + (size_t)(16 * n + l15) * HS + k0), acc[n], 0, 0, 0);
    }
  }
#pragma unroll
  for (int n = 0; n < 8; n++){
    float bv = eob[16 * n + l15];
#pragma unroll
    for (int r = 0; r < 4; r++) acc[n][r] += bv;
  }
  float scl[4];
#pragma unroll
  for (int r = 0; r < 4; r++){
    float ss = 0.f;
#pragma unroll
    for (int n = 0; n < 8; n++) ss += acc[n][r] * acc[n][r];
#pragma unroll
    for (int o = 1; o < 16; o <<= 1) ss += __shfl_xor(ss, o, 64);
    scl[r] = 1.f / fmaxf(sqrtf(ss), 1e-12f);
  }
#pragma unroll
  for (int r = 0; r < 4; r++){
    int ro = base + lg * 4 + r;
    int g = batch_id[ro];
#pragma unroll
    for (int n = 0; n < 8; n++){
      int col = 16 * n + l15;
      float v = acc[n][r] * scl[r];
      brep[(size_t)ro * HS + col] = v;
      atomicAdd(&gsum[g * HS + col], v);
    }
  }
}

// ---- fused edge kernel v9: 128 edges/WG as 2 sequential 64-edge tiles.
// W2 and CW1 fragments loaded in tile 0, reused from REGISTERS in tile 1.
// Agg-flush accumulator carried across the tile boundary (rows sorted).
template<int COORD>
__global__ __launch_bounds__(256, 3) void edge_kernel(
    const int* __restrict__ srow, const int* __restrict__ scol,
    const ushortT* __restrict__ sattr,
    const float* __restrict__ x,
    const ushortT* __restrict__ Pbf, const ushortT* __restrict__ Qbf,
    const ushortT* __restrict__ W1ct, const ushortT* __restrict__ W2tp,
    const ushortT* __restrict__ CW1tp,
    const float* __restrict__ b2, const float* __restrict__ cb1,
    const float* __restrict__ cw3,
    float* __restrict__ xacc, float* __restrict__ agg){
  __shared__ float bias_l[3][128];
  __shared__ int   rid_s[64];
  __shared__ float dif_s[COORD ? 64 : 1][3];
  __shared__ float wall[COORD ? 4 : 1][COORD ? 64 : 1];
  __shared__ __align__(16) ushortT S1[64 * 128];   // m1, pi-order, swizzled
  __shared__ __align__(16) ushortT S2[64 * 128];   // m,  pi-order, swizzled

  const int t = threadIdx.x;
  const int lane = t & 63;
  const int wv = t >> 6;
  const int l15 = lane & 15, lg = lane >> 4;
  const f32x4 zero = {0.f, 0.f, 0.f, 0.f};

  if (t < 128){
    bias_l[0][t] = b2[t];
    if (COORD){ bias_l[1][t] = cb1[t]; bias_l[2][t] = cw3[t]; }
  }

  bf16x8 wf2[4][2];                  // W2 B-fragments (loaded tile 0, reused tile 1)
  bf16x8 cwf[4][2];                  // CW1 B-fragments (COORD)
  const int c0 = c_of_p(2 * lane), c1 = c_of_p(2 * lane + 1);
  float run0 = 0.f, run1 = 0.f;
  int prev = -1;

  const int erow = wv * 16 + l15;

#pragma unroll
  for (int tile = 0; tile < 2; tile++){
    // ---------- phase A: m1 for this wave's 16 edges ----------
    const int e = blockIdx.x * 128 + tile * 64 + erow;
    const int r = srow[e], c = scol[e];
    const float dx = x[r * 3 + 0] - x[c * 3 + 0];
    const float dy = x[r * 3 + 1] - x[c * 3 + 1];
    const float dz = x[r * 3 + 2] - x[c * 3 + 2];
    const float rad = dx * dx + dy * dy + dz * dz;
    ushort8 at8 = __builtin_bit_cast(ushort8, load8bf(sattr + (size_t)e * 32 + lg * 8));
    if (lg == 0) at8[0] = f2bff(rad);
    const bf16x8 atb = __builtin_bit_cast(bf16x8, at8);

#pragma unroll
    for (int ks = 0; ks < 4; ks++){
      f32x4 a0 = __builtin_amdgcn_mfma_f32_16x16x32_bf16(
          load8bf(W1ct + (size_t)(16 * (2 * ks)     + l15) * 32 + lg * 8), atb, zero, 0, 0, 0);
      f32x4 a1 = __builtin_amdgcn_mfma_f32_16x16x32_bf16(
          load8bf(W1ct + (size_t)(16 * (2 * ks + 1) + l15) * 32 + lg * 8), atb, zero, 0, 0, 0);
      ushort8 pv = __builtin_bit_cast(ushort8, load8bf(Pbf + (size_t)r * HS + ks * 32 + lg * 8));
      ushort8 qv = __builtin_bit_cast(ushort8, load8bf(Qbf + (size_t)c * HS + ks * 32 + lg * 8));
      ushort8 af;
#pragma unroll
      for (int j = 0; j < 4; j++)
        af[j] = f2bff(silu(a0[j] + bf2f(pv[j]) + bf2f(qv[j])));
#pragma unroll
      for (int j = 4; j < 8; j++)
        af[j] = f2bff(silu(a1[j - 4] + bf2f(pv[j]) + bf2f(qv[j])));
      int byte = (erow * 256 + ks * 64 + lg * 16) ^ ((erow & 7) << 4);
      *reinterpret_cast<uint4*>(reinterpret_cast<char*>(S1) + byte) = __builtin_bit_cast(uint4, af);
    }
    __syncthreads();   // bar1: S1 ready; prior tile's flush/scatter complete

    // rid/dif writes AFTER bar1 (readers are post-bar2/bar3 of this tile)
    if (lg == 0){
      rid_s[erow] = r;
      if (COORD){ dif_s[erow][0] = dx; dif_s[erow][1] = dy; dif_s[erow][2] = dz; }
    }

    // ---------- phase B: GEMM2 chan-split (groups 2wv, 2wv+1; all 64 edges) ----------
    f32x4 acc2[4][2];
#pragma unroll
    for (int et = 0; et < 4; et++){ acc2[et][0] = zero; acc2[et][1] = zero; }
#pragma unroll
    for (int ks = 0; ks < 4; ks++){
      if (tile == 0){
        wf2[ks][0] = load8bf(W2tp + (size_t)(16 * (2 * wv)     + l15) * HS + ks * 32 + lg * 8);
        wf2[ks][1] = load8bf(W2tp + (size_t)(16 * (2 * wv + 1) + l15) * HS + ks * 32 + lg * 8);
      }
#pragma unroll
      for (int et = 0; et < 4; et++){
        int row2 = et * 16 + l15;
        int byte = (row2 * 256 + ks * 64 + lg * 16) ^ ((row2 & 7) << 4);
        bf16x8 mb = __builtin_bit_cast(bf16x8,
            *reinterpret_cast<const uint4*>(reinterpret_cast<const char*>(S1) + byte));
        acc2[et][0] = __builtin_amdgcn_mfma_f32_16x16x32_bf16(wf2[ks][0], mb, acc2[et][0], 0, 0, 0);
        acc2[et][1] = __builtin_amdgcn_mfma_f32_16x16x32_bf16(wf2[ks][1], mb, acc2[et][1], 0, 0, 0);
      }
    }
    // m-epilogue: silu + b2 -> mreg + single b128 S2 write
    ushort8 mreg[4];
#pragma unroll
    for (int et = 0; et < 4; et++){
      ushort8 mq;
#pragma unroll
      for (int g = 0; g < 2; g++){
        float4 bv = *reinterpret_cast<const float4*>(&bias_l[0][16 * (2 * wv + g) + lg * 4]);
#pragma unroll
        for (int rr = 0; rr < 4; rr++)
          mq[g * 4 + rr] = f2bff(silu(acc2[et][g][rr] + (&bv.x)[rr]));
      }
      mreg[et] = mq;
      int row2 = et * 16 + l15;
      int byte = (row2 * 256 + wv * 64 + lg * 16) ^ ((row2 & 7) << 4);
      *reinterpret_cast<uint4*>(reinterpret_cast<char*>(S2) + byte) = __builtin_bit_cast(uint4, mq);
    }
    __syncthreads();   // bar2: S2 + rid/dif ready

    if (COORD){
      // ---------- phase C: coord GEMM chan-split (own ks slice from registers) ----------
      f32x4 acc3[4][2];
#pragma unroll
      for (int et = 0; et < 4; et++){ acc3[et][0] = zero; acc3[et][1] = zero; }
#pragma unroll
      for (int ks = 0; ks < 4; ks++){
        if (tile == 0){
          cwf[ks][0] = load8bf(CW1tp + (size_t)(16 * (2 * wv)     + l15) * HS + ks * 32 + lg * 8);
          cwf[ks][1] = load8bf(CW1tp + (size_t)(16 * (2 * wv + 1) + l15) * HS + ks * 32 + lg * 8);
        }
#pragma unroll
        for (int et = 0; et < 4; et++){
          bf16x8 mb;
          if (ks == wv){
            mb = __builtin_bit_cast(bf16x8, mreg[et]);
          } else {
            int row2 = et * 16 + l15;
            int byte = (row2 * 256 + ks * 64 + lg * 16) ^ ((row2 & 7) << 4);
            mb = __builtin_bit_cast(bf16x8,
                *reinterpret_cast<const uint4*>(reinterpret_cast<const char*>(S2) + byte));
          }
          acc3[et][0] = __builtin_amdgcn_mfma_f32_16x16x32_bf16(cwf[ks][0], mb, acc3[et][0], 0, 0, 0);
          acc3[et][1] = __builtin_amdgcn_mfma_f32_16x16x32_bf16(cwf[ks][1], mb, acc3[et][1], 0, 0, 0);
        }
      }
      // per-wave partial w -> wall
#pragma unroll
      for (int et = 0; et < 4; et++){
        float ws = 0.f;
#pragma unroll
        for (int g = 0; g < 2; g++){
          int n = 2 * wv + g;
          float4 cbv = *reinterpret_cast<const float4*>(&bias_l[1][16 * n + lg * 4]);
          float4 cwv = *reinterpret_cast<const float4*>(&bias_l[2][16 * n + lg * 4]);
#pragma unroll
          for (int rr = 0; rr < 4; rr++)
            ws += silu(acc3[et][g][rr] + (&cbv.x)[rr]) * (&cwv.x)[rr];
        }
        ws += __shfl_xor(ws, 16, 64);
        ws += __shfl_xor(ws, 32, 64);
        if (lg == 0) wall[wv][et * 16 + l15] = ws;
      }
    }

    // ---------- agg flush: this wave's own 16 edges, carry across tiles ----------
    {
#pragma unroll
      for (int e2 = 0; e2 < 16; e2++){
        int re = __builtin_amdgcn_readfirstlane(rid_s[wv * 16 + e2]);
        if (re != prev){
          if (prev >= 0){
            atomicAdd(&agg[(size_t)prev * HS + c0], run0);
            atomicAdd(&agg[(size_t)prev * HS + c1], run1);
          }
          run0 = 0.f; run1 = 0.f; prev = re;
        }
        int row2 = wv * 16 + e2;
        int byte = (row2 * 256 + lane * 4) ^ ((row2 & 7) << 4);
        uint u = *reinterpret_cast<const uint*>(reinterpret_cast<const char*>(S2) + byte);
        run0 += bf2f((ushortT)(u & 0xFFFF));
        run1 += bf2f((ushortT)(u >> 16));
      }
    }

    if (COORD){
      __syncthreads();   // bar3: wall complete
      if (t < 192){
        int e2 = t / 3, cd = t % 3;
        float w = wall[0][e2] + wall[1][e2] + wall[2][e2] + wall[3][e2];
        atomicAdd(&xacc[(size_t)rid_s[e2] * 3 + cd], dif_s[e2][cd] * w);
      }
    }
  }
  // final carried flush
  if (prev >= 0){
    atomicAdd(&agg[(size_t)prev * HS + c0], run0);
    atomicAdd(&agg[(size_t)prev * HS + c1], run1);
  }
}

__global__ void norm_graph_kernel(const float* __restrict__ gsum, float* __restrict__ grep){
  int wv = threadIdx.x >> 6, lane = threadIdx.x & 63;
  int g = blockIdx.x * 4 + wv;
  if (g >= N_GRAPHS) return;
  float v0 = gsum[g * HS + lane];
  float v1 = gsum[g * HS + 64 + lane];
  float ss = v0 * v0 + v1 * v1;
#pragma unroll
  for (int o = 1; o < 64; o <<= 1) ss += __shfl_xor(ss, o, 64);
  float s = 1.f / fmaxf(sqrtf(ss), 1e-12f);
  grep[(size_t)g * HS + lane] = v0 * s;
  grep[(size_t)g * HS + 64 + lane] = v1 * s;
}

extern "C" void kernel_launch(void* const* d_in, const int* in_sizes, int n_in,
                              void* d_out, int out_size, void* d_ws, size_t ws_size,
                              hipStream_t stream){
  const float* H         = (const float*)d_in[0];
  const float* Z         = (const float*)d_in[1];
  const int*   block_id  = (const int*)d_in[2];
  const int*   batch_id  = (const int*)d_in[3];
  const int*   edges     = (const int*)d_in[4];
  const float* edge_attr = (const float*)d_in[5];
  const float* emb_in_w  = (const float*)d_in[6];
  const float* emb_in_b  = (const float*)d_in[7];
  const float* emb_out_w = (const float*)d_in[8];
  const float* emb_out_b = (const float*)d_in[9];
  const float* edge_w1   = (const float*)d_in[10];
  const float* edge_b1   = (const float*)d_in[11];
  const float* edge_w2   = (const float*)d_in[12];
  const float* edge_b2   = (const float*)d_in[13];
  const float* node_w1   = (const float*)d_in[14];
  const float* node_b1   = (const float*)d_in[15];
  const float* node_w2   = (const float*)d_in[16];
  const float* node_b2   = (const float*)d_in[17];
  const float* coord_w1  = (const float*)d_in[18];
  const float* coord_b1  = (const float*)d_in[19];
  const float* coord_w3  = (const float*)d_in[20];

  float* out  = (float*)d_out;
  float* Hm   = out;                               // [16000 x 128]
  float* brep = out + (size_t)N_BLOCKS * HS;       // [16000 x 128]
  float* grep = out + (size_t)2 * N_BLOCKS * HS;   // [128 x 128]

  char* base = (char*)d_ws;
  size_t off = 0;
  auto take = [&](size_t bytes) -> char* {
    char* p = base + off;
    off += (bytes + 255) & ~(size_t)255;
    return p;
  };
  float*   x     = (float*)  take((size_t)N_BLOCKS * 3 * 4);
  float*   xacc  = (float*)  take((size_t)N_BLOCKS * 3 * 4);
  float*   h     = (float*)  take((size_t)N_BLOCKS * HS * 4);
  float*   agg   = (float*)  take((size_t)N_BLOCKS * HS * 4);
  float*   gsum  = (float*)  take((size_t)N_GRAPHS * HS * 4);
  int*     bstart= (int*)    take((size_t)(N_BLOCKS + 1) * 4);
  int*     hist  = (int*)    take((size_t)N_BLOCKS * 4);
  int*     estart= (int*)    take((size_t)(N_BLOCKS + 1) * 4);
  int*     ecur  = (int*)    take((size_t)N_BLOCKS * 4);
  int*     srow  = (int*)    take((size_t)N_EDGES * 4);
  int*     scol  = (int*)    take((size_t)N_EDGES * 4);
  ushortT* sattr = (ushortT*)take((size_t)N_EDGES * 32 * 2);
  ushortT* Pbf   = (ushortT*)take((size_t)N_BLOCKS * HS * 2);
  ushortT* Qbf   = (ushortT*)take((size_t)N_BLOCKS * HS * 2);
  ushortT* W1atp = (ushortT*)take((size_t)3 * 128 * 128 * 2);
  ushortT* W1btp = (ushortT*)take((size_t)3 * 128 * 128 * 2);
  ushortT* W1ct  = (ushortT*)take((size_t)3 * 128 * 32 * 2);
  ushortT* W2tp  = (ushortT*)take((size_t)3 * 128 * 128 * 2);
  ushortT* CW1tp = (ushortT*)take((size_t)3 * 128 * 128 * 2);
  ushortT* NW1t  = (ushortT*)take((size_t)3 * 128 * 256 * 2);
  ushortT* NW2t  = (ushortT*)take((size_t)3 * 128 * 128 * 2);
  ushortT* Eint  = (ushortT*)take((size_t)128 * 128 * 2);
  ushortT* Eoutt = (ushortT*)take((size_t)128 * 128 * 2);
  float*   b1p   = (float*)  take((size_t)3 * 128 * 4);

  // merged prep (weights + bias perm + hist zero)
  PrepParams P;
  P.ew1 = edge_w1; P.ew2 = edge_w2; P.cw1 = coord_w1;
  P.nw1 = node_w1; P.nw2 = node_w2; P.ei = emb_in_w; P.eo = emb_out_w;
  P.eb1 = edge_b1;
  P.W1atp = W1atp; P.W1btp = W1btp; P.W1ct = W1ct; P.W2tp = W2tp; P.CW1tp = CW1tp;
  P.NW1t = NW1t; P.NW2t = NW2t; P.Eint = Eint; P.Eoutt = Eoutt;
  P.b1p = b1p; P.hist = hist;
  prep_kernel<<<(PREP_TOTAL + 255) / 256, 256, 0, stream>>>(P);

  hist_bstart_kernel<<<N_EDGES / 256 + (N_BLOCKS + 1 + 255) / 256, 256, 0, stream>>>(
      edges, hist, block_id, bstart);
  scan_kernel<<<1, 1024, 0, stream>>>(hist, estart, ecur);
  scatter_kernel<<<N_EDGES / 256, 256, 0, stream>>>(edges, edge_attr, ecur, srow, scol, sattr);
  pool_kernel<<<N_BLOCKS, 128, 0, stream>>>(H, Z, bstart, Hm, x, gsum);

  // h = Hm @ emb_in_w + b ; P/Q layer 0 ; zero agg/xacc
  gemm_pq_kernel<<<N_BLOCKS / 16, 64, 0, stream>>>(Hm, Eint, emb_in_b, h,
                                                   W1atp, W1btp, b1p, Pbf, Qbf, agg, xacc);

  for (int l = 0; l < 3; l++){
    if (l < 2){
      edge_kernel<1><<<N_EDGES / 128, 256, 0, stream>>>(
          srow, scol, sattr, x, Pbf, Qbf,
          W1ct + (size_t)l * 128 * 32, W2tp + (size_t)l * 128 * 128, CW1tp + (size_t)l * 128 * 128,
          edge_b2 + l * 128, coord_b1 + l * 128, coord_w3 + l * 128,
          xacc, agg);
      node_pq_kernel<<<N_BLOCKS / 16, 64, 0, stream>>>(
          h, agg, NW1t + (size_t)l * 128 * 256, NW2t + (size_t)l * 128 * 128,
          node_b1 + l * 128, node_b2 + l * 128,
          W1atp + (size_t)(l + 1) * 128 * 128, W1btp + (size_t)(l + 1) * 128 * 128,
          b1p + (l + 1) * 128, Pbf, Qbf, x, xacc, estart);
    } else {
      edge_kernel<0><<<N_EDGES / 128, 256, 0, stream>>>(
          srow, scol, sattr, x, Pbf, Qbf,
          W1ct + (size_t)l * 128 * 32, W2tp + (size_t)l * 128 * 128, CW1tp + (size_t)l * 128 * 128,
          edge_b2 + l * 128, coord_b1 + l * 128, coord_w3 + l * 128,
          xacc, agg);
      node_emb_kernel<<<N_BLOCKS / 16, 64, 0, stream>>>(
          h, agg, NW1t + (size_t)l * 128 * 256, NW2t + (size_t)l * 128 * 128,
          node_b1 + l * 128, node_b2 + l * 128,
          Eoutt, emb_out_b, batch_id, brep, gsum);
    }
  }

  norm_graph_kernel<<<N_GRAPHS / 4, 256, 0, stream>>>(gsum, grep);
}

// Round 13
// 521.777 us; speedup vs baseline: 1.0388x; 1.0388x over previous
//
#include <hip/hip_runtime.h>

#define N_ATOMS  80000
#define N_BLOCKS 16000
#define N_EDGES  320000
#define N_GRAPHS 128
#define HS       128

typedef unsigned short ushortT;
typedef __attribute__((ext_vector_type(8))) __bf16 bf16x8;
typedef __attribute__((ext_vector_type(8))) unsigned short ushort8;
typedef __attribute__((ext_vector_type(4))) float f32x4;

__device__ __forceinline__ unsigned short f2bf(float f){
  unsigned int u = __builtin_bit_cast(unsigned int, f);
  u = (u + 0x7FFFu + ((u >> 16) & 1u)) >> 16;
  return (unsigned short)u;
}
__device__ __forceinline__ ushortT f2bff(float f){
  __bf16 b = (__bf16)f;
  return __builtin_bit_cast(ushortT, b);
}
__device__ __forceinline__ float bf2f(ushortT u){
  unsigned int v = ((unsigned int)u) << 16;
  return __builtin_bit_cast(float, v);
}
__device__ __forceinline__ bf16x8 load8bf(const ushortT* p){
  uint4 u = *reinterpret_cast<const uint4*>(p);
  return __builtin_bit_cast(bf16x8, u);
}
__device__ __forceinline__ bf16x8 load8f_bf(const float* p){
  float4 a = *reinterpret_cast<const float4*>(p);
  float4 b = *reinterpret_cast<const float4*>(p + 4);
  ushort8 u = { f2bff(a.x), f2bff(a.y), f2bff(a.z), f2bff(a.w),
                f2bff(b.x), f2bff(b.y), f2bff(b.z), f2bff(b.w) };
  return __builtin_bit_cast(bf16x8, u);
}
// fast silu: v * rcp(1+exp(-v))
__device__ __forceinline__ float silu(float v){
  return v * __builtin_amdgcn_rcpf(1.f + __expf(-v));
}

// pi-permutation: C-fragment register (n,r) of lane-group lg holds natural col
// c = 16n + lg*4 + r; B-fragment position p = ks*32 + lg*8 + j, n = 2ks + (j>>2), r = j&3.
__device__ __forceinline__ int c_of_p(int p){
  int ks = p >> 5, lg = (p >> 3) & 3, j = p & 7;
  return 16 * (ks * 2 + (j >> 2)) + lg * 4 + (j & 3);
}

// ---- merged prep: all weight transposes + bias perm + hist zero
struct PrepParams {
  const float* ew1; const float* ew2; const float* cw1;
  const float* nw1; const float* nw2; const float* ei; const float* eo;
  const float* eb1;
  ushortT* W1atp; ushortT* W1btp; ushortT* W1ct; ushortT* W2tp; ushortT* CW1tp;
  ushortT* NW1t; ushortT* NW2t; ushortT* Eint; ushortT* Eoutt;
  float* b1p; int* hist;
};

__device__ __forceinline__ void tcvt(int idx, const float* __restrict__ src,
                                     ushortT* __restrict__ dst,
                                     int srcK, int row_off, int K, int N, int Kpad,
                                     int pn, int pk){
  int k = idx % Kpad;
  int rem = idx / Kpad;
  int n = rem % N;
  int l = rem / N;
  float v = 0.f;
  if (k < K){
    int kk = pk ? c_of_p(k) : k;
    int nn = pn ? c_of_p(n) : n;
    v = src[((size_t)l * srcK + row_off + kk) * N + nn];
  }
  dst[idx] = f2bf(v);
}

#define PREP_TOTAL (49152*5 + 12288 + 98304 + 16384*2 + 16000 + 384)

__global__ void prep_kernel(PrepParams P){
  int idx = blockIdx.x * 256 + threadIdx.x;
  if (idx < 49152){ tcvt(idx, P.ew1, P.W1atp, 273,   0, 128, 128, 128, 1, 0); return; }
  idx -= 49152;
  if (idx < 49152){ tcvt(idx, P.ew1, P.W1btp, 273, 128, 128, 128, 128, 1, 0); return; }
  idx -= 49152;
  if (idx < 12288){ tcvt(idx, P.ew1, P.W1ct,  273, 256,  17, 128,  32, 0, 0); return; }
  idx -= 12288;
  if (idx < 49152){ tcvt(idx, P.ew2, P.W2tp,  128,   0, 128, 128, 128, 0, 1); return; }
  idx -= 49152;
  if (idx < 49152){ tcvt(idx, P.cw1, P.CW1tp, 128,   0, 128, 128, 128, 0, 1); return; }
  idx -= 49152;
  if (idx < 98304){ tcvt(idx, P.nw1, P.NW1t,  256,   0, 256, 128, 256, 0, 0); return; }
  idx -= 98304;
  if (idx < 49152){ tcvt(idx, P.nw2, P.NW2t,  128,   0, 128, 128, 128, 0, 0); return; }
  idx -= 49152;
  if (idx < 16384){ tcvt(idx, P.ei,  P.Eint,  128,   0, 128, 128, 128, 0, 0); return; }
  idx -= 16384;
  if (idx < 16384){ tcvt(idx, P.eo,  P.Eoutt, 128,   0, 128, 128, 128, 0, 0); return; }
  idx -= 16384;
  if (idx < 16000){ P.hist[idx] = 0; return; }
  idx -= 16000;
  if (idx < 384){ int l = idx >> 7, p = idx & 127; P.b1p[idx] = P.eb1[l * 128 + c_of_p(p)]; }
}

// ---- hist + block_start merged
__global__ void hist_bstart_kernel(const int* __restrict__ edges, int* __restrict__ hist,
                                   const int* __restrict__ bid, int* __restrict__ bstart){
  int b = blockIdx.x;
  if (b < N_EDGES / 256){
    int e = b * 256 + threadIdx.x;
    atomicAdd(&hist[edges[e]], 1);
  } else {
    int i = (b - N_EDGES / 256) * 256 + threadIdx.x;
    if (i <= N_BLOCKS){
      int lo = 0, hi = N_ATOMS;
      while (lo < hi){ int mid = (lo + hi) >> 1; if (bid[mid] < i) lo = mid + 1; else hi = mid; }
      bstart[i] = lo;
    }
  }
}

__global__ __launch_bounds__(1024) void scan_kernel(const int* __restrict__ hist,
                                                    int* __restrict__ estart,
                                                    int* __restrict__ ecur){
  __shared__ int ps[1024];
  int t = threadIdx.x;
  const int chunk = (N_BLOCKS + 1023) / 1024;
  int lo = t * chunk, hi = lo + chunk;
  if (hi > N_BLOCKS) hi = N_BLOCKS;
  if (lo > N_BLOCKS) lo = N_BLOCKS;
  int s = 0;
  for (int i = lo; i < hi; i++) s += hist[i];
  ps[t] = s;
  __syncthreads();
  for (int off = 1; off < 1024; off <<= 1){
    int v = (t >= off) ? ps[t - off] : 0;
    __syncthreads();
    ps[t] += v;
    __syncthreads();
  }
  int base = (t == 0) ? 0 : ps[t - 1];
  for (int i = lo; i < hi; i++){ estart[i] = base; ecur[i] = base; base += hist[i]; }
  if (t == 1023) estart[N_BLOCKS] = base;
}

// scatter into sorted order; sattr padded: 32 u16/edge = [0, attr0..15, 0 x15]
__global__ void scatter_kernel(const int* __restrict__ edges, const float* __restrict__ attr,
                               int* __restrict__ ecur,
                               int* __restrict__ srow, int* __restrict__ scol,
                               ushortT* __restrict__ sattr){
  int e = blockIdx.x * 256 + threadIdx.x;
  if (e >= N_EDGES) return;
  int r = edges[e], c = edges[N_EDGES + e];
  int p = atomicAdd(&ecur[r], 1);
  srow[p] = r; scol[p] = c;
  ushortT buf[32];
  buf[0] = 0;
#pragma unroll
  for (int k = 0; k < 16; k++) buf[k + 1] = f2bf(attr[(size_t)e * 16 + k]);
#pragma unroll
  for (int k = 17; k < 32; k++) buf[k] = 0;
#pragma unroll
  for (int k = 0; k < 16; k++)
    reinterpret_cast<uint*>(sattr + (size_t)p * 32)[k] = reinterpret_cast<uint*>(buf)[k];
}

__global__ void pool_kernel(const float* __restrict__ H, const float* __restrict__ Z,
                            const int* __restrict__ start,
                            float* __restrict__ Hm, float* __restrict__ x,
                            float* __restrict__ gsum){
  int b = blockIdx.x;
  int t = threadIdx.x;            // 128 threads
  if (b < 128) gsum[b * 128 + t] = 0.f;
  int s = start[b], e = start[b + 1];
  float inv = 1.f / (float)((e - s) > 0 ? (e - s) : 1);
  float sum = 0.f;
  for (int a = s; a < e; a++) sum += H[(size_t)a * HS + t];
  Hm[(size_t)b * HS + t] = sum * inv;
  if (t < 3){
    float sz = 0.f;
    for (int a = s; a < e; a++) sz += Z[a * 3 + t];
    x[b * 3 + t] = sz * inv;
  }
}

// ---- fused emb_in GEMM + layer-0 P/Q + zero agg/xacc slices (1-wave blocks, 1000)
__global__ __launch_bounds__(64) void gemm_pq_kernel(
    const float* __restrict__ A,
    const ushortT* __restrict__ Wt, const float* __restrict__ bias,
    float* __restrict__ Cf,
    const ushortT* __restrict__ Wa, const ushortT* __restrict__ Wb,
    const float* __restrict__ b1p,
    ushortT* __restrict__ Pbf, ushortT* __restrict__ Qbf,
    float* __restrict__ agg, float* __restrict__ xacc){
  __shared__ __align__(16) ushortT T1[2048];
  int lane = threadIdx.x;
  int l15 = lane & 15, lg = lane >> 4;
  int base = blockIdx.x * 16;
  int row = base + l15;
  {
    float4 z4 = {0.f, 0.f, 0.f, 0.f};
    float4* aggp = reinterpret_cast<float4*>(agg + (size_t)blockIdx.x * 16 * HS);
#pragma unroll
    for (int i = 0; i < 8; i++) aggp[lane + 64 * i] = z4;
    if (lane < 48) xacc[blockIdx.x * 48 + lane] = 0.f;
  }
  f32x4 zero = {0.f, 0.f, 0.f, 0.f};
  f32x4 acc[8];
#pragma unroll
  for (int n = 0; n < 8; n++) acc[n] = zero;
#pragma unroll
  for (int ks = 0; ks < 4; ks++){
    int k0 = ks * 32 + lg * 8;
    bf16x8 af = load8f_bf(A + (size_t)row * HS + k0);
#pragma unroll
    for (int n = 0; n < 8; n++){
      bf16x8 bf = load8bf(Wt + (size_t)(16 * n + l15) * HS + k0);
      acc[n] = __builtin_amdgcn_mfma_f32_16x16x32_bf16(af, bf, acc[n], 0, 0, 0);
    }
  }
#pragma unroll
  for (int n = 0; n < 8; n++){
    int col = 16 * n + l15;
    float bv = bias[col];
#pragma unroll
    for (int r = 0; r < 4; r++){
      int ro = base + lg * 4 + r;
      int er = lg * 4 + r;
      float hv = acc[n][r] + bv;
      Cf[(size_t)ro * HS + col] = hv;
      T1[(er * 128 + col) ^ ((er & 7) << 3)] = f2bff(hv);
    }
  }
  f32x4 accp[8], accq[8];
#pragma unroll
  for (int n = 0; n < 8; n++){ accp[n] = zero; accq[n] = zero; }
#pragma unroll
  for (int ks = 0; ks < 4; ks++){
    int k0 = ks * 32 + lg * 8;
    bf16x8 af = load8bf(&T1[(l15 * 128 + k0) ^ ((l15 & 7) << 3)]);
#pragma unroll
    for (int n = 0; n < 8; n++){
      accp[n] = __builtin_amdgcn_mfma_f32_16x16x32_bf16(af, load8bf(Wa + (size_t)(16 * n + l15) * HS + k0), accp[n], 0, 0, 0);
      accq[n] = __builtin_amdgcn_mfma_f32_16x16x32_bf16(af, load8bf(Wb + (size_t)(16 * n + l15) * HS + k0), accq[n], 0, 0, 0);
    }
  }
#pragma unroll
  for (int n = 0; n < 8; n++){
    int col = 16 * n + l15;
    float bv = b1p[col];
#pragma unroll
    for (int r = 0; r < 4; r++){
      int ro = base + lg * 4 + r;
      Pbf[(size_t)ro * HS + col] = f2bff(accp[n][r] + bv);
      Qbf[(size_t)ro * HS + col] = f2bff(accq[n][r]);
    }
  }
}

// ---- fused node MLP + x_update + zero-next + next-layer P/Q (1-wave blocks, 1000)
__global__ __launch_bounds__(64) void node_pq_kernel(
    float* __restrict__ h, float* __restrict__ agg,
    const ushortT* __restrict__ W1t, const ushortT* __restrict__ W2t,
    const float* __restrict__ b1, const float* __restrict__ b2,
    const ushortT* __restrict__ Wa, const ushortT* __restrict__ Wb,
    const float* __restrict__ b1p,
    ushortT* __restrict__ Pbf, ushortT* __restrict__ Qbf,
    float* __restrict__ x, float* __restrict__ xacc, const int* __restrict__ estart){
  __shared__ __align__(16) ushortT T1[2048];
  int lane = threadIdx.x;
  int l15 = lane & 15, lg = lane >> 4;
  int base = blockIdx.x * 16;
  int row = base + l15;
  f32x4 zero = {0.f, 0.f, 0.f, 0.f};

  if (lane < 48){
    int i = blockIdx.x * 48 + lane;
    int b = i / 3;
    int cnt = estart[b + 1] - estart[b];
    x[i] += xacc[i] / (float)(cnt > 0 ? cnt : 1);
    xacc[i] = 0.f;
  }

  f32x4 acc[8];
#pragma unroll
  for (int n = 0; n < 8; n++) acc[n] = zero;
#pragma unroll
  for (int ks = 0; ks < 8; ks++){
    int k0 = ks * 32 + lg * 8;
    bf16x8 af = (k0 < 128) ? load8f_bf(h + (size_t)row * HS + k0)
                           : load8f_bf(agg + (size_t)row * HS + (k0 - 128));
#pragma unroll
    for (int n = 0; n < 8; n++){
      acc[n] = __builtin_amdgcn_mfma_f32_16x16x32_bf16(af, load8bf(W1t + (size_t)(16 * n + l15) * 256 + k0), acc[n], 0, 0, 0);
    }
  }
  // drain agg reads then zero this block's agg slice
  __syncthreads();
  {
    float4 z4 = {0.f, 0.f, 0.f, 0.f};
    float4* aggp = reinterpret_cast<float4*>(agg + (size_t)blockIdx.x * 16 * HS);
#pragma unroll
    for (int i = 0; i < 8; i++) aggp[lane + 64 * i] = z4;
  }
#pragma unroll
  for (int n = 0; n < 8; n++){
    int col = 16 * n + l15;
    float bv = b1[col];
#pragma unroll
    for (int r = 0; r < 4; r++){
      int er = lg * 4 + r;
      T1[(er * 128 + col) ^ ((er & 7) << 3)] = f2bff(silu(acc[n][r] + bv));
    }
  }
#pragma unroll
  for (int n = 0; n < 8; n++) acc[n] = zero;
#pragma unroll
  for (int ks = 0; ks < 4; ks++){
    int k0 = ks * 32 + lg * 8;
    bf16x8 af = load8bf(&T1[(l15 * 128 + k0) ^ ((l15 & 7) << 3)]);
#pragma unroll
    for (int n = 0; n < 8; n++){
      acc[n] = __builtin_amdgcn_mfma_f32_16x16x32_bf16(af, load8bf(W2t + (size_t)(16 * n + l15) * HS + k0), acc[n], 0, 0, 0);
    }
  }
#pragma unroll
  for (int n = 0; n < 8; n++){
    int col = 16 * n + l15;
    float bv = b2[col];
#pragma unroll
    for (int r = 0; r < 4; r++){
      int ro = base + lg * 4 + r;
      int er = lg * 4 + r;
      float hv = h[(size_t)ro * HS + col] + acc[n][r] + bv;
      h[(size_t)ro * HS + col] = hv;
      T1[(er * 128 + col) ^ ((er & 7) << 3)] = f2bff(hv);
    }
  }
  // next-layer P/Q from T1
  f32x4 accp[8], accq[8];
#pragma unroll
  for (int n = 0; n < 8; n++){ accp[n] = zero; accq[n] = zero; }
#pragma unroll
  for (int ks = 0; ks < 4; ks++){
    int k0 = ks * 32 + lg * 8;
    bf16x8 af = load8bf(&T1[(l15 * 128 + k0) ^ ((l15 & 7) << 3)]);
#pragma unroll
    for (int n = 0; n < 8; n++){
      accp[n] = __builtin_amdgcn_mfma_f32_16x16x32_bf16(af, load8bf(Wa + (size_t)(16 * n + l15) * HS + k0), accp[n], 0, 0, 0);
      accq[n] = __builtin_amdgcn_mfma_f32_16x16x32_bf16(af, load8bf(Wb + (size_t)(16 * n + l15) * HS + k0), accq[n], 0, 0, 0);
    }
  }
#pragma unroll
  for (int n = 0; n < 8; n++){
    int col = 16 * n + l15;
    float bv = b1p[col];
#pragma unroll
    for (int r = 0; r < 4; r++){
      int ro = base + lg * 4 + r;
      Pbf[(size_t)ro * HS + col] = f2bff(accp[n][r] + bv);
      Qbf[(size_t)ro * HS + col] = f2bff(accq[n][r]);
    }
  }
}

// ---- fused final node MLP + emb_out GEMM + normalize + graph accumulate (1-wave, 1000)
__global__ __launch_bounds__(64) void node_emb_kernel(
    const float* __restrict__ h, const float* __restrict__ agg,
    const ushortT* __restrict__ W1t, const ushortT* __restrict__ W2t,
    const float* __restrict__ b1, const float* __restrict__ b2,
    const ushortT* __restrict__ Eoutt, const float* __restrict__ eob,
    const int* __restrict__ batch_id,
    float* __restrict__ brep, float* __restrict__ gsum){
  __shared__ __align__(16) ushortT T1[2048];
  int lane = threadIdx.x;
  int l15 = lane & 15, lg = lane >> 4;
  int base = blockIdx.x * 16;
  int row = base + l15;
  f32x4 zero = {0.f, 0.f, 0.f, 0.f};

  f32x4 acc[8];
#pragma unroll
  for (int n = 0; n < 8; n++) acc[n] = zero;
#pragma unroll
  for (int ks = 0; ks < 8; ks++){
    int k0 = ks * 32 + lg * 8;
    bf16x8 af = (k0 < 128) ? load8f_bf(h + (size_t)row * HS + k0)
                           : load8f_bf(agg + (size_t)row * HS + (k0 - 128));
#pragma unroll
    for (int n = 0; n < 8; n++){
      acc[n] = __builtin_amdgcn_mfma_f32_16x16x32_bf16(af, load8bf(W1t + (size_t)(16 * n + l15) * 256 + k0), acc[n], 0, 0, 0);
    }
  }
#pragma unroll
  for (int n = 0; n < 8; n++){
    int col = 16 * n + l15;
    float bv = b1[col];
#pragma unroll
    for (int r = 0; r < 4; r++){
      int er = lg * 4 + r;
      T1[(er * 128 + col) ^ ((er & 7) << 3)] = f2bff(silu(acc[n][r] + bv));
    }
  }
#pragma unroll
  for (int n = 0; n < 8; n++) acc[n] = zero;
#pragma unroll
  for (int ks = 0; ks < 4; ks++){
    int k0 = ks * 32 + lg * 8;
    bf16x8 af = load8bf(&T1[(l15 * 128 + k0) ^ ((l15 & 7) << 3)]);
#pragma unroll
    for (int n = 0; n < 8; n++){
      acc[n] = __builtin_amdgcn_mfma_f32_16x16x32_bf16(af, load8bf(W2t + (size_t)(16 * n + l15) * HS + k0), acc[n], 0, 0, 0);
    }
  }
  // h_final = h + acc + b2 -> T1 (bf16)
#pragma unroll
  for (int n = 0; n < 8; n++){
    int col = 16 * n + l15;
    float bv = b2[col];
#pragma unroll
    for (int r = 0; r < 4; r++){
      int ro = base + lg * 4 + r;
      int er = lg * 4 + r;
      float hv = h[(size_t)ro * HS + col] + acc[n][r] + bv;
      T1[(er * 128 + col) ^ ((er & 7) << 3)] = f2bff(hv);
    }
  }
  // emb_out GEMM from T1
#pragma unroll
  for (int n = 0; n < 8; n++) acc[n] = zero;
#pragma unroll
  for (int ks = 0; ks < 4; ks++){
    int k0 = ks * 32 + lg * 8;
    bf16x8 af = load8bf(&T1[(l15 * 128 + k0) ^ ((l15 & 7) << 3)]);
#pragma unroll
    for (int n = 0; n < 8; n++){
      acc[n] = __builtin_amdgcn_mfma_f32_16x16x32_bf16(af, load8bf(Eoutt + (size_t)(16 * n + l15) * HS + k0), acc[n], 0, 0, 0);
    }
  }
#pragma unroll
  for (int n = 0; n < 8; n++){
    float bv = eob[16 * n + l15];
#pragma unroll
    for (int r = 0; r < 4; r++) acc[n][r] += bv;
  }
  float scl[4];
#pragma unroll
  for (int r = 0; r < 4; r++){
    float ss = 0.f;
#pragma unroll
    for (int n = 0; n < 8; n++) ss += acc[n][r] * acc[n][r];
#pragma unroll
    for (int o = 1; o < 16; o <<= 1) ss += __shfl_xor(ss, o, 64);
    scl[r] = 1.f / fmaxf(sqrtf(ss), 1e-12f);
  }
#pragma unroll
  for (int r = 0; r < 4; r++){
    int ro = base + lg * 4 + r;
    int g = batch_id[ro];
#pragma unroll
    for (int n = 0; n < 8; n++){
      int col = 16 * n + l15;
      float v = acc[n][r] * scl[r];
      brep[(size_t)ro * HS + col] = v;
      atomicAdd(&gsum[g * HS + col], v);
    }
  }
}

// ---- fused edge kernel: channel-split + phase-C register reuse of own ks slice.
template<int COORD>
__global__ __launch_bounds__(256, 4) void edge_kernel(
    const int* __restrict__ srow, const int* __restrict__ scol,
    const ushortT* __restrict__ sattr,
    const float* __restrict__ x,
    const ushortT* __restrict__ Pbf, const ushortT* __restrict__ Qbf,
    const ushortT* __restrict__ W1ct, const ushortT* __restrict__ W2tp,
    const ushortT* __restrict__ CW1tp,
    const float* __restrict__ b2, const float* __restrict__ cb1,
    const float* __restrict__ cw3,
    float* __restrict__ xacc, float* __restrict__ agg){
  __shared__ float bias_l[3][128];
  __shared__ int   rid_s[64];
  __shared__ float dif_s[COORD ? 64 : 1][3];
  __shared__ float wall[COORD ? 4 : 1][COORD ? 64 : 1];
  __shared__ __align__(16) ushortT S1[64 * 128];   // m1, pi-order, swizzled
  __shared__ __align__(16) ushortT S2[64 * 128];   // m,  pi-order, swizzled

  const int t = threadIdx.x;
  const int lane = t & 63;
  const int wv = t >> 6;
  const int l15 = lane & 15, lg = lane >> 4;
  const f32x4 zero = {0.f, 0.f, 0.f, 0.f};

  if (t < 128){
    bias_l[0][t] = b2[t];
    if (COORD){ bias_l[1][t] = cb1[t]; bias_l[2][t] = cw3[t]; }
  }

  // ---------- phase A: m1 for this wave's 16 edges ----------
  const int erow = wv * 16 + l15;
  const int e = blockIdx.x * 64 + erow;
  const int r = srow[e], c = scol[e];
  const float dx = x[r * 3 + 0] - x[c * 3 + 0];
  const float dy = x[r * 3 + 1] - x[c * 3 + 1];
  const float dz = x[r * 3 + 2] - x[c * 3 + 2];
  const float rad = dx * dx + dy * dy + dz * dz;
  if (lg == 0){
    rid_s[erow] = r;
    if (COORD){ dif_s[erow][0] = dx; dif_s[erow][1] = dy; dif_s[erow][2] = dz; }
  }
  ushort8 at8 = __builtin_bit_cast(ushort8, load8bf(sattr + (size_t)e * 32 + lg * 8));
  if (lg == 0) at8[0] = f2bff(rad);
  const bf16x8 atb = __builtin_bit_cast(bf16x8, at8);

#pragma unroll
  for (int ks = 0; ks < 4; ks++){
    f32x4 a0 = __builtin_amdgcn_mfma_f32_16x16x32_bf16(
        load8bf(W1ct + (size_t)(16 * (2 * ks)     + l15) * 32 + lg * 8), atb, zero, 0, 0, 0);
    f32x4 a1 = __builtin_amdgcn_mfma_f32_16x16x32_bf16(
        load8bf(W1ct + (size_t)(16 * (2 * ks + 1) + l15) * 32 + lg * 8), atb, zero, 0, 0, 0);
    ushort8 pv = __builtin_bit_cast(ushort8, load8bf(Pbf + (size_t)r * HS + ks * 32 + lg * 8));
    ushort8 qv = __builtin_bit_cast(ushort8, load8bf(Qbf + (size_t)c * HS + ks * 32 + lg * 8));
    ushort8 af;
#pragma unroll
    for (int j = 0; j < 4; j++)
      af[j] = f2bff(silu(a0[j] + bf2f(pv[j]) + bf2f(qv[j])));
#pragma unroll
    for (int j = 4; j < 8; j++)
      af[j] = f2bff(silu(a1[j - 4] + bf2f(pv[j]) + bf2f(qv[j])));
    int byte = (erow * 256 + ks * 64 + lg * 16) ^ ((erow & 7) << 4);
    *reinterpret_cast<uint4*>(reinterpret_cast<char*>(S1) + byte) = __builtin_bit_cast(uint4, af);
  }
  __syncthreads();   // bar1: S1 + rid + dif + biases ready

  // ---------- phase B: GEMM2 chan-split (groups 2wv, 2wv+1; all 64 edges) ----------
  f32x4 acc2[4][2];
#pragma unroll
  for (int et = 0; et < 4; et++){ acc2[et][0] = zero; acc2[et][1] = zero; }
#pragma unroll
  for (int ks = 0; ks < 4; ks++){
    bf16x8 wf0 = load8bf(W2tp + (size_t)(16 * (2 * wv)     + l15) * HS + ks * 32 + lg * 8);
    bf16x8 wf1 = load8bf(W2tp + (size_t)(16 * (2 * wv + 1) + l15) * HS + ks * 32 + lg * 8);
#pragma unroll
    for (int et = 0; et < 4; et++){
      int row2 = et * 16 + l15;
      int byte = (row2 * 256 + ks * 64 + lg * 16) ^ ((row2 & 7) << 4);
      bf16x8 mb = __builtin_bit_cast(bf16x8,
          *reinterpret_cast<const uint4*>(reinterpret_cast<const char*>(S1) + byte));
      acc2[et][0] = __builtin_amdgcn_mfma_f32_16x16x32_bf16(wf0, mb, acc2[et][0], 0, 0, 0);
      acc2[et][1] = __builtin_amdgcn_mfma_f32_16x16x32_bf16(wf1, mb, acc2[et][1], 0, 0, 0);
    }
  }
  // m-epilogue: silu + b2 -> mreg (kept for phase C's ks==wv) + single b128 S2 write
  ushort8 mreg[4];
#pragma unroll
  for (int et = 0; et < 4; et++){
    ushort8 mq;
#pragma unroll
    for (int g = 0; g < 2; g++){
      float4 bv = *reinterpret_cast<const float4*>(&bias_l[0][16 * (2 * wv + g) + lg * 4]);
#pragma unroll
      for (int rr = 0; rr < 4; rr++)
        mq[g * 4 + rr] = f2bff(silu(acc2[et][g][rr] + (&bv.x)[rr]));
    }
    mreg[et] = mq;
    int row2 = et * 16 + l15;
    int byte = (row2 * 256 + wv * 64 + lg * 16) ^ ((row2 & 7) << 4);
    *reinterpret_cast<uint4*>(reinterpret_cast<char*>(S2) + byte) = __builtin_bit_cast(uint4, mq);
  }
  __syncthreads();   // bar2: S2 ready

  if (COORD){
    // ---------- phase C: coord GEMM chan-split (own ks slice from registers) ----------
    f32x4 acc3[4][2];
#pragma unroll
    for (int et = 0; et < 4; et++){ acc3[et][0] = zero; acc3[et][1] = zero; }
#pragma unroll
    for (int ks = 0; ks < 4; ks++){
      bf16x8 wf0 = load8bf(CW1tp + (size_t)(16 * (2 * wv)     + l15) * HS + ks * 32 + lg * 8);
      bf16x8 wf1 = load8bf(CW1tp + (size_t)(16 * (2 * wv + 1) + l15) * HS + ks * 32 + lg * 8);
#pragma unroll
      for (int et = 0; et < 4; et++){
        bf16x8 mb;
        if (ks == wv){
          mb = __builtin_bit_cast(bf16x8, mreg[et]);
        } else {
          int row2 = et * 16 + l15;
          int byte = (row2 * 256 + ks * 64 + lg * 16) ^ ((row2 & 7) << 4);
          mb = __builtin_bit_cast(bf16x8,
              *reinterpret_cast<const uint4*>(reinterpret_cast<const char*>(S2) + byte));
        }
        acc3[et][0] = __builtin_amdgcn_mfma_f32_16x16x32_bf16(wf0, mb, acc3[et][0], 0, 0, 0);
        acc3[et][1] = __builtin_amdgcn_mfma_f32_16x16x32_bf16(wf1, mb, acc3[et][1], 0, 0, 0);
      }
    }
    // per-wave partial w -> wall
#pragma unroll
    for (int et = 0; et < 4; et++){
      float ws = 0.f;
#pragma unroll
      for (int g = 0; g < 2; g++){
        int n = 2 * wv + g;
        float4 cbv = *reinterpret_cast<const float4*>(&bias_l[1][16 * n + lg * 4]);
        float4 cwv = *reinterpret_cast<const float4*>(&bias_l[2][16 * n + lg * 4]);
#pragma unroll
        for (int rr = 0; rr < 4; rr++)
          ws += silu(acc3[et][g][rr] + (&cbv.x)[rr]) * (&cwv.x)[rr];
      }
      ws += __shfl_xor(ws, 16, 64);
      ws += __shfl_xor(ws, 32, 64);
      if (lg == 0) wall[wv][et * 16 + l15] = ws;
    }
  }

  // ---------- agg flush: this wave's own 16 edges, full chans from S2 (b32 pairs) ----------
  {
    const int c0 = c_of_p(2 * lane), c1 = c_of_p(2 * lane + 1);
    float run0 = 0.f, run1 = 0.f;
    int prev = __builtin_amdgcn_readfirstlane(rid_s[wv * 16]);
#pragma unroll
    for (int e2 = 0; e2 < 16; e2++){
      int re = __builtin_amdgcn_readfirstlane(rid_s[wv * 16 + e2]);
      if (re != prev){
        atomicAdd(&agg[(size_t)prev * HS + c0], run0);
        atomicAdd(&agg[(size_t)prev * HS + c1], run1);
        run0 = 0.f; run1 = 0.f; prev = re;
      }
      int row2 = wv * 16 + e2;
      int byte = (row2 * 256 + lane * 4) ^ ((row2 & 7) << 4);
      uint u = *reinterpret_cast<const uint*>(reinterpret_cast<const char*>(S2) + byte);
      run0 += bf2f((ushortT)(u & 0xFFFF));
      run1 += bf2f((ushortT)(u >> 16));
    }
    atomicAdd(&agg[(size_t)prev * HS + c0], run0);
    atomicAdd(&agg[(size_t)prev * HS + c1], run1);
  }

  if (COORD){
    __syncthreads();   // bar3: wall complete
    if (t < 192){
      int e2 = t / 3, cd = t % 3;
      float w = wall[0][e2] + wall[1][e2] + wall[2][e2] + wall[3][e2];
      atomicAdd(&xacc[(size_t)rid_s[e2] * 3 + cd], dif_s[e2][cd] * w);
    }
  }
}

__global__ void norm_graph_kernel(const float* __restrict__ gsum, float* __restrict__ grep){
  int wv = threadIdx.x >> 6, lane = threadIdx.x & 63;
  int g = blockIdx.x * 4 + wv;
  if (g >= N_GRAPHS) return;
  float v0 = gsum[g * HS + lane];
  float v1 = gsum[g * HS + 64 + lane];
  float ss = v0 * v0 + v1 * v1;
#pragma unroll
  for (int o = 1; o < 64; o <<= 1) ss += __shfl_xor(ss, o, 64);
  float s = 1.f / fmaxf(sqrtf(ss), 1e-12f);
  grep[(size_t)g * HS + lane] = v0 * s;
  grep[(size_t)g * HS + 64 + lane] = v1 * s;
}

extern "C" void kernel_launch(void* const* d_in, const int* in_sizes, int n_in,
                              void* d_out, int out_size, void* d_ws, size_t ws_size,
                              hipStream_t stream){
  const float* H         = (const float*)d_in[0];
  const float* Z         = (const float*)d_in[1];
  const int*   block_id  = (const int*)d_in[2];
  const int*   batch_id  = (const int*)d_in[3];
  const int*   edges     = (const int*)d_in[4];
  const float* edge_attr = (const float*)d_in[5];
  const float* emb_in_w  = (const float*)d_in[6];
  const float* emb_in_b  = (const float*)d_in[7];
  const float* emb_out_w = (const float*)d_in[8];
  const float* emb_out_b = (const float*)d_in[9];
  const float* edge_w1   = (const float*)d_in[10];
  const float* edge_b1   = (const float*)d_in[11];
  const float* edge_w2   = (const float*)d_in[12];
  const float* edge_b2   = (const float*)d_in[13];
  const float* node_w1   = (const float*)d_in[14];
  const float* node_b1   = (const float*)d_in[15];
  const float* node_w2   = (const float*)d_in[16];
  const float* node_b2   = (const float*)d_in[17];
  const float* coord_w1  = (const float*)d_in[18];
  const float* coord_b1  = (const float*)d_in[19];
  const float* coord_w3  = (const float*)d_in[20];

  float* out  = (float*)d_out;
  float* Hm   = out;                               // [16000 x 128]
  float* brep = out + (size_t)N_BLOCKS * HS;       // [16000 x 128]
  float* grep = out + (size_t)2 * N_BLOCKS * HS;   // [128 x 128]

  char* base = (char*)d_ws;
  size_t off = 0;
  auto take = [&](size_t bytes) -> char* {
    char* p = base + off;
    off += (bytes + 255) & ~(size_t)255;
    return p;
  };
  float*   x     = (float*)  take((size_t)N_BLOCKS * 3 * 4);
  float*   xacc  = (float*)  take((size_t)N_BLOCKS * 3 * 4);
  float*   h     = (float*)  take((size_t)N_BLOCKS * HS * 4);
  float*   agg   = (float*)  take((size_t)N_BLOCKS * HS * 4);
  float*   gsum  = (float*)  take((size_t)N_GRAPHS * HS * 4);
  int*     bstart= (int*)    take((size_t)(N_BLOCKS + 1) * 4);
  int*     hist  = (int*)    take((size_t)N_BLOCKS * 4);
  int*     estart= (int*)    take((size_t)(N_BLOCKS + 1) * 4);
  int*     ecur  = (int*)    take((size_t)N_BLOCKS * 4);
  int*     srow  = (int*)    take((size_t)N_EDGES * 4);
  int*     scol  = (int*)    take((size_t)N_EDGES * 4);
  ushortT* sattr = (ushortT*)take((size_t)N_EDGES * 32 * 2);
  ushortT* Pbf   = (ushortT*)take((size_t)N_BLOCKS * HS * 2);
  ushortT* Qbf   = (ushortT*)take((size_t)N_BLOCKS * HS * 2);
  ushortT* W1atp = (ushortT*)take((size_t)3 * 128 * 128 * 2);
  ushortT* W1btp = (ushortT*)take((size_t)3 * 128 * 128 * 2);
  ushortT* W1ct  = (ushortT*)take((size_t)3 * 128 * 32 * 2);
  ushortT* W2tp  = (ushortT*)take((size_t)3 * 128 * 128 * 2);
  ushortT* CW1tp = (ushortT*)take((size_t)3 * 128 * 128 * 2);
  ushortT* NW1t  = (ushortT*)take((size_t)3 * 128 * 256 * 2);
  ushortT* NW2t  = (ushortT*)take((size_t)3 * 128 * 128 * 2);
  ushortT* Eint  = (ushortT*)take((size_t)128 * 128 * 2);
  ushortT* Eoutt = (ushortT*)take((size_t)128 * 128 * 2);
  float*   b1p   = (float*)  take((size_t)3 * 128 * 4);

  // merged prep (weights + bias perm + hist zero)
  PrepParams P;
  P.ew1 = edge_w1; P.ew2 = edge_w2; P.cw1 = coord_w1;
  P.nw1 = node_w1; P.nw2 = node_w2; P.ei = emb_in_w; P.eo = emb_out_w;
  P.eb1 = edge_b1;
  P.W1atp = W1atp; P.W1btp = W1btp; P.W1ct = W1ct; P.W2tp = W2tp; P.CW1tp = CW1tp;
  P.NW1t = NW1t; P.NW2t = NW2t; P.Eint = Eint; P.Eoutt = Eoutt;
  P.b1p = b1p; P.hist = hist;
  prep_kernel<<<(PREP_TOTAL + 255) / 256, 256, 0, stream>>>(P);

  hist_bstart_kernel<<<N_EDGES / 256 + (N_BLOCKS + 1 + 255) / 256, 256, 0, stream>>>(
      edges, hist, block_id, bstart);
  scan_kernel<<<1, 1024, 0, stream>>>(hist, estart, ecur);
  scatter_kernel<<<N_EDGES / 256, 256, 0, stream>>>(edges, edge_attr, ecur, srow, scol, sattr);
  pool_kernel<<<N_BLOCKS, 128, 0, stream>>>(H, Z, bstart, Hm, x, gsum);

  // h = Hm @ emb_in_w + b ; P/Q layer 0 ; zero agg/xacc
  gemm_pq_kernel<<<N_BLOCKS / 16, 64, 0, stream>>>(Hm, Eint, emb_in_b, h,
                                                   W1atp, W1btp, b1p, Pbf, Qbf, agg, xacc);

  for (int l = 0; l < 3; l++){
    if (l < 2){
      edge_kernel<1><<<N_EDGES / 64, 256, 0, stream>>>(
          srow, scol, sattr, x, Pbf, Qbf,
          W1ct + (size_t)l * 128 * 32, W2tp + (size_t)l * 128 * 128, CW1tp + (size_t)l * 128 * 128,
          edge_b2 + l * 128, coord_b1 + l * 128, coord_w3 + l * 128,
          xacc, agg);
      node_pq_kernel<<<N_BLOCKS / 16, 64, 0, stream>>>(
          h, agg, NW1t + (size_t)l * 128 * 256, NW2t + (size_t)l * 128 * 128,
          node_b1 + l * 128, node_b2 + l * 128,
          W1atp + (size_t)(l + 1) * 128 * 128, W1btp + (size_t)(l + 1) * 128 * 128,
          b1p + (l + 1) * 128, Pbf, Qbf, x, xacc, estart);
    } else {
      edge_kernel<0><<<N_EDGES / 64, 256, 0, stream>>>(
          srow, scol, sattr, x, Pbf, Qbf,
          W1ct + (size_t)l * 128 * 32, W2tp + (size_t)l * 128 * 128, CW1tp + (size_t)l * 128 * 128,
          edge_b2 + l * 128, coord_b1 + l * 128, coord_w3 + l * 128,
          xacc, agg);
      node_emb_kernel<<<N_BLOCKS / 16, 64, 0, stream>>>(
          h, agg, NW1t + (size_t)l * 128 * 256, NW2t + (size_t)l * 128 * 128,
          node_b1 + l * 128, node_b2 + l * 128,
          Eoutt, emb_out_b, batch_id, brep, gsum);
    }
  }

  norm_graph_kernel<<<N_GRAPHS / 4, 256, 0, stream>>>(gsum, grep);
}

// Round 14
// 504.975 us; speedup vs baseline: 1.0734x; 1.0333x over previous
//
#include <hip/hip_runtime.h>

#define N_ATOMS  80000
#define N_BLOCKS 16000
#define N_EDGES  320000
#define N_GRAPHS 128
#define HS       128

typedef unsigned short ushortT;
typedef __attribute__((ext_vector_type(8))) __bf16 bf16x8;
typedef __attribute__((ext_vector_type(8))) unsigned short ushort8;
typedef __attribute__((ext_vector_type(4))) float f32x4;

__device__ __forceinline__ unsigned short f2bf(float f){
  unsigned int u = __builtin_bit_cast(unsigned int, f);
  u = (u + 0x7FFFu + ((u >> 16) & 1u)) >> 16;
  return (unsigned short)u;
}
__device__ __forceinline__ ushortT f2bff(float f){
  __bf16 b = (__bf16)f;
  return __builtin_bit_cast(ushortT, b);
}
__device__ __forceinline__ float bf2f(ushortT u){
  unsigned int v = ((unsigned int)u) << 16;
  return __builtin_bit_cast(float, v);
}
__device__ __forceinline__ bf16x8 load8bf(const ushortT* p){
  uint4 u = *reinterpret_cast<const uint4*>(p);
  return __builtin_bit_cast(bf16x8, u);
}
__device__ __forceinline__ bf16x8 load8f_bf(const float* p){
  float4 a = *reinterpret_cast<const float4*>(p);
  float4 b = *reinterpret_cast<const float4*>(p + 4);
  ushort8 u = { f2bff(a.x), f2bff(a.y), f2bff(a.z), f2bff(a.w),
                f2bff(b.x), f2bff(b.y), f2bff(b.z), f2bff(b.w) };
  return __builtin_bit_cast(bf16x8, u);
}
// fast silu: v * rcp(1+exp(-v))
__device__ __forceinline__ float silu(float v){
  return v * __builtin_amdgcn_rcpf(1.f + __expf(-v));
}

// pi-permutation: C-fragment register (n,r) of lane-group lg holds natural col
// c = 16n + lg*4 + r; B-fragment position p = ks*32 + lg*8 + j, n = 2ks + (j>>2), r = j&3.
__device__ __forceinline__ int c_of_p(int p){
  int ks = p >> 5, lg = (p >> 3) & 3, j = p & 7;
  return 16 * (ks * 2 + (j >> 2)) + lg * 4 + (j & 3);
}

// ---- merged prep: all weight transposes + bias perm + hist zero
struct PrepParams {
  const float* ew1; const float* ew2; const float* cw1;
  const float* nw1; const float* nw2; const float* ei; const float* eo;
  const float* eb1;
  ushortT* W1atp; ushortT* W1btp; ushortT* W1ct; ushortT* W2tp; ushortT* CW1tp;
  ushortT* NW1t; ushortT* NW2t; ushortT* Eint; ushortT* Eoutt;
  float* b1p; int* hist;
};

__device__ __forceinline__ void tcvt(int idx, const float* __restrict__ src,
                                     ushortT* __restrict__ dst,
                                     int srcK, int row_off, int K, int N, int Kpad,
                                     int pn, int pk){
  int k = idx % Kpad;
  int rem = idx / Kpad;
  int n = rem % N;
  int l = rem / N;
  float v = 0.f;
  if (k < K){
    int kk = pk ? c_of_p(k) : k;
    int nn = pn ? c_of_p(n) : n;
    v = src[((size_t)l * srcK + row_off + kk) * N + nn];
  }
  dst[idx] = f2bf(v);
}

#define PREP_TOTAL (49152*5 + 12288 + 98304 + 16384*2 + 16000 + 384)

__global__ void prep_kernel(PrepParams P){
  int idx = blockIdx.x * 256 + threadIdx.x;
  if (idx < 49152){ tcvt(idx, P.ew1, P.W1atp, 273,   0, 128, 128, 128, 1, 0); return; }
  idx -= 49152;
  if (idx < 49152){ tcvt(idx, P.ew1, P.W1btp, 273, 128, 128, 128, 128, 1, 0); return; }
  idx -= 49152;
  if (idx < 12288){ tcvt(idx, P.ew1, P.W1ct,  273, 256,  17, 128,  32, 0, 0); return; }
  idx -= 12288;
  if (idx < 49152){ tcvt(idx, P.ew2, P.W2tp,  128,   0, 128, 128, 128, 0, 1); return; }
  idx -= 49152;
  if (idx < 49152){ tcvt(idx, P.cw1, P.CW1tp, 128,   0, 128, 128, 128, 0, 1); return; }
  idx -= 49152;
  if (idx < 98304){ tcvt(idx, P.nw1, P.NW1t,  256,   0, 256, 128, 256, 0, 0); return; }
  idx -= 98304;
  if (idx < 49152){ tcvt(idx, P.nw2, P.NW2t,  128,   0, 128, 128, 128, 0, 0); return; }
  idx -= 49152;
  if (idx < 16384){ tcvt(idx, P.ei,  P.Eint,  128,   0, 128, 128, 128, 0, 0); return; }
  idx -= 16384;
  if (idx < 16384){ tcvt(idx, P.eo,  P.Eoutt, 128,   0, 128, 128, 128, 0, 0); return; }
  idx -= 16384;
  if (idx < 16000){ P.hist[idx] = 0; return; }
  idx -= 16000;
  if (idx < 384){ int l = idx >> 7, p = idx & 127; P.b1p[idx] = P.eb1[l * 128 + c_of_p(p)]; }
}

// ---- hist + block_start merged
__global__ void hist_bstart_kernel(const int* __restrict__ edges, int* __restrict__ hist,
                                   const int* __restrict__ bid, int* __restrict__ bstart){
  int b = blockIdx.x;
  if (b < N_EDGES / 256){
    int e = b * 256 + threadIdx.x;
    atomicAdd(&hist[edges[e]], 1);
  } else {
    int i = (b - N_EDGES / 256) * 256 + threadIdx.x;
    if (i <= N_BLOCKS){
      int lo = 0, hi = N_ATOMS;
      while (lo < hi){ int mid = (lo + hi) >> 1; if (bid[mid] < i) lo = mid + 1; else hi = mid; }
      bstart[i] = lo;
    }
  }
}

__global__ __launch_bounds__(1024) void scan_kernel(const int* __restrict__ hist,
                                                    int* __restrict__ estart,
                                                    int* __restrict__ ecur){
  __shared__ int ps[1024];
  int t = threadIdx.x;
  const int chunk = (N_BLOCKS + 1023) / 1024;
  int lo = t * chunk, hi = lo + chunk;
  if (hi > N_BLOCKS) hi = N_BLOCKS;
  if (lo > N_BLOCKS) lo = N_BLOCKS;
  int s = 0;
  for (int i = lo; i < hi; i++) s += hist[i];
  ps[t] = s;
  __syncthreads();
  for (int off = 1; off < 1024; off <<= 1){
    int v = (t >= off) ? ps[t - off] : 0;
    __syncthreads();
    ps[t] += v;
    __syncthreads();
  }
  int base = (t == 0) ? 0 : ps[t - 1];
  for (int i = lo; i < hi; i++){ estart[i] = base; ecur[i] = base; base += hist[i]; }
  if (t == 1023) estart[N_BLOCKS] = base;
}

// scatter into sorted order; sattr padded: 32 u16/edge = [0, attr0..15, 0 x15]
__global__ void scatter_kernel(const int* __restrict__ edges, const float* __restrict__ attr,
                               int* __restrict__ ecur,
                               int* __restrict__ srow, int* __restrict__ scol,
                               ushortT* __restrict__ sattr){
  int e = blockIdx.x * 256 + threadIdx.x;
  if (e >= N_EDGES) return;
  int r = edges[e], c = edges[N_EDGES + e];
  int p = atomicAdd(&ecur[r], 1);
  srow[p] = r; scol[p] = c;
  ushortT buf[32];
  buf[0] = 0;
#pragma unroll
  for (int k = 0; k < 16; k++) buf[k + 1] = f2bf(attr[(size_t)e * 16 + k]);
#pragma unroll
  for (int k = 17; k < 32; k++) buf[k] = 0;
#pragma unroll
  for (int k = 0; k < 16; k++)
    reinterpret_cast<uint*>(sattr + (size_t)p * 32)[k] = reinterpret_cast<uint*>(buf)[k];
}

__global__ void pool_kernel(const float* __restrict__ H, const float* __restrict__ Z,
                            const int* __restrict__ start,
                            float* __restrict__ Hm, float* __restrict__ x,
                            float* __restrict__ gsum){
  int b = blockIdx.x;
  int t = threadIdx.x;            // 128 threads
  if (b < 128) gsum[b * 128 + t] = 0.f;
  int s = start[b], e = start[b + 1];
  float inv = 1.f / (float)((e - s) > 0 ? (e - s) : 1);
  float sum = 0.f;
  for (int a = s; a < e; a++) sum += H[(size_t)a * HS + t];
  Hm[(size_t)b * HS + t] = sum * inv;
  if (t < 3){
    float sz = 0.f;
    for (int a = s; a < e; a++) sz += Z[a * 3 + t];
    x[b * 3 + t] = sz * inv;
  }
}

// ---- fused emb_in GEMM + layer-0 P/Q + zero agg/xacc slices (1-wave blocks, 1000)
__global__ __launch_bounds__(64) void gemm_pq_kernel(
    const float* __restrict__ A,
    const ushortT* __restrict__ Wt, const float* __restrict__ bias,
    float* __restrict__ Cf,
    const ushortT* __restrict__ Wa, const ushortT* __restrict__ Wb,
    const float* __restrict__ b1p,
    ushortT* __restrict__ Pbf, ushortT* __restrict__ Qbf,
    float* __restrict__ agg, float* __restrict__ xacc){
  __shared__ __align__(16) ushortT T1[2048];
  int lane = threadIdx.x;
  int l15 = lane & 15, lg = lane >> 4;
  int base = blockIdx.x * 16;
  int row = base + l15;
  {
    float4 z4 = {0.f, 0.f, 0.f, 0.f};
    float4* aggp = reinterpret_cast<float4*>(agg + (size_t)blockIdx.x * 16 * HS);
#pragma unroll
    for (int i = 0; i < 8; i++) aggp[lane + 64 * i] = z4;
    if (lane < 48) xacc[blockIdx.x * 48 + lane] = 0.f;
  }
  f32x4 zero = {0.f, 0.f, 0.f, 0.f};
  f32x4 acc[8];
#pragma unroll
  for (int n = 0; n < 8; n++) acc[n] = zero;
#pragma unroll
  for (int ks = 0; ks < 4; ks++){
    int k0 = ks * 32 + lg * 8;
    bf16x8 af = load8f_bf(A + (size_t)row * HS + k0);
#pragma unroll
    for (int n = 0; n < 8; n++){
      bf16x8 bf = load8bf(Wt + (size_t)(16 * n + l15) * HS + k0);
      acc[n] = __builtin_amdgcn_mfma_f32_16x16x32_bf16(af, bf, acc[n], 0, 0, 0);
    }
  }
#pragma unroll
  for (int n = 0; n < 8; n++){
    int col = 16 * n + l15;
    float bv = bias[col];
#pragma unroll
    for (int r = 0; r < 4; r++){
      int ro = base + lg * 4 + r;
      int er = lg * 4 + r;
      float hv = acc[n][r] + bv;
      Cf[(size_t)ro * HS + col] = hv;
      T1[(er * 128 + col) ^ ((er & 7) << 3)] = f2bff(hv);
    }
  }
  f32x4 accp[8], accq[8];
#pragma unroll
  for (int n = 0; n < 8; n++){ accp[n] = zero; accq[n] = zero; }
#pragma unroll
  for (int ks = 0; ks < 4; ks++){
    int k0 = ks * 32 + lg * 8;
    bf16x8 af = load8bf(&T1[(l15 * 128 + k0) ^ ((l15 & 7) << 3)]);
#pragma unroll
    for (int n = 0; n < 8; n++){
      accp[n] = __builtin_amdgcn_mfma_f32_16x16x32_bf16(af, load8bf(Wa + (size_t)(16 * n + l15) * HS + k0), accp[n], 0, 0, 0);
      accq[n] = __builtin_amdgcn_mfma_f32_16x16x32_bf16(af, load8bf(Wb + (size_t)(16 * n + l15) * HS + k0), accq[n], 0, 0, 0);
    }
  }
#pragma unroll
  for (int n = 0; n < 8; n++){
    int col = 16 * n + l15;
    float bv = b1p[col];
#pragma unroll
    for (int r = 0; r < 4; r++){
      int ro = base + lg * 4 + r;
      Pbf[(size_t)ro * HS + col] = f2bff(accp[n][r] + bv);
      Qbf[(size_t)ro * HS + col] = f2bff(accq[n][r]);
    }
  }
}

// ---- fused node MLP + x_update + zero-next + next-layer P/Q (1-wave blocks, 1000)
__global__ __launch_bounds__(64) void node_pq_kernel(
    float* __restrict__ h, float* __restrict__ agg,
    const ushortT* __restrict__ W1t, const ushortT* __restrict__ W2t,
    const float* __restrict__ b1, const float* __restrict__ b2,
    const ushortT* __restrict__ Wa, const ushortT* __restrict__ Wb,
    const float* __restrict__ b1p,
    ushortT* __restrict__ Pbf, ushortT* __restrict__ Qbf,
    float* __restrict__ x, float* __restrict__ xacc, const int* __restrict__ estart){
  __shared__ __align__(16) ushortT T1[2048];
  int lane = threadIdx.x;
  int l15 = lane & 15, lg = lane >> 4;
  int base = blockIdx.x * 16;
  int row = base + l15;
  f32x4 zero = {0.f, 0.f, 0.f, 0.f};

  if (lane < 48){
    int i = blockIdx.x * 48 + lane;
    int b = i / 3;
    int cnt = estart[b + 1] - estart[b];
    x[i] += xacc[i] / (float)(cnt > 0 ? cnt : 1);
    xacc[i] = 0.f;
  }

  f32x4 acc[8];
#pragma unroll
  for (int n = 0; n < 8; n++) acc[n] = zero;
#pragma unroll
  for (int ks = 0; ks < 8; ks++){
    int k0 = ks * 32 + lg * 8;
    bf16x8 af = (k0 < 128) ? load8f_bf(h + (size_t)row * HS + k0)
                           : load8f_bf(agg + (size_t)row * HS + (k0 - 128));
#pragma unroll
    for (int n = 0; n < 8; n++){
      acc[n] = __builtin_amdgcn_mfma_f32_16x16x32_bf16(af, load8bf(W1t + (size_t)(16 * n + l15) * 256 + k0), acc[n], 0, 0, 0);
    }
  }
  // drain agg reads then zero this block's agg slice
  __syncthreads();
  {
    float4 z4 = {0.f, 0.f, 0.f, 0.f};
    float4* aggp = reinterpret_cast<float4*>(agg + (size_t)blockIdx.x * 16 * HS);
#pragma unroll
    for (int i = 0; i < 8; i++) aggp[lane + 64 * i] = z4;
  }
#pragma unroll
  for (int n = 0; n < 8; n++){
    int col = 16 * n + l15;
    float bv = b1[col];
#pragma unroll
    for (int r = 0; r < 4; r++){
      int er = lg * 4 + r;
      T1[(er * 128 + col) ^ ((er & 7) << 3)] = f2bff(silu(acc[n][r] + bv));
    }
  }
#pragma unroll
  for (int n = 0; n < 8; n++) acc[n] = zero;
#pragma unroll
  for (int ks = 0; ks < 4; ks++){
    int k0 = ks * 32 + lg * 8;
    bf16x8 af = load8bf(&T1[(l15 * 128 + k0) ^ ((l15 & 7) << 3)]);
#pragma unroll
    for (int n = 0; n < 8; n++){
      acc[n] = __builtin_amdgcn_mfma_f32_16x16x32_bf16(af, load8bf(W2t + (size_t)(16 * n + l15) * HS + k0), acc[n], 0, 0, 0);
    }
  }
#pragma unroll
  for (int n = 0; n < 8; n++){
    int col = 16 * n + l15;
    float bv = b2[col];
#pragma unroll
    for (int r = 0; r < 4; r++){
      int ro = base + lg * 4 + r;
      int er = lg * 4 + r;
      float hv = h[(size_t)ro * HS + col] + acc[n][r] + bv;
      h[(size_t)ro * HS + col] = hv;
      T1[(er * 128 + col) ^ ((er & 7) << 3)] = f2bff(hv);
    }
  }
  // next-layer P/Q from T1
  f32x4 accp[8], accq[8];
#pragma unroll
  for (int n = 0; n < 8; n++){ accp[n] = zero; accq[n] = zero; }
#pragma unroll
  for (int ks = 0; ks < 4; ks++){
    int k0 = ks * 32 + lg * 8;
    bf16x8 af = load8bf(&T1[(l15 * 128 + k0) ^ ((l15 & 7) << 3)]);
#pragma unroll
    for (int n = 0; n < 8; n++){
      accp[n] = __builtin_amdgcn_mfma_f32_16x16x32_bf16(af, load8bf(Wa + (size_t)(16 * n + l15) * HS + k0), accp[n], 0, 0, 0);
      accq[n] = __builtin_amdgcn_mfma_f32_16x16x32_bf16(af, load8bf(Wb + (size_t)(16 * n + l15) * HS + k0), accq[n], 0, 0, 0);
    }
  }
#pragma unroll
  for (int n = 0; n < 8; n++){
    int col = 16 * n + l15;
    float bv = b1p[col];
#pragma unroll
    for (int r = 0; r < 4; r++){
      int ro = base + lg * 4 + r;
      Pbf[(size_t)ro * HS + col] = f2bff(accp[n][r] + bv);
      Qbf[(size_t)ro * HS + col] = f2bff(accq[n][r]);
    }
  }
}

// ---- fused final node MLP + emb_out GEMM + normalize + graph accumulate (1-wave, 1000)
__global__ __launch_bounds__(64) void node_emb_kernel(
    const float* __restrict__ h, const float* __restrict__ agg,
    const ushortT* __restrict__ W1t, const ushortT* __restrict__ W2t,
    const float* __restrict__ b1, const float* __restrict__ b2,
    const ushortT* __restrict__ Eoutt, const float* __restrict__ eob,
    const int* __restrict__ batch_id,
    float* __restrict__ brep, float* __restrict__ gsum){
  __shared__ __align__(16) ushortT T1[2048];
  int lane = threadIdx.x;
  int l15 = lane & 15, lg = lane >> 4;
  int base = blockIdx.x * 16;
  int row = base + l15;
  f32x4 zero = {0.f, 0.f, 0.f, 0.f};

  f32x4 acc[8];
#pragma unroll
  for (int n = 0; n < 8; n++) acc[n] = zero;
#pragma unroll
  for (int ks = 0; ks < 8; ks++){
    int k0 = ks * 32 + lg * 8;
    bf16x8 af = (k0 < 128) ? load8f_bf(h + (size_t)row * HS + k0)
                           : load8f_bf(agg + (size_t)row * HS + (k0 - 128));
#pragma unroll
    for (int n = 0; n < 8; n++){
      acc[n] = __builtin_amdgcn_mfma_f32_16x16x32_bf16(af, load8bf(W1t + (size_t)(16 * n + l15) * 256 + k0), acc[n], 0, 0, 0);
    }
  }
#pragma unroll
  for (int n = 0; n < 8; n++){
    int col = 16 * n + l15;
    float bv = b1[col];
#pragma unroll
    for (int r = 0; r < 4; r++){
      int er = lg * 4 + r;
      T1[(er * 128 + col) ^ ((er & 7) << 3)] = f2bff(silu(acc[n][r] + bv));
    }
  }
#pragma unroll
  for (int n = 0; n < 8; n++) acc[n] = zero;
#pragma unroll
  for (int ks = 0; ks < 4; ks++){
    int k0 = ks * 32 + lg * 8;
    bf16x8 af = load8bf(&T1[(l15 * 128 + k0) ^ ((l15 & 7) << 3)]);
#pragma unroll
    for (int n = 0; n < 8; n++){
      acc[n] = __builtin_amdgcn_mfma_f32_16x16x32_bf16(af, load8bf(W2t + (size_t)(16 * n + l15) * HS + k0), acc[n], 0, 0, 0);
    }
  }
  // h_final = h + acc + b2 -> T1 (bf16)
#pragma unroll
  for (int n = 0; n < 8; n++){
    int col = 16 * n + l15;
    float bv = b2[col];
#pragma unroll
    for (int r = 0; r < 4; r++){
      int ro = base + lg * 4 + r;
      int er = lg * 4 + r;
      float hv = h[(size_t)ro * HS + col] + acc[n][r] + bv;
      T1[(er * 128 + col) ^ ((er & 7) << 3)] = f2bff(hv);
    }
  }
  // emb_out GEMM from T1
#pragma unroll
  for (int n = 0; n < 8; n++) acc[n] = zero;
#pragma unroll
  for (int ks = 0; ks < 4; ks++){
    int k0 = ks * 32 + lg * 8;
    bf16x8 af = load8bf(&T1[(l15 * 128 + k0) ^ ((l15 & 7) << 3)]);
#pragma unroll
    for (int n = 0; n < 8; n++){
      acc[n] = __builtin_amdgcn_mfma_f32_16x16x32_bf16(af, load8bf(Eoutt + (size_t)(16 * n + l15) * HS + k0), acc[n], 0, 0, 0);
    }
  }
#pragma unroll
  for (int n = 0; n < 8; n++){
    float bv = eob[16 * n + l15];
#pragma unroll
    for (int r = 0; r < 4; r++) acc[n][r] += bv;
  }
  float scl[4];
#pragma unroll
  for (int r = 0; r < 4; r++){
    float ss = 0.f;
#pragma unroll
    for (int n = 0; n < 8; n++) ss += acc[n][r] * acc[n][r];
#pragma unroll
    for (int o = 1; o < 16; o <<= 1) ss += __shfl_xor(ss, o, 64);
    scl[r] = 1.f / fmaxf(sqrtf(ss), 1e-12f);
  }
#pragma unroll
  for (int r = 0; r < 4; r++){
    int ro = base + lg * 4 + r;
    int g = batch_id[ro];
#pragma unroll
    for (int n = 0; n < 8; n++){
      int col = 16 * n + l15;
      float v = acc[n][r] * scl[r];
      brep[(size_t)ro * HS + col] = v;
      atomicAdd(&gsum[g * HS + col], v);
    }
  }
}

// ---- fused edge kernel v10: 8-wave WG (512 thr), 128 edges, 1 chan-group per wave.
// Per-edge weight vmem halves vs 4-wave split; same per-wave register footprint.
template<int COORD>
__global__ __launch_bounds__(512, 2) void edge_kernel(
    const int* __restrict__ srow, const int* __restrict__ scol,
    const ushortT* __restrict__ sattr,
    const float* __restrict__ x,
    const ushortT* __restrict__ Pbf, const ushortT* __restrict__ Qbf,
    const ushortT* __restrict__ W1ct, const ushortT* __restrict__ W2tp,
    const ushortT* __restrict__ CW1tp,
    const float* __restrict__ b2, const float* __restrict__ cb1,
    const float* __restrict__ cw3,
    float* __restrict__ xacc, float* __restrict__ agg){
  __shared__ float bias_l[3][128];
  __shared__ int   rid_s[128];
  __shared__ float dif_s[COORD ? 128 : 1][3];
  __shared__ float wall[COORD ? 8 : 1][COORD ? 128 : 1];
  __shared__ __align__(16) ushortT S1[128 * 128];   // m1, pi-order, swizzled (32 KB)
  __shared__ __align__(16) ushortT S2[128 * 128];   // m,  pi-order, swizzled (32 KB)

  const int t = threadIdx.x;
  const int lane = t & 63;
  const int wv = t >> 6;                    // 0..7 = chan group
  const int l15 = lane & 15, lg = lane >> 4;
  const f32x4 zero = {0.f, 0.f, 0.f, 0.f};

  if (t < 128){
    bias_l[0][t] = b2[t];
    if (COORD){ bias_l[1][t] = cb1[t]; bias_l[2][t] = cw3[t]; }
  }

  // ---------- phase A: m1 for this wave's 16 edges ----------
  const int erow = wv * 16 + l15;           // 0..127
  const int e = blockIdx.x * 128 + erow;
  const int r = srow[e], c = scol[e];
  const float dx = x[r * 3 + 0] - x[c * 3 + 0];
  const float dy = x[r * 3 + 1] - x[c * 3 + 1];
  const float dz = x[r * 3 + 2] - x[c * 3 + 2];
  const float rad = dx * dx + dy * dy + dz * dz;
  if (lg == 0){
    rid_s[erow] = r;
    if (COORD){ dif_s[erow][0] = dx; dif_s[erow][1] = dy; dif_s[erow][2] = dz; }
  }
  ushort8 at8 = __builtin_bit_cast(ushort8, load8bf(sattr + (size_t)e * 32 + lg * 8));
  if (lg == 0) at8[0] = f2bff(rad);
  const bf16x8 atb = __builtin_bit_cast(bf16x8, at8);

#pragma unroll
  for (int ks = 0; ks < 4; ks++){
    f32x4 a0 = __builtin_amdgcn_mfma_f32_16x16x32_bf16(
        load8bf(W1ct + (size_t)(16 * (2 * ks)     + l15) * 32 + lg * 8), atb, zero, 0, 0, 0);
    f32x4 a1 = __builtin_amdgcn_mfma_f32_16x16x32_bf16(
        load8bf(W1ct + (size_t)(16 * (2 * ks + 1) + l15) * 32 + lg * 8), atb, zero, 0, 0, 0);
    ushort8 pv = __builtin_bit_cast(ushort8, load8bf(Pbf + (size_t)r * HS + ks * 32 + lg * 8));
    ushort8 qv = __builtin_bit_cast(ushort8, load8bf(Qbf + (size_t)c * HS + ks * 32 + lg * 8));
    ushort8 af;
#pragma unroll
    for (int j = 0; j < 4; j++)
      af[j] = f2bff(silu(a0[j] + bf2f(pv[j]) + bf2f(qv[j])));
#pragma unroll
    for (int j = 4; j < 8; j++)
      af[j] = f2bff(silu(a1[j - 4] + bf2f(pv[j]) + bf2f(qv[j])));
    int byte = (erow * 256 + ks * 64 + lg * 16) ^ ((erow & 7) << 4);
    *reinterpret_cast<uint4*>(reinterpret_cast<char*>(S1) + byte) = __builtin_bit_cast(uint4, af);
  }
  __syncthreads();   // bar1: S1 + rid + dif + biases ready

  // ---------- phase B: GEMM2, group wv for ALL 128 edges (8 et-tiles) ----------
  f32x4 acc2[8];
#pragma unroll
  for (int et = 0; et < 8; et++) acc2[et] = zero;
#pragma unroll
  for (int ks = 0; ks < 4; ks++){
    bf16x8 wf = load8bf(W2tp + (size_t)(16 * wv + l15) * HS + ks * 32 + lg * 8);
#pragma unroll
    for (int et = 0; et < 8; et++){
      int row2 = et * 16 + l15;
      int byte = (row2 * 256 + ks * 64 + lg * 16) ^ ((row2 & 7) << 4);
      bf16x8 mb = __builtin_bit_cast(bf16x8,
          *reinterpret_cast<const uint4*>(reinterpret_cast<const char*>(S1) + byte));
      acc2[et] = __builtin_amdgcn_mfma_f32_16x16x32_bf16(wf, mb, acc2[et], 0, 0, 0);
    }
  }
  // m-epilogue: silu + b2 -> S2 at pi positions for group wv (uint2 per et)
  {
    float4 bv = *reinterpret_cast<const float4*>(&bias_l[0][16 * wv + lg * 4]);
    int pbyte = ((wv >> 1) * 32 + lg * 8 + (wv & 1) * 4) * 2;
#pragma unroll
    for (int et = 0; et < 8; et++){
      ushortT mm[4];
#pragma unroll
      for (int rr = 0; rr < 4; rr++)
        mm[rr] = f2bff(silu(acc2[et][rr] + (&bv.x)[rr]));
      int row2 = et * 16 + l15;
      int byte = (row2 * 256 + pbyte) ^ ((row2 & 7) << 4);
      *reinterpret_cast<uint2*>(reinterpret_cast<char*>(S2) + byte) =
          *reinterpret_cast<uint2*>(mm);
    }
  }
  __syncthreads();   // bar2: S2 ready

  if (COORD){
    // ---------- phase C: coord GEMM, group wv for ALL 128 edges ----------
    f32x4 acc3[8];
#pragma unroll
    for (int et = 0; et < 8; et++) acc3[et] = zero;
#pragma unroll
    for (int ks = 0; ks < 4; ks++){
      bf16x8 wf = load8bf(CW1tp + (size_t)(16 * wv + l15) * HS + ks * 32 + lg * 8);
#pragma unroll
      for (int et = 0; et < 8; et++){
        int row2 = et * 16 + l15;
        int byte = (row2 * 256 + ks * 64 + lg * 16) ^ ((row2 & 7) << 4);
        bf16x8 mb = __builtin_bit_cast(bf16x8,
            *reinterpret_cast<const uint4*>(reinterpret_cast<const char*>(S2) + byte));
        acc3[et] = __builtin_amdgcn_mfma_f32_16x16x32_bf16(wf, mb, acc3[et], 0, 0, 0);
      }
    }
    // per-wave partial w (16 chans of group wv) -> wall
    {
      float4 cbv = *reinterpret_cast<const float4*>(&bias_l[1][16 * wv + lg * 4]);
      float4 cwv = *reinterpret_cast<const float4*>(&bias_l[2][16 * wv + lg * 4]);
#pragma unroll
      for (int et = 0; et < 8; et++){
        float ws = 0.f;
#pragma unroll
        for (int rr = 0; rr < 4; rr++)
          ws += silu(acc3[et][rr] + (&cbv.x)[rr]) * (&cwv.x)[rr];
        ws += __shfl_xor(ws, 16, 64);
        ws += __shfl_xor(ws, 32, 64);
        if (lg == 0) wall[wv][et * 16 + l15] = ws;
      }
    }
  }

  // ---------- agg flush: this wave's own 16 edges, full chans from S2 (b32 pairs) ----------
  {
    const int c0 = c_of_p(2 * lane), c1 = c_of_p(2 * lane + 1);
    float run0 = 0.f, run1 = 0.f;
    int prev = __builtin_amdgcn_readfirstlane(rid_s[wv * 16]);
#pragma unroll
    for (int e2 = 0; e2 < 16; e2++){
      int re = __builtin_amdgcn_readfirstlane(rid_s[wv * 16 + e2]);
      if (re != prev){
        atomicAdd(&agg[(size_t)prev * HS + c0], run0);
        atomicAdd(&agg[(size_t)prev * HS + c1], run1);
        run0 = 0.f; run1 = 0.f; prev = re;
      }
      int row2 = wv * 16 + e2;
      int byte = (row2 * 256 + lane * 4) ^ ((row2 & 7) << 4);
      uint u = *reinterpret_cast<const uint*>(reinterpret_cast<const char*>(S2) + byte);
      run0 += bf2f((ushortT)(u & 0xFFFF));
      run1 += bf2f((ushortT)(u >> 16));
    }
    atomicAdd(&agg[(size_t)prev * HS + c0], run0);
    atomicAdd(&agg[(size_t)prev * HS + c1], run1);
  }

  if (COORD){
    __syncthreads();   // bar3: wall complete
    // xacc: parallel scatter, per-WG summed w, one atomic per (edge,coord)
    if (t < 384){
      int e2 = t / 3, cd = t % 3;
      float w = 0.f;
#pragma unroll
      for (int wv2 = 0; wv2 < 8; wv2++) w += wall[wv2][e2];
      atomicAdd(&xacc[(size_t)rid_s[e2] * 3 + cd], dif_s[e2][cd] * w);
    }
  }
}

__global__ void norm_graph_kernel(const float* __restrict__ gsum, float* __restrict__ grep){
  int wv = threadIdx.x >> 6, lane = threadIdx.x & 63;
  int g = blockIdx.x * 4 + wv;
  if (g >= N_GRAPHS) return;
  float v0 = gsum[g * HS + lane];
  float v1 = gsum[g * HS + 64 + lane];
  float ss = v0 * v0 + v1 * v1;
#pragma unroll
  for (int o = 1; o < 64; o <<= 1) ss += __shfl_xor(ss, o, 64);
  float s = 1.f / fmaxf(sqrtf(ss), 1e-12f);
  grep[(size_t)g * HS + lane] = v0 * s;
  grep[(size_t)g * HS + 64 + lane] = v1 * s;
}

extern "C" void kernel_launch(void* const* d_in, const int* in_sizes, int n_in,
                              void* d_out, int out_size, void* d_ws, size_t ws_size,
                              hipStream_t stream){
  const float* H         = (const float*)d_in[0];
  const float* Z         = (const float*)d_in[1];
  const int*   block_id  = (const int*)d_in[2];
  const int*   batch_id  = (const int*)d_in[3];
  const int*   edges     = (const int*)d_in[4];
  const float* edge_attr = (const float*)d_in[5];
  const float* emb_in_w  = (const float*)d_in[6];
  const float* emb_in_b  = (const float*)d_in[7];
  const float* emb_out_w = (const float*)d_in[8];
  const float* emb_out_b = (const float*)d_in[9];
  const float* edge_w1   = (const float*)d_in[10];
  const float* edge_b1   = (const float*)d_in[11];
  const float* edge_w2   = (const float*)d_in[12];
  const float* edge_b2   = (const float*)d_in[13];
  const float* node_w1   = (const float*)d_in[14];
  const float* node_b1   = (const float*)d_in[15];
  const float* node_w2   = (const float*)d_in[16];
  const float* node_b2   = (const float*)d_in[17];
  const float* coord_w1  = (const float*)d_in[18];
  const float* coord_b1  = (const float*)d_in[19];
  const float* coord_w3  = (const float*)d_in[20];

  float* out  = (float*)d_out;
  float* Hm   = out;                               // [16000 x 128]
  float* brep = out + (size_t)N_BLOCKS * HS;       // [16000 x 128]
  float* grep = out + (size_t)2 * N_BLOCKS * HS;   // [128 x 128]

  char* base = (char*)d_ws;
  size_t off = 0;
  auto take = [&](size_t bytes) -> char* {
    char* p = base + off;
    off += (bytes + 255) & ~(size_t)255;
    return p;
  };
  float*   x     = (float*)  take((size_t)N_BLOCKS * 3 * 4);
  float*   xacc  = (float*)  take((size_t)N_BLOCKS * 3 * 4);
  float*   h     = (float*)  take((size_t)N_BLOCKS * HS * 4);
  float*   agg   = (float*)  take((size_t)N_BLOCKS * HS * 4);
  float*   gsum  = (float*)  take((size_t)N_GRAPHS * HS * 4);
  int*     bstart= (int*)    take((size_t)(N_BLOCKS + 1) * 4);
  int*     hist  = (int*)    take((size_t)N_BLOCKS * 4);
  int*     estart= (int*)    take((size_t)(N_BLOCKS + 1) * 4);
  int*     ecur  = (int*)    take((size_t)N_BLOCKS * 4);
  int*     srow  = (int*)    take((size_t)N_EDGES * 4);
  int*     scol  = (int*)    take((size_t)N_EDGES * 4);
  ushortT* sattr = (ushortT*)take((size_t)N_EDGES * 32 * 2);
  ushortT* Pbf   = (ushortT*)take((size_t)N_BLOCKS * HS * 2);
  ushortT* Qbf   = (ushortT*)take((size_t)N_BLOCKS * HS * 2);
  ushortT* W1atp = (ushortT*)take((size_t)3 * 128 * 128 * 2);
  ushortT* W1btp = (ushortT*)take((size_t)3 * 128 * 128 * 2);
  ushortT* W1ct  = (ushortT*)take((size_t)3 * 128 * 32 * 2);
  ushortT* W2tp  = (ushortT*)take((size_t)3 * 128 * 128 * 2);
  ushortT* CW1tp = (ushortT*)take((size_t)3 * 128 * 128 * 2);
  ushortT* NW1t  = (ushortT*)take((size_t)3 * 128 * 256 * 2);
  ushortT* NW2t  = (ushortT*)take((size_t)3 * 128 * 128 * 2);
  ushortT* Eint  = (ushortT*)take((size_t)128 * 128 * 2);
  ushortT* Eoutt = (ushortT*)take((size_t)128 * 128 * 2);
  float*   b1p   = (float*)  take((size_t)3 * 128 * 4);

  // merged prep (weights + bias perm + hist zero)
  PrepParams P;
  P.ew1 = edge_w1; P.ew2 = edge_w2; P.cw1 = coord_w1;
  P.nw1 = node_w1; P.nw2 = node_w2; P.ei = emb_in_w; P.eo = emb_out_w;
  P.eb1 = edge_b1;
  P.W1atp = W1atp; P.W1btp = W1btp; P.W1ct = W1ct; P.W2tp = W2tp; P.CW1tp = CW1tp;
  P.NW1t = NW1t; P.NW2t = NW2t; P.Eint = Eint; P.Eoutt = Eoutt;
  P.b1p = b1p; P.hist = hist;
  prep_kernel<<<(PREP_TOTAL + 255) / 256, 256, 0, stream>>>(P);

  hist_bstart_kernel<<<N_EDGES / 256 + (N_BLOCKS + 1 + 255) / 256, 256, 0, stream>>>(
      edges, hist, block_id, bstart);
  scan_kernel<<<1, 1024, 0, stream>>>(hist, estart, ecur);
  scatter_kernel<<<N_EDGES / 256, 256, 0, stream>>>(edges, edge_attr, ecur, srow, scol, sattr);
  pool_kernel<<<N_BLOCKS, 128, 0, stream>>>(H, Z, bstart, Hm, x, gsum);

  // h = Hm @ emb_in_w + b ; P/Q layer 0 ; zero agg/xacc
  gemm_pq_kernel<<<N_BLOCKS / 16, 64, 0, stream>>>(Hm, Eint, emb_in_b, h,
                                                   W1atp, W1btp, b1p, Pbf, Qbf, agg, xacc);

  for (int l = 0; l < 3; l++){
    if (l < 2){
      edge_kernel<1><<<N_EDGES / 128, 512, 0, stream>>>(
          srow, scol, sattr, x, Pbf, Qbf,
          W1ct + (size_t)l * 128 * 32, W2tp + (size_t)l * 128 * 128, CW1tp + (size_t)l * 128 * 128,
          edge_b2 + l * 128, coord_b1 + l * 128, coord_w3 + l * 128,
          xacc, agg);
      node_pq_kernel<<<N_BLOCKS / 16, 64, 0, stream>>>(
          h, agg, NW1t + (size_t)l * 128 * 256, NW2t + (size_t)l * 128 * 128,
          node_b1 + l * 128, node_b2 + l * 128,
          W1atp + (size_t)(l + 1) * 128 * 128, W1btp + (size_t)(l + 1) * 128 * 128,
          b1p + (l + 1) * 128, Pbf, Qbf, x, xacc, estart);
    } else {
      edge_kernel<0><<<N_EDGES / 128, 512, 0, stream>>>(
          srow, scol, sattr, x, Pbf, Qbf,
          W1ct + (size_t)l * 128 * 32, W2tp + (size_t)l * 128 * 128, CW1tp + (size_t)l * 128 * 128,
          edge_b2 + l * 128, coord_b1 + l * 128, coord_w3 + l * 128,
          xacc, agg);
      node_emb_kernel<<<N_BLOCKS / 16, 64, 0, stream>>>(
          h, agg, NW1t + (size_t)l * 128 * 256, NW2t + (size_t)l * 128 * 128,
          node_b1 + l * 128, node_b2 + l * 128,
          Eoutt, emb_out_b, batch_id, brep, gsum);
    }
  }

  norm_graph_kernel<<<N_GRAPHS / 4, 256, 0, stream>>>(gsum, grep);
}

// Round 15
// 490.092 us; speedup vs baseline: 1.1060x; 1.0304x over previous
//
#include <hip/hip_runtime.h>

#define N_ATOMS  80000
#define N_BLOCKS 16000
#define N_EDGES  320000
#define N_GRAPHS 128
#define HS       128

typedef unsigned short ushortT;
typedef __attribute__((ext_vector_type(8))) __bf16 bf16x8;
typedef __attribute__((ext_vector_type(8))) unsigned short ushort8;
typedef __attribute__((ext_vector_type(4))) float f32x4;

__device__ __forceinline__ unsigned short f2bf(float f){
  unsigned int u = __builtin_bit_cast(unsigned int, f);
  u = (u + 0x7FFFu + ((u >> 16) & 1u)) >> 16;
  return (unsigned short)u;
}
__device__ __forceinline__ ushortT f2bff(float f){
  __bf16 b = (__bf16)f;
  return __builtin_bit_cast(ushortT, b);
}
__device__ __forceinline__ float bf2f(ushortT u){
  unsigned int v = ((unsigned int)u) << 16;
  return __builtin_bit_cast(float, v);
}
__device__ __forceinline__ bf16x8 load8bf(const ushortT* p){
  uint4 u = *reinterpret_cast<const uint4*>(p);
  return __builtin_bit_cast(bf16x8, u);
}
__device__ __forceinline__ bf16x8 load8f_bf(const float* p){
  float4 a = *reinterpret_cast<const float4*>(p);
  float4 b = *reinterpret_cast<const float4*>(p + 4);
  ushort8 u = { f2bff(a.x), f2bff(a.y), f2bff(a.z), f2bff(a.w),
                f2bff(b.x), f2bff(b.y), f2bff(b.z), f2bff(b.w) };
  return __builtin_bit_cast(bf16x8, u);
}
// fast silu: v * rcp(1+exp(-v))
__device__ __forceinline__ float silu(float v){
  return v * __builtin_amdgcn_rcpf(1.f + __expf(-v));
}

// pi-permutation: C-fragment register (n,r) of lane-group lg holds natural col
// c = 16n + lg*4 + r; B-fragment position p = ks*32 + lg*8 + j, n = 2ks + (j>>2), r = j&3.
__device__ __forceinline__ int c_of_p(int p){
  int ks = p >> 5, lg = (p >> 3) & 3, j = p & 7;
  return 16 * (ks * 2 + (j >> 2)) + lg * 4 + (j & 3);
}

// ---- merged prep: all weight transposes + bias perm + hist zero
struct PrepParams {
  const float* ew1; const float* ew2; const float* cw1;
  const float* nw1; const float* nw2; const float* ei; const float* eo;
  const float* eb1;
  ushortT* W1atp; ushortT* W1btp; ushortT* W1ct; ushortT* W2tp; ushortT* CW1tp;
  ushortT* NW1t; ushortT* NW2t; ushortT* Eint; ushortT* Eoutt;
  float* b1p; int* hist;
};

__device__ __forceinline__ void tcvt(int idx, const float* __restrict__ src,
                                     ushortT* __restrict__ dst,
                                     int srcK, int row_off, int K, int N, int Kpad,
                                     int pn, int pk){
  int k = idx % Kpad;
  int rem = idx / Kpad;
  int n = rem % N;
  int l = rem / N;
  float v = 0.f;
  if (k < K){
    int kk = pk ? c_of_p(k) : k;
    int nn = pn ? c_of_p(n) : n;
    v = src[((size_t)l * srcK + row_off + kk) * N + nn];
  }
  dst[idx] = f2bf(v);
}

#define PREP_TOTAL (49152*5 + 12288 + 98304 + 16384*2 + 16000 + 384)

__global__ void prep_kernel(PrepParams P){
  int idx = blockIdx.x * 256 + threadIdx.x;
  if (idx < 49152){ tcvt(idx, P.ew1, P.W1atp, 273,   0, 128, 128, 128, 1, 0); return; }
  idx -= 49152;
  if (idx < 49152){ tcvt(idx, P.ew1, P.W1btp, 273, 128, 128, 128, 128, 1, 0); return; }
  idx -= 49152;
  if (idx < 12288){ tcvt(idx, P.ew1, P.W1ct,  273, 256,  17, 128,  32, 0, 0); return; }
  idx -= 12288;
  if (idx < 49152){ tcvt(idx, P.ew2, P.W2tp,  128,   0, 128, 128, 128, 0, 1); return; }
  idx -= 49152;
  if (idx < 49152){ tcvt(idx, P.cw1, P.CW1tp, 128,   0, 128, 128, 128, 0, 1); return; }
  idx -= 49152;
  if (idx < 98304){ tcvt(idx, P.nw1, P.NW1t,  256,   0, 256, 128, 256, 0, 0); return; }
  idx -= 98304;
  if (idx < 49152){ tcvt(idx, P.nw2, P.NW2t,  128,   0, 128, 128, 128, 0, 0); return; }
  idx -= 49152;
  if (idx < 16384){ tcvt(idx, P.ei,  P.Eint,  128,   0, 128, 128, 128, 0, 0); return; }
  idx -= 16384;
  if (idx < 16384){ tcvt(idx, P.eo,  P.Eoutt, 128,   0, 128, 128, 128, 0, 0); return; }
  idx -= 16384;
  if (idx < 16000){ P.hist[idx] = 0; return; }
  idx -= 16000;
  if (idx < 384){ int l = idx >> 7, p = idx & 127; P.b1p[idx] = P.eb1[l * 128 + c_of_p(p)]; }
}

// ---- hist + block_start merged
__global__ void hist_bstart_kernel(const int* __restrict__ edges, int* __restrict__ hist,
                                   const int* __restrict__ bid, int* __restrict__ bstart){
  int b = blockIdx.x;
  if (b < N_EDGES / 256){
    int e = b * 256 + threadIdx.x;
    atomicAdd(&hist[edges[e]], 1);
  } else {
    int i = (b - N_EDGES / 256) * 256 + threadIdx.x;
    if (i <= N_BLOCKS){
      int lo = 0, hi = N_ATOMS;
      while (lo < hi){ int mid = (lo + hi) >> 1; if (bid[mid] < i) lo = mid + 1; else hi = mid; }
      bstart[i] = lo;
    }
  }
}

__global__ __launch_bounds__(1024) void scan_kernel(const int* __restrict__ hist,
                                                    int* __restrict__ estart,
                                                    int* __restrict__ ecur){
  __shared__ int ps[1024];
  int t = threadIdx.x;
  const int chunk = (N_BLOCKS + 1023) / 1024;
  int lo = t * chunk, hi = lo + chunk;
  if (hi > N_BLOCKS) hi = N_BLOCKS;
  if (lo > N_BLOCKS) lo = N_BLOCKS;
  int s = 0;
  for (int i = lo; i < hi; i++) s += hist[i];
  ps[t] = s;
  __syncthreads();
  for (int off = 1; off < 1024; off <<= 1){
    int v = (t >= off) ? ps[t - off] : 0;
    __syncthreads();
    ps[t] += v;
    __syncthreads();
  }
  int base = (t == 0) ? 0 : ps[t - 1];
  for (int i = lo; i < hi; i++){ estart[i] = base; ecur[i] = base; base += hist[i]; }
  if (t == 1023) estart[N_BLOCKS] = base;
}

// scatter into sorted order; sattr padded: 32 u16/edge = [0, attr0..15, 0 x15]
__global__ void scatter_kernel(const int* __restrict__ edges, const float* __restrict__ attr,
                               int* __restrict__ ecur,
                               int* __restrict__ srow, int* __restrict__ scol,
                               ushortT* __restrict__ sattr){
  int e = blockIdx.x * 256 + threadIdx.x;
  if (e >= N_EDGES) return;
  int r = edges[e], c = edges[N_EDGES + e];
  int p = atomicAdd(&ecur[r], 1);
  srow[p] = r; scol[p] = c;
  ushortT buf[32];
  buf[0] = 0;
#pragma unroll
  for (int k = 0; k < 16; k++) buf[k + 1] = f2bf(attr[(size_t)e * 16 + k]);
#pragma unroll
  for (int k = 17; k < 32; k++) buf[k] = 0;
#pragma unroll
  for (int k = 0; k < 16; k++)
    reinterpret_cast<uint*>(sattr + (size_t)p * 32)[k] = reinterpret_cast<uint*>(buf)[k];
}

__global__ void pool_kernel(const float* __restrict__ H, const float* __restrict__ Z,
                            const int* __restrict__ start,
                            float* __restrict__ Hm, float* __restrict__ x,
                            float* __restrict__ gsum){
  int b = blockIdx.x;
  int t = threadIdx.x;            // 128 threads
  if (b < 128) gsum[b * 128 + t] = 0.f;
  int s = start[b], e = start[b + 1];
  float inv = 1.f / (float)((e - s) > 0 ? (e - s) : 1);
  float sum = 0.f;
  for (int a = s; a < e; a++) sum += H[(size_t)a * HS + t];
  Hm[(size_t)b * HS + t] = sum * inv;
  if (t < 3){
    float sz = 0.f;
    for (int a = s; a < e; a++) sz += Z[a * 3 + t];
    x[b * 3 + t] = sz * inv;
  }
}

// ---- fused emb_in GEMM + layer-0 P/Q + zero agg/xacc slices (1-wave blocks, 1000)
__global__ __launch_bounds__(64) void gemm_pq_kernel(
    const float* __restrict__ A,
    const ushortT* __restrict__ Wt, const float* __restrict__ bias,
    float* __restrict__ Cf,
    const ushortT* __restrict__ Wa, const ushortT* __restrict__ Wb,
    const float* __restrict__ b1p,
    ushortT* __restrict__ Pbf, ushortT* __restrict__ Qbf,
    float* __restrict__ agg, float* __restrict__ xacc){
  __shared__ __align__(16) ushortT T1[2048];
  int lane = threadIdx.x;
  int l15 = lane & 15, lg = lane >> 4;
  int base = blockIdx.x * 16;
  int row = base + l15;
  {
    float4 z4 = {0.f, 0.f, 0.f, 0.f};
    float4* aggp = reinterpret_cast<float4*>(agg + (size_t)blockIdx.x * 16 * HS);
#pragma unroll
    for (int i = 0; i < 8; i++) aggp[lane + 64 * i] = z4;
    if (lane < 48) xacc[blockIdx.x * 48 + lane] = 0.f;
  }
  f32x4 zero = {0.f, 0.f, 0.f, 0.f};
  f32x4 acc[8];
#pragma unroll
  for (int n = 0; n < 8; n++) acc[n] = zero;
#pragma unroll
  for (int ks = 0; ks < 4; ks++){
    int k0 = ks * 32 + lg * 8;
    bf16x8 af = load8f_bf(A + (size_t)row * HS + k0);
#pragma unroll
    for (int n = 0; n < 8; n++){
      bf16x8 bf = load8bf(Wt + (size_t)(16 * n + l15) * HS + k0);
      acc[n] = __builtin_amdgcn_mfma_f32_16x16x32_bf16(af, bf, acc[n], 0, 0, 0);
    }
  }
#pragma unroll
  for (int n = 0; n < 8; n++){
    int col = 16 * n + l15;
    float bv = bias[col];
#pragma unroll
    for (int r = 0; r < 4; r++){
      int ro = base + lg * 4 + r;
      int er = lg * 4 + r;
      float hv = acc[n][r] + bv;
      Cf[(size_t)ro * HS + col] = hv;
      T1[(er * 128 + col) ^ ((er & 7) << 3)] = f2bff(hv);
    }
  }
  f32x4 accp[8], accq[8];
#pragma unroll
  for (int n = 0; n < 8; n++){ accp[n] = zero; accq[n] = zero; }
#pragma unroll
  for (int ks = 0; ks < 4; ks++){
    int k0 = ks * 32 + lg * 8;
    bf16x8 af = load8bf(&T1[(l15 * 128 + k0) ^ ((l15 & 7) << 3)]);
#pragma unroll
    for (int n = 0; n < 8; n++){
      accp[n] = __builtin_amdgcn_mfma_f32_16x16x32_bf16(af, load8bf(Wa + (size_t)(16 * n + l15) * HS + k0), accp[n], 0, 0, 0);
      accq[n] = __builtin_amdgcn_mfma_f32_16x16x32_bf16(af, load8bf(Wb + (size_t)(16 * n + l15) * HS + k0), accq[n], 0, 0, 0);
    }
  }
#pragma unroll
  for (int n = 0; n < 8; n++){
    int col = 16 * n + l15;
    float bv = b1p[col];
#pragma unroll
    for (int r = 0; r < 4; r++){
      int ro = base + lg * 4 + r;
      Pbf[(size_t)ro * HS + col] = f2bff(accp[n][r] + bv);
      Qbf[(size_t)ro * HS + col] = f2bff(accq[n][r]);
    }
  }
}

// ---- fused node MLP + x_update + zero-next + next-layer P/Q (1-wave blocks, 1000)
__global__ __launch_bounds__(64) void node_pq_kernel(
    float* __restrict__ h, float* __restrict__ agg,
    const ushortT* __restrict__ W1t, const ushortT* __restrict__ W2t,
    const float* __restrict__ b1, const float* __restrict__ b2,
    const ushortT* __restrict__ Wa, const ushortT* __restrict__ Wb,
    const float* __restrict__ b1p,
    ushortT* __restrict__ Pbf, ushortT* __restrict__ Qbf,
    float* __restrict__ x, float* __restrict__ xacc, const int* __restrict__ estart){
  __shared__ __align__(16) ushortT T1[2048];
  int lane = threadIdx.x;
  int l15 = lane & 15, lg = lane >> 4;
  int base = blockIdx.x * 16;
  int row = base + l15;
  f32x4 zero = {0.f, 0.f, 0.f, 0.f};

  if (lane < 48){
    int i = blockIdx.x * 48 + lane;
    int b = i / 3;
    int cnt = estart[b + 1] - estart[b];
    x[i] += xacc[i] / (float)(cnt > 0 ? cnt : 1);
    xacc[i] = 0.f;
  }

  f32x4 acc[8];
#pragma unroll
  for (int n = 0; n < 8; n++) acc[n] = zero;
#pragma unroll
  for (int ks = 0; ks < 8; ks++){
    int k0 = ks * 32 + lg * 8;
    bf16x8 af = (k0 < 128) ? load8f_bf(h + (size_t)row * HS + k0)
                           : load8f_bf(agg + (size_t)row * HS + (k0 - 128));
#pragma unroll
    for (int n = 0; n < 8; n++){
      acc[n] = __builtin_amdgcn_mfma_f32_16x16x32_bf16(af, load8bf(W1t + (size_t)(16 * n + l15) * 256 + k0), acc[n], 0, 0, 0);
    }
  }
  // drain agg reads then zero this block's agg slice
  __syncthreads();
  {
    float4 z4 = {0.f, 0.f, 0.f, 0.f};
    float4* aggp = reinterpret_cast<float4*>(agg + (size_t)blockIdx.x * 16 * HS);
#pragma unroll
    for (int i = 0; i < 8; i++) aggp[lane + 64 * i] = z4;
  }
#pragma unroll
  for (int n = 0; n < 8; n++){
    int col = 16 * n + l15;
    float bv = b1[col];
#pragma unroll
    for (int r = 0; r < 4; r++){
      int er = lg * 4 + r;
      T1[(er * 128 + col) ^ ((er & 7) << 3)] = f2bff(silu(acc[n][r] + bv));
    }
  }
#pragma unroll
  for (int n = 0; n < 8; n++) acc[n] = zero;
#pragma unroll
  for (int ks = 0; ks < 4; ks++){
    int k0 = ks * 32 + lg * 8;
    bf16x8 af = load8bf(&T1[(l15 * 128 + k0) ^ ((l15 & 7) << 3)]);
#pragma unroll
    for (int n = 0; n < 8; n++){
      acc[n] = __builtin_amdgcn_mfma_f32_16x16x32_bf16(af, load8bf(W2t + (size_t)(16 * n + l15) * HS + k0), acc[n], 0, 0, 0);
    }
  }
#pragma unroll
  for (int n = 0; n < 8; n++){
    int col = 16 * n + l15;
    float bv = b2[col];
#pragma unroll
    for (int r = 0; r < 4; r++){
      int ro = base + lg * 4 + r;
      int er = lg * 4 + r;
      float hv = h[(size_t)ro * HS + col] + acc[n][r] + bv;
      h[(size_t)ro * HS + col] = hv;
      T1[(er * 128 + col) ^ ((er & 7) << 3)] = f2bff(hv);
    }
  }
  // next-layer P/Q from T1
  f32x4 accp[8], accq[8];
#pragma unroll
  for (int n = 0; n < 8; n++){ accp[n] = zero; accq[n] = zero; }
#pragma unroll
  for (int ks = 0; ks < 4; ks++){
    int k0 = ks * 32 + lg * 8;
    bf16x8 af = load8bf(&T1[(l15 * 128 + k0) ^ ((l15 & 7) << 3)]);
#pragma unroll
    for (int n = 0; n < 8; n++){
      accp[n] = __builtin_amdgcn_mfma_f32_16x16x32_bf16(af, load8bf(Wa + (size_t)(16 * n + l15) * HS + k0), accp[n], 0, 0, 0);
      accq[n] = __builtin_amdgcn_mfma_f32_16x16x32_bf16(af, load8bf(Wb + (size_t)(16 * n + l15) * HS + k0), accq[n], 0, 0, 0);
    }
  }
#pragma unroll
  for (int n = 0; n < 8; n++){
    int col = 16 * n + l15;
    float bv = b1p[col];
#pragma unroll
    for (int r = 0; r < 4; r++){
      int ro = base + lg * 4 + r;
      Pbf[(size_t)ro * HS + col] = f2bff(accp[n][r] + bv);
      Qbf[(size_t)ro * HS + col] = f2bff(accq[n][r]);
    }
  }
}

// ---- fused final node MLP + emb_out GEMM + normalize + graph accumulate (1-wave, 1000)
__global__ __launch_bounds__(64) void node_emb_kernel(
    const float* __restrict__ h, const float* __restrict__ agg,
    const ushortT* __restrict__ W1t, const ushortT* __restrict__ W2t,
    const float* __restrict__ b1, const float* __restrict__ b2,
    const ushortT* __restrict__ Eoutt, const float* __restrict__ eob,
    const int* __restrict__ batch_id,
    float* __restrict__ brep, float* __restrict__ gsum){
  __shared__ __align__(16) ushortT T1[2048];
  int lane = threadIdx.x;
  int l15 = lane & 15, lg = lane >> 4;
  int base = blockIdx.x * 16;
  int row = base + l15;
  f32x4 zero = {0.f, 0.f, 0.f, 0.f};

  f32x4 acc[8];
#pragma unroll
  for (int n = 0; n < 8; n++) acc[n] = zero;
#pragma unroll
  for (int ks = 0; ks < 8; ks++){
    int k0 = ks * 32 + lg * 8;
    bf16x8 af = (k0 < 128) ? load8f_bf(h + (size_t)row * HS + k0)
                           : load8f_bf(agg + (size_t)row * HS + (k0 - 128));
#pragma unroll
    for (int n = 0; n < 8; n++){
      acc[n] = __builtin_amdgcn_mfma_f32_16x16x32_bf16(af, load8bf(W1t + (size_t)(16 * n + l15) * 256 + k0), acc[n], 0, 0, 0);
    }
  }
#pragma unroll
  for (int n = 0; n < 8; n++){
    int col = 16 * n + l15;
    float bv = b1[col];
#pragma unroll
    for (int r = 0; r < 4; r++){
      int er = lg * 4 + r;
      T1[(er * 128 + col) ^ ((er & 7) << 3)] = f2bff(silu(acc[n][r] + bv));
    }
  }
#pragma unroll
  for (int n = 0; n < 8; n++) acc[n] = zero;
#pragma unroll
  for (int ks = 0; ks < 4; ks++){
    int k0 = ks * 32 + lg * 8;
    bf16x8 af = load8bf(&T1[(l15 * 128 + k0) ^ ((l15 & 7) << 3)]);
#pragma unroll
    for (int n = 0; n < 8; n++){
      acc[n] = __builtin_amdgcn_mfma_f32_16x16x32_bf16(af, load8bf(W2t + (size_t)(16 * n + l15) * HS + k0), acc[n], 0, 0, 0);
    }
  }
  // h_final = h + acc + b2 -> T1 (bf16)
#pragma unroll
  for (int n = 0; n < 8; n++){
    int col = 16 * n + l15;
    float bv = b2[col];
#pragma unroll
    for (int r = 0; r < 4; r++){
      int ro = base + lg * 4 + r;
      int er = lg * 4 + r;
      float hv = h[(size_t)ro * HS + col] + acc[n][r] + bv;
      T1[(er * 128 + col) ^ ((er & 7) << 3)] = f2bff(hv);
    }
  }
  // emb_out GEMM from T1
#pragma unroll
  for (int n = 0; n < 8; n++) acc[n] = zero;
#pragma unroll
  for (int ks = 0; ks < 4; ks++){
    int k0 = ks * 32 + lg * 8;
    bf16x8 af = load8bf(&T1[(l15 * 128 + k0) ^ ((l15 & 7) << 3)]);
#pragma unroll
    for (int n = 0; n < 8; n++){
      acc[n] = __builtin_amdgcn_mfma_f32_16x16x32_bf16(af, load8bf(Eoutt + (size_t)(16 * n + l15) * HS + k0), acc[n], 0, 0, 0);
    }
  }
#pragma unroll
  for (int n = 0; n < 8; n++){
    float bv = eob[16 * n + l15];
#pragma unroll
    for (int r = 0; r < 4; r++) acc[n][r] += bv;
  }
  float scl[4];
#pragma unroll
  for (int r = 0; r < 4; r++){
    float ss = 0.f;
#pragma unroll
    for (int n = 0; n < 8; n++) ss += acc[n][r] * acc[n][r];
#pragma unroll
    for (int o = 1; o < 16; o <<= 1) ss += __shfl_xor(ss, o, 64);
    scl[r] = 1.f / fmaxf(sqrtf(ss), 1e-12f);
  }
#pragma unroll
  for (int r = 0; r < 4; r++){
    int ro = base + lg * 4 + r;
    int g = batch_id[ro];
#pragma unroll
    for (int n = 0; n < 8; n++){
      int col = 16 * n + l15;
      float v = acc[n][r] * scl[r];
      brep[(size_t)ro * HS + col] = v;
      atomicAdd(&gsum[g * HS + col], v);
    }
  }
}

// ---- fused edge kernel v11: 8-wave chan-split; agg flush moved BEFORE phase C so
// its LDS-read + atomic chain drains under phase C's MFMA/LDS compute.
template<int COORD>
__global__ __launch_bounds__(512, 2) void edge_kernel(
    const int* __restrict__ srow, const int* __restrict__ scol,
    const ushortT* __restrict__ sattr,
    const float* __restrict__ x,
    const ushortT* __restrict__ Pbf, const ushortT* __restrict__ Qbf,
    const ushortT* __restrict__ W1ct, const ushortT* __restrict__ W2tp,
    const ushortT* __restrict__ CW1tp,
    const float* __restrict__ b2, const float* __restrict__ cb1,
    const float* __restrict__ cw3,
    float* __restrict__ xacc, float* __restrict__ agg){
  __shared__ float bias_l[3][128];
  __shared__ int   rid_s[128];
  __shared__ float dif_s[COORD ? 128 : 1][3];
  __shared__ float wall[COORD ? 8 : 1][COORD ? 128 : 1];
  __shared__ __align__(16) ushortT S1[128 * 128];   // m1, pi-order, swizzled (32 KB)
  __shared__ __align__(16) ushortT S2[128 * 128];   // m,  pi-order, swizzled (32 KB)

  const int t = threadIdx.x;
  const int lane = t & 63;
  const int wv = t >> 6;                    // 0..7 = chan group
  const int l15 = lane & 15, lg = lane >> 4;
  const f32x4 zero = {0.f, 0.f, 0.f, 0.f};

  if (t < 128){
    bias_l[0][t] = b2[t];
    if (COORD){ bias_l[1][t] = cb1[t]; bias_l[2][t] = cw3[t]; }
  }

  // ---------- phase A: m1 for this wave's 16 edges ----------
  const int erow = wv * 16 + l15;           // 0..127
  const int e = blockIdx.x * 128 + erow;
  const int r = srow[e], c = scol[e];
  const float dx = x[r * 3 + 0] - x[c * 3 + 0];
  const float dy = x[r * 3 + 1] - x[c * 3 + 1];
  const float dz = x[r * 3 + 2] - x[c * 3 + 2];
  const float rad = dx * dx + dy * dy + dz * dz;
  if (lg == 0){
    rid_s[erow] = r;
    if (COORD){ dif_s[erow][0] = dx; dif_s[erow][1] = dy; dif_s[erow][2] = dz; }
  }
  ushort8 at8 = __builtin_bit_cast(ushort8, load8bf(sattr + (size_t)e * 32 + lg * 8));
  if (lg == 0) at8[0] = f2bff(rad);
  const bf16x8 atb = __builtin_bit_cast(bf16x8, at8);

#pragma unroll
  for (int ks = 0; ks < 4; ks++){
    f32x4 a0 = __builtin_amdgcn_mfma_f32_16x16x32_bf16(
        load8bf(W1ct + (size_t)(16 * (2 * ks)     + l15) * 32 + lg * 8), atb, zero, 0, 0, 0);
    f32x4 a1 = __builtin_amdgcn_mfma_f32_16x16x32_bf16(
        load8bf(W1ct + (size_t)(16 * (2 * ks + 1) + l15) * 32 + lg * 8), atb, zero, 0, 0, 0);
    ushort8 pv = __builtin_bit_cast(ushort8, load8bf(Pbf + (size_t)r * HS + ks * 32 + lg * 8));
    ushort8 qv = __builtin_bit_cast(ushort8, load8bf(Qbf + (size_t)c * HS + ks * 32 + lg * 8));
    ushort8 af;
#pragma unroll
    for (int j = 0; j < 4; j++)
      af[j] = f2bff(silu(a0[j] + bf2f(pv[j]) + bf2f(qv[j])));
#pragma unroll
    for (int j = 4; j < 8; j++)
      af[j] = f2bff(silu(a1[j - 4] + bf2f(pv[j]) + bf2f(qv[j])));
    int byte = (erow * 256 + ks * 64 + lg * 16) ^ ((erow & 7) << 4);
    *reinterpret_cast<uint4*>(reinterpret_cast<char*>(S1) + byte) = __builtin_bit_cast(uint4, af);
  }
  __syncthreads();   // bar1: S1 + rid + dif + biases ready

  // ---------- phase B: GEMM2, group wv for ALL 128 edges (8 et-tiles) ----------
  f32x4 acc2[8];
#pragma unroll
  for (int et = 0; et < 8; et++) acc2[et] = zero;
#pragma unroll
  for (int ks = 0; ks < 4; ks++){
    bf16x8 wf = load8bf(W2tp + (size_t)(16 * wv + l15) * HS + ks * 32 + lg * 8);
#pragma unroll
    for (int et = 0; et < 8; et++){
      int row2 = et * 16 + l15;
      int byte = (row2 * 256 + ks * 64 + lg * 16) ^ ((row2 & 7) << 4);
      bf16x8 mb = __builtin_bit_cast(bf16x8,
          *reinterpret_cast<const uint4*>(reinterpret_cast<const char*>(S1) + byte));
      acc2[et] = __builtin_amdgcn_mfma_f32_16x16x32_bf16(wf, mb, acc2[et], 0, 0, 0);
    }
  }
  // m-epilogue: silu + b2 -> S2 at pi positions for group wv (uint2 per et)
  {
    float4 bv = *reinterpret_cast<const float4*>(&bias_l[0][16 * wv + lg * 4]);
    int pbyte = ((wv >> 1) * 32 + lg * 8 + (wv & 1) * 4) * 2;
#pragma unroll
    for (int et = 0; et < 8; et++){
      ushortT mm[4];
#pragma unroll
      for (int rr = 0; rr < 4; rr++)
        mm[rr] = f2bff(silu(acc2[et][rr] + (&bv.x)[rr]));
      int row2 = et * 16 + l15;
      int byte = (row2 * 256 + pbyte) ^ ((row2 & 7) << 4);
      *reinterpret_cast<uint2*>(reinterpret_cast<char*>(S2) + byte) =
          *reinterpret_cast<uint2*>(mm);
    }
  }
  __syncthreads();   // bar2: S2 ready

  // ---------- agg flush FIRST (depends only on S2): atomics drain under phase C ----------
  {
    const int c0 = c_of_p(2 * lane), c1 = c_of_p(2 * lane + 1);
    float run0 = 0.f, run1 = 0.f;
    int prev = __builtin_amdgcn_readfirstlane(rid_s[wv * 16]);
#pragma unroll
    for (int e2 = 0; e2 < 16; e2++){
      int re = __builtin_amdgcn_readfirstlane(rid_s[wv * 16 + e2]);
      if (re != prev){
        atomicAdd(&agg[(size_t)prev * HS + c0], run0);
        atomicAdd(&agg[(size_t)prev * HS + c1], run1);
        run0 = 0.f; run1 = 0.f; prev = re;
      }
      int row2 = wv * 16 + e2;
      int byte = (row2 * 256 + lane * 4) ^ ((row2 & 7) << 4);
      uint u = *reinterpret_cast<const uint*>(reinterpret_cast<const char*>(S2) + byte);
      run0 += bf2f((ushortT)(u & 0xFFFF));
      run1 += bf2f((ushortT)(u >> 16));
    }
    atomicAdd(&agg[(size_t)prev * HS + c0], run0);
    atomicAdd(&agg[(size_t)prev * HS + c1], run1);
  }

  if (COORD){
    // ---------- phase C: coord GEMM, group wv for ALL 128 edges ----------
    f32x4 acc3[8];
#pragma unroll
    for (int et = 0; et < 8; et++) acc3[et] = zero;
#pragma unroll
    for (int ks = 0; ks < 4; ks++){
      bf16x8 wf = load8bf(CW1tp + (size_t)(16 * wv + l15) * HS + ks * 32 + lg * 8);
#pragma unroll
      for (int et = 0; et < 8; et++){
        int row2 = et * 16 + l15;
        int byte = (row2 * 256 + ks * 64 + lg * 16) ^ ((row2 & 7) << 4);
        bf16x8 mb = __builtin_bit_cast(bf16x8,
            *reinterpret_cast<const uint4*>(reinterpret_cast<const char*>(S2) + byte));
        acc3[et] = __builtin_amdgcn_mfma_f32_16x16x32_bf16(wf, mb, acc3[et], 0, 0, 0);
      }
    }
    // per-wave partial w (16 chans of group wv) -> wall
    {
      float4 cbv = *reinterpret_cast<const float4*>(&bias_l[1][16 * wv + lg * 4]);
      float4 cwv = *reinterpret_cast<const float4*>(&bias_l[2][16 * wv + lg * 4]);
#pragma unroll
      for (int et = 0; et < 8; et++){
        float ws = 0.f;
#pragma unroll
        for (int rr = 0; rr < 4; rr++)
          ws += silu(acc3[et][rr] + (&cbv.x)[rr]) * (&cwv.x)[rr];
        ws += __shfl_xor(ws, 16, 64);
        ws += __shfl_xor(ws, 32, 64);
        if (lg == 0) wall[wv][et * 16 + l15] = ws;
      }
    }
    __syncthreads();   // bar3: wall complete
    // xacc: parallel scatter, per-WG summed w, one atomic per (edge,coord)
    if (t < 384){
      int e2 = t / 3, cd = t % 3;
      float w = 0.f;
#pragma unroll
      for (int wv2 = 0; wv2 < 8; wv2++) w += wall[wv2][e2];
      atomicAdd(&xacc[(size_t)rid_s[e2] * 3 + cd], dif_s[e2][cd] * w);
    }
  }
}

__global__ void norm_graph_kernel(const float* __restrict__ gsum, float* __restrict__ grep){
  int wv = threadIdx.x >> 6, lane = threadIdx.x & 63;
  int g = blockIdx.x * 4 + wv;
  if (g >= N_GRAPHS) return;
  float v0 = gsum[g * HS + lane];
  float v1 = gsum[g * HS + 64 + lane];
  float ss = v0 * v0 + v1 * v1;
#pragma unroll
  for (int o = 1; o < 64; o <<= 1) ss += __shfl_xor(ss, o, 64);
  float s = 1.f / fmaxf(sqrtf(ss), 1e-12f);
  grep[(size_t)g * HS + lane] = v0 * s;
  grep[(size_t)g * HS + 64 + lane] = v1 * s;
}

extern "C" void kernel_launch(void* const* d_in, const int* in_sizes, int n_in,
                              void* d_out, int out_size, void* d_ws, size_t ws_size,
                              hipStream_t stream){
  const float* H         = (const float*)d_in[0];
  const float* Z         = (const float*)d_in[1];
  const int*   block_id  = (const int*)d_in[2];
  const int*   batch_id  = (const int*)d_in[3];
  const int*   edges     = (const int*)d_in[4];
  const float* edge_attr = (const float*)d_in[5];
  const float* emb_in_w  = (const float*)d_in[6];
  const float* emb_in_b  = (const float*)d_in[7];
  const float* emb_out_w = (const float*)d_in[8];
  const float* emb_out_b = (const float*)d_in[9];
  const float* edge_w1   = (const float*)d_in[10];
  const float* edge_b1   = (const float*)d_in[11];
  const float* edge_w2   = (const float*)d_in[12];
  const float* edge_b2   = (const float*)d_in[13];
  const float* node_w1   = (const float*)d_in[14];
  const float* node_b1   = (const float*)d_in[15];
  const float* node_w2   = (const float*)d_in[16];
  const float* node_b2   = (const float*)d_in[17];
  const float* coord_w1  = (const float*)d_in[18];
  const float* coord_b1  = (const float*)d_in[19];
  const float* coord_w3  = (const float*)d_in[20];

  float* out  = (float*)d_out;
  float* Hm   = out;                               // [16000 x 128]
  float* brep = out + (size_t)N_BLOCKS * HS;       // [16000 x 128]
  float* grep = out + (size_t)2 * N_BLOCKS * HS;   // [128 x 128]

  char* base = (char*)d_ws;
  size_t off = 0;
  auto take = [&](size_t bytes) -> char* {
    char* p = base + off;
    off += (bytes + 255) & ~(size_t)255;
    return p;
  };
  float*   x     = (float*)  take((size_t)N_BLOCKS * 3 * 4);
  float*   xacc  = (float*)  take((size_t)N_BLOCKS * 3 * 4);
  float*   h     = (float*)  take((size_t)N_BLOCKS * HS * 4);
  float*   agg   = (float*)  take((size_t)N_BLOCKS * HS * 4);
  float*   gsum  = (float*)  take((size_t)N_GRAPHS * HS * 4);
  int*     bstart= (int*)    take((size_t)(N_BLOCKS + 1) * 4);
  int*     hist  = (int*)    take((size_t)N_BLOCKS * 4);
  int*     estart= (int*)    take((size_t)(N_BLOCKS + 1) * 4);
  int*     ecur  = (int*)    take((size_t)N_BLOCKS * 4);
  int*     srow  = (int*)    take((size_t)N_EDGES * 4);
  int*     scol  = (int*)    take((size_t)N_EDGES * 4);
  ushortT* sattr = (ushortT*)take((size_t)N_EDGES * 32 * 2);
  ushortT* Pbf   = (ushortT*)take((size_t)N_BLOCKS * HS * 2);
  ushortT* Qbf   = (ushortT*)take((size_t)N_BLOCKS * HS * 2);
  ushortT* W1atp = (ushortT*)take((size_t)3 * 128 * 128 * 2);
  ushortT* W1btp = (ushortT*)take((size_t)3 * 128 * 128 * 2);
  ushortT* W1ct  = (ushortT*)take((size_t)3 * 128 * 32 * 2);
  ushortT* W2tp  = (ushortT*)take((size_t)3 * 128 * 128 * 2);
  ushortT* CW1tp = (ushortT*)take((size_t)3 * 128 * 128 * 2);
  ushortT* NW1t  = (ushortT*)take((size_t)3 * 128 * 256 * 2);
  ushortT* NW2t  = (ushortT*)take((size_t)3 * 128 * 128 * 2);
  ushortT* Eint  = (ushortT*)take((size_t)128 * 128 * 2);
  ushortT* Eoutt = (ushortT*)take((size_t)128 * 128 * 2);
  float*   b1p   = (float*)  take((size_t)3 * 128 * 4);

  // merged prep (weights + bias perm + hist zero)
  PrepParams P;
  P.ew1 = edge_w1; P.ew2 = edge_w2; P.cw1 = coord_w1;
  P.nw1 = node_w1; P.nw2 = node_w2; P.ei = emb_in_w; P.eo = emb_out_w;
  P.eb1 = edge_b1;
  P.W1atp = W1atp; P.W1btp = W1btp; P.W1ct = W1ct; P.W2tp = W2tp; P.CW1tp = CW1tp;
  P.NW1t = NW1t; P.NW2t = NW2t; P.Eint = Eint; P.Eoutt = Eoutt;
  P.b1p = b1p; P.hist = hist;
  prep_kernel<<<(PREP_TOTAL + 255) / 256, 256, 0, stream>>>(P);

  hist_bstart_kernel<<<N_EDGES / 256 + (N_BLOCKS + 1 + 255) / 256, 256, 0, stream>>>(
      edges, hist, block_id, bstart);
  scan_kernel<<<1, 1024, 0, stream>>>(hist, estart, ecur);
  scatter_kernel<<<N_EDGES / 256, 256, 0, stream>>>(edges, edge_attr, ecur, srow, scol, sattr);
  pool_kernel<<<N_BLOCKS, 128, 0, stream>>>(H, Z, bstart, Hm, x, gsum);

  // h = Hm @ emb_in_w + b ; P/Q layer 0 ; zero agg/xacc
  gemm_pq_kernel<<<N_BLOCKS / 16, 64, 0, stream>>>(Hm, Eint, emb_in_b, h,
                                                   W1atp, W1btp, b1p, Pbf, Qbf, agg, xacc);

  for (int l = 0; l < 3; l++){
    if (l < 2){
      edge_kernel<1><<<N_EDGES / 128, 512, 0, stream>>>(
          srow, scol, sattr, x, Pbf, Qbf,
          W1ct + (size_t)l * 128 * 32, W2tp + (size_t)l * 128 * 128, CW1tp + (size_t)l * 128 * 128,
          edge_b2 + l * 128, coord_b1 + l * 128, coord_w3 + l * 128,
          xacc, agg);
      node_pq_kernel<<<N_BLOCKS / 16, 64, 0, stream>>>(
          h, agg, NW1t + (size_t)l * 128 * 256, NW2t + (size_t)l * 128 * 128,
          node_b1 + l * 128, node_b2 + l * 128,
          W1atp + (size_t)(l + 1) * 128 * 128, W1btp + (size_t)(l + 1) * 128 * 128,
          b1p + (l + 1) * 128, Pbf, Qbf, x, xacc, estart);
    } else {
      edge_kernel<0><<<N_EDGES / 128, 512, 0, stream>>>(
          srow, scol, sattr, x, Pbf, Qbf,
          W1ct + (size_t)l * 128 * 32, W2tp + (size_t)l * 128 * 128, CW1tp + (size_t)l * 128 * 128,
          edge_b2 + l * 128, coord_b1 + l * 128, coord_w3 + l * 128,
          xacc, agg);
      node_emb_kernel<<<N_BLOCKS / 16, 64, 0, stream>>>(
          h, agg, NW1t + (size_t)l * 128 * 256, NW2t + (size_t)l * 128 * 128,
          node_b1 + l * 128, node_b2 + l * 128,
          Eoutt, emb_out_b, batch_id, brep, gsum);
    }
  }

  norm_graph_kernel<<<N_GRAPHS / 4, 256, 0, stream>>>(gsum, grep);
}

// Round 16
// 479.877 us; speedup vs baseline: 1.1295x; 1.0213x over previous
//
#include <hip/hip_runtime.h>

#define N_ATOMS  80000
#define N_BLOCKS 16000
#define N_EDGES  320000
#define N_GRAPHS 128
#define HS       128

typedef unsigned short ushortT;
typedef __attribute__((ext_vector_type(8))) __bf16 bf16x8;
typedef __attribute__((ext_vector_type(8))) unsigned short ushort8;
typedef __attribute__((ext_vector_type(4))) float f32x4;

__device__ __forceinline__ unsigned short f2bf(float f){
  unsigned int u = __builtin_bit_cast(unsigned int, f);
  u = (u + 0x7FFFu + ((u >> 16) & 1u)) >> 16;
  return (unsigned short)u;
}
__device__ __forceinline__ ushortT f2bff(float f){
  __bf16 b = (__bf16)f;
  return __builtin_bit_cast(ushortT, b);
}
__device__ __forceinline__ float bf2f(ushortT u){
  unsigned int v = ((unsigned int)u) << 16;
  return __builtin_bit_cast(float, v);
}
__device__ __forceinline__ bf16x8 load8bf(const ushortT* p){
  uint4 u = *reinterpret_cast<const uint4*>(p);
  return __builtin_bit_cast(bf16x8, u);
}
__device__ __forceinline__ bf16x8 load8f_bf(const float* p){
  float4 a = *reinterpret_cast<const float4*>(p);
  float4 b = *reinterpret_cast<const float4*>(p + 4);
  ushort8 u = { f2bff(a.x), f2bff(a.y), f2bff(a.z), f2bff(a.w),
                f2bff(b.x), f2bff(b.y), f2bff(b.z), f2bff(b.w) };
  return __builtin_bit_cast(bf16x8, u);
}
// fast silu: v * rcp(1+exp(-v))
__device__ __forceinline__ float silu(float v){
  return v * __builtin_amdgcn_rcpf(1.f + __expf(-v));
}

// pi-permutation: C-fragment register (n,r) of lane-group lg holds natural col
// c = 16n + lg*4 + r; B-fragment position p = ks*32 + lg*8 + j, n = 2ks + (j>>2), r = j&3.
__device__ __forceinline__ int c_of_p(int p){
  int ks = p >> 5, lg = (p >> 3) & 3, j = p & 7;
  return 16 * (ks * 2 + (j >> 2)) + lg * 4 + (j & 3);
}

// ---- merged prep: all weight transposes + bias perm + hist zero
struct PrepParams {
  const float* ew1; const float* ew2; const float* cw1;
  const float* nw1; const float* nw2; const float* ei; const float* eo;
  const float* eb1;
  ushortT* W1atp; ushortT* W1btp; ushortT* W1ct; ushortT* W2tp; ushortT* CW1tp;
  ushortT* NW1t; ushortT* NW2t; ushortT* Eint; ushortT* Eoutt;
  float* b1p; int* hist;
};

__device__ __forceinline__ void tcvt(int idx, const float* __restrict__ src,
                                     ushortT* __restrict__ dst,
                                     int srcK, int row_off, int K, int N, int Kpad,
                                     int pn, int pk){
  int k = idx % Kpad;
  int rem = idx / Kpad;
  int n = rem % N;
  int l = rem / N;
  float v = 0.f;
  if (k < K){
    int kk = pk ? c_of_p(k) : k;
    int nn = pn ? c_of_p(n) : n;
    v = src[((size_t)l * srcK + row_off + kk) * N + nn];
  }
  dst[idx] = f2bf(v);
}

#define PREP_TOTAL (49152*5 + 12288 + 98304 + 16384*2 + 16000 + 384)

__global__ void prep_kernel(PrepParams P){
  int idx = blockIdx.x * 256 + threadIdx.x;
  if (idx < 49152){ tcvt(idx, P.ew1, P.W1atp, 273,   0, 128, 128, 128, 1, 0); return; }
  idx -= 49152;
  if (idx < 49152){ tcvt(idx, P.ew1, P.W1btp, 273, 128, 128, 128, 128, 1, 0); return; }
  idx -= 49152;
  if (idx < 12288){ tcvt(idx, P.ew1, P.W1ct,  273, 256,  17, 128,  32, 0, 0); return; }
  idx -= 12288;
  if (idx < 49152){ tcvt(idx, P.ew2, P.W2tp,  128,   0, 128, 128, 128, 0, 1); return; }
  idx -= 49152;
  if (idx < 49152){ tcvt(idx, P.cw1, P.CW1tp, 128,   0, 128, 128, 128, 0, 1); return; }
  idx -= 49152;
  if (idx < 98304){ tcvt(idx, P.nw1, P.NW1t,  256,   0, 256, 128, 256, 0, 0); return; }
  idx -= 98304;
  if (idx < 49152){ tcvt(idx, P.nw2, P.NW2t,  128,   0, 128, 128, 128, 0, 0); return; }
  idx -= 49152;
  if (idx < 16384){ tcvt(idx, P.ei,  P.Eint,  128,   0, 128, 128, 128, 0, 0); return; }
  idx -= 16384;
  if (idx < 16384){ tcvt(idx, P.eo,  P.Eoutt, 128,   0, 128, 128, 128, 0, 0); return; }
  idx -= 16384;
  if (idx < 16000){ P.hist[idx] = 0; return; }
  idx -= 16000;
  if (idx < 384){ int l = idx >> 7, p = idx & 127; P.b1p[idx] = P.eb1[l * 128 + c_of_p(p)]; }
}

// ---- hist + block_start merged
__global__ void hist_bstart_kernel(const int* __restrict__ edges, int* __restrict__ hist,
                                   const int* __restrict__ bid, int* __restrict__ bstart){
  int b = blockIdx.x;
  if (b < N_EDGES / 256){
    int e = b * 256 + threadIdx.x;
    atomicAdd(&hist[edges[e]], 1);
  } else {
    int i = (b - N_EDGES / 256) * 256 + threadIdx.x;
    if (i <= N_BLOCKS){
      int lo = 0, hi = N_ATOMS;
      while (lo < hi){ int mid = (lo + hi) >> 1; if (bid[mid] < i) lo = mid + 1; else hi = mid; }
      bstart[i] = lo;
    }
  }
}

__global__ __launch_bounds__(1024) void scan_kernel(const int* __restrict__ hist,
                                                    int* __restrict__ estart,
                                                    int* __restrict__ ecur){
  __shared__ int ps[1024];
  int t = threadIdx.x;
  const int chunk = (N_BLOCKS + 1023) / 1024;
  int lo = t * chunk, hi = lo + chunk;
  if (hi > N_BLOCKS) hi = N_BLOCKS;
  if (lo > N_BLOCKS) lo = N_BLOCKS;
  int s = 0;
  for (int i = lo; i < hi; i++) s += hist[i];
  ps[t] = s;
  __syncthreads();
  for (int off = 1; off < 1024; off <<= 1){
    int v = (t >= off) ? ps[t - off] : 0;
    __syncthreads();
    ps[t] += v;
    __syncthreads();
  }
  int base = (t == 0) ? 0 : ps[t - 1];
  for (int i = lo; i < hi; i++){ estart[i] = base; ecur[i] = base; base += hist[i]; }
  if (t == 1023) estart[N_BLOCKS] = base;
}

// scatter into sorted order; sattr padded: 32 u16/edge = [0, attr0..15, 0 x15]
__global__ void scatter_kernel(const int* __restrict__ edges, const float* __restrict__ attr,
                               int* __restrict__ ecur,
                               int* __restrict__ srow, int* __restrict__ scol,
                               ushortT* __restrict__ sattr){
  int e = blockIdx.x * 256 + threadIdx.x;
  if (e >= N_EDGES) return;
  int r = edges[e], c = edges[N_EDGES + e];
  int p = atomicAdd(&ecur[r], 1);
  srow[p] = r; scol[p] = c;
  ushortT buf[32];
  buf[0] = 0;
#pragma unroll
  for (int k = 0; k < 16; k++) buf[k + 1] = f2bf(attr[(size_t)e * 16 + k]);
#pragma unroll
  for (int k = 17; k < 32; k++) buf[k] = 0;
#pragma unroll
  for (int k = 0; k < 16; k++)
    reinterpret_cast<uint*>(sattr + (size_t)p * 32)[k] = reinterpret_cast<uint*>(buf)[k];
}

__global__ void pool_kernel(const float* __restrict__ H, const float* __restrict__ Z,
                            const int* __restrict__ start,
                            float* __restrict__ Hm, float* __restrict__ x,
                            float* __restrict__ gsum){
  int b = blockIdx.x;
  int t = threadIdx.x;            // 128 threads
  if (b < 128) gsum[b * 128 + t] = 0.f;
  int s = start[b], e = start[b + 1];
  float inv = 1.f / (float)((e - s) > 0 ? (e - s) : 1);
  float sum = 0.f;
  for (int a = s; a < e; a++) sum += H[(size_t)a * HS + t];
  Hm[(size_t)b * HS + t] = sum * inv;
  if (t < 3){
    float sz = 0.f;
    for (int a = s; a < e; a++) sz += Z[a * 3 + t];
    x[b * 3 + t] = sz * inv;
  }
}

// ---- fused emb_in GEMM + layer-0 P/Q + zero agg/xacc slices (1-wave blocks, 1000)
__global__ __launch_bounds__(64) void gemm_pq_kernel(
    const float* __restrict__ A,
    const ushortT* __restrict__ Wt, const float* __restrict__ bias,
    float* __restrict__ Cf,
    const ushortT* __restrict__ Wa, const ushortT* __restrict__ Wb,
    const float* __restrict__ b1p,
    ushortT* __restrict__ Pbf, ushortT* __restrict__ Qbf,
    float* __restrict__ agg, float* __restrict__ xacc){
  __shared__ __align__(16) ushortT T1[2048];
  int lane = threadIdx.x;
  int l15 = lane & 15, lg = lane >> 4;
  int base = blockIdx.x * 16;
  int row = base + l15;
  {
    float4 z4 = {0.f, 0.f, 0.f, 0.f};
    float4* aggp = reinterpret_cast<float4*>(agg + (size_t)blockIdx.x * 16 * HS);
#pragma unroll
    for (int i = 0; i < 8; i++) aggp[lane + 64 * i] = z4;
    if (lane < 48) xacc[blockIdx.x * 48 + lane] = 0.f;
  }
  f32x4 zero = {0.f, 0.f, 0.f, 0.f};
  f32x4 acc[8];
#pragma unroll
  for (int n = 0; n < 8; n++) acc[n] = zero;
#pragma unroll
  for (int ks = 0; ks < 4; ks++){
    int k0 = ks * 32 + lg * 8;
    bf16x8 af = load8f_bf(A + (size_t)row * HS + k0);
#pragma unroll
    for (int n = 0; n < 8; n++){
      bf16x8 bf = load8bf(Wt + (size_t)(16 * n + l15) * HS + k0);
      acc[n] = __builtin_amdgcn_mfma_f32_16x16x32_bf16(af, bf, acc[n], 0, 0, 0);
    }
  }
#pragma unroll
  for (int n = 0; n < 8; n++){
    int col = 16 * n + l15;
    float bv = bias[col];
#pragma unroll
    for (int r = 0; r < 4; r++){
      int ro = base + lg * 4 + r;
      int er = lg * 4 + r;
      float hv = acc[n][r] + bv;
      Cf[(size_t)ro * HS + col] = hv;
      T1[(er * 128 + col) ^ ((er & 7) << 3)] = f2bff(hv);
    }
  }
  f32x4 accp[8], accq[8];
#pragma unroll
  for (int n = 0; n < 8; n++){ accp[n] = zero; accq[n] = zero; }
#pragma unroll
  for (int ks = 0; ks < 4; ks++){
    int k0 = ks * 32 + lg * 8;
    bf16x8 af = load8bf(&T1[(l15 * 128 + k0) ^ ((l15 & 7) << 3)]);
#pragma unroll
    for (int n = 0; n < 8; n++){
      accp[n] = __builtin_amdgcn_mfma_f32_16x16x32_bf16(af, load8bf(Wa + (size_t)(16 * n + l15) * HS + k0), accp[n], 0, 0, 0);
      accq[n] = __builtin_amdgcn_mfma_f32_16x16x32_bf16(af, load8bf(Wb + (size_t)(16 * n + l15) * HS + k0), accq[n], 0, 0, 0);
    }
  }
#pragma unroll
  for (int n = 0; n < 8; n++){
    int col = 16 * n + l15;
    float bv = b1p[col];
#pragma unroll
    for (int r = 0; r < 4; r++){
      int ro = base + lg * 4 + r;
      Pbf[(size_t)ro * HS + col] = f2bff(accp[n][r] + bv);
      Qbf[(size_t)ro * HS + col] = f2bff(accq[n][r]);
    }
  }
}

// ---- fused node MLP + x_update + zero-next + next-layer P/Q (1-wave blocks, 1000)
__global__ __launch_bounds__(64) void node_pq_kernel(
    float* __restrict__ h, float* __restrict__ agg,
    const ushortT* __restrict__ W1t, const ushortT* __restrict__ W2t,
    const float* __restrict__ b1, const float* __restrict__ b2,
    const ushortT* __restrict__ Wa, const ushortT* __restrict__ Wb,
    const float* __restrict__ b1p,
    ushortT* __restrict__ Pbf, ushortT* __restrict__ Qbf,
    float* __restrict__ x, float* __restrict__ xacc, const int* __restrict__ estart){
  __shared__ __align__(16) ushortT T1[2048];
  int lane = threadIdx.x;
  int l15 = lane & 15, lg = lane >> 4;
  int base = blockIdx.x * 16;
  int row = base + l15;
  f32x4 zero = {0.f, 0.f, 0.f, 0.f};

  if (lane < 48){
    int i = blockIdx.x * 48 + lane;
    int b = i / 3;
    int cnt = estart[b + 1] - estart[b];
    x[i] += xacc[i] / (float)(cnt > 0 ? cnt : 1);
    xacc[i] = 0.f;
  }

  f32x4 acc[8];
#pragma unroll
  for (int n = 0; n < 8; n++) acc[n] = zero;
#pragma unroll
  for (int ks = 0; ks < 8; ks++){
    int k0 = ks * 32 + lg * 8;
    bf16x8 af = (k0 < 128) ? load8f_bf(h + (size_t)row * HS + k0)
                           : load8f_bf(agg + (size_t)row * HS + (k0 - 128));
#pragma unroll
    for (int n = 0; n < 8; n++){
      acc[n] = __builtin_amdgcn_mfma_f32_16x16x32_bf16(af, load8bf(W1t + (size_t)(16 * n + l15) * 256 + k0), acc[n], 0, 0, 0);
    }
  }
  // drain agg reads then zero this block's agg slice
  __syncthreads();
  {
    float4 z4 = {0.f, 0.f, 0.f, 0.f};
    float4* aggp = reinterpret_cast<float4*>(agg + (size_t)blockIdx.x * 16 * HS);
#pragma unroll
    for (int i = 0; i < 8; i++) aggp[lane + 64 * i] = z4;
  }
#pragma unroll
  for (int n = 0; n < 8; n++){
    int col = 16 * n + l15;
    float bv = b1[col];
#pragma unroll
    for (int r = 0; r < 4; r++){
      int er = lg * 4 + r;
      T1[(er * 128 + col) ^ ((er & 7) << 3)] = f2bff(silu(acc[n][r] + bv));
    }
  }
#pragma unroll
  for (int n = 0; n < 8; n++) acc[n] = zero;
#pragma unroll
  for (int ks = 0; ks < 4; ks++){
    int k0 = ks * 32 + lg * 8;
    bf16x8 af = load8bf(&T1[(l15 * 128 + k0) ^ ((l15 & 7) << 3)]);
#pragma unroll
    for (int n = 0; n < 8; n++){
      acc[n] = __builtin_amdgcn_mfma_f32_16x16x32_bf16(af, load8bf(W2t + (size_t)(16 * n + l15) * HS + k0), acc[n], 0, 0, 0);
    }
  }
#pragma unroll
  for (int n = 0; n < 8; n++){
    int col = 16 * n + l15;
    float bv = b2[col];
#pragma unroll
    for (int r = 0; r < 4; r++){
      int ro = base + lg * 4 + r;
      int er = lg * 4 + r;
      float hv = h[(size_t)ro * HS + col] + acc[n][r] + bv;
      h[(size_t)ro * HS + col] = hv;
      T1[(er * 128 + col) ^ ((er & 7) << 3)] = f2bff(hv);
    }
  }
  // next-layer P/Q from T1
  f32x4 accp[8], accq[8];
#pragma unroll
  for (int n = 0; n < 8; n++){ accp[n] = zero; accq[n] = zero; }
#pragma unroll
  for (int ks = 0; ks < 4; ks++){
    int k0 = ks * 32 + lg * 8;
    bf16x8 af = load8bf(&T1[(l15 * 128 + k0) ^ ((l15 & 7) << 3)]);
#pragma unroll
    for (int n = 0; n < 8; n++){
      accp[n] = __builtin_amdgcn_mfma_f32_16x16x32_bf16(af, load8bf(Wa + (size_t)(16 * n + l15) * HS + k0), accp[n], 0, 0, 0);
      accq[n] = __builtin_amdgcn_mfma_f32_16x16x32_bf16(af, load8bf(Wb + (size_t)(16 * n + l15) * HS + k0), accq[n], 0, 0, 0);
    }
  }
#pragma unroll
  for (int n = 0; n < 8; n++){
    int col = 16 * n + l15;
    float bv = b1p[col];
#pragma unroll
    for (int r = 0; r < 4; r++){
      int ro = base + lg * 4 + r;
      Pbf[(size_t)ro * HS + col] = f2bff(accp[n][r] + bv);
      Qbf[(size_t)ro * HS + col] = f2bff(accq[n][r]);
    }
  }
}

// ---- fused final node MLP + emb_out GEMM + normalize + graph accumulate (1-wave, 1000)
__global__ __launch_bounds__(64) void node_emb_kernel(
    const float* __restrict__ h, const float* __restrict__ agg,
    const ushortT* __restrict__ W1t, const ushortT* __restrict__ W2t,
    const float* __restrict__ b1, const float* __restrict__ b2,
    const ushortT* __restrict__ Eoutt, const float* __restrict__ eob,
    const int* __restrict__ batch_id,
    float* __restrict__ brep, float* __restrict__ gsum){
  __shared__ __align__(16) ushortT T1[2048];
  int lane = threadIdx.x;
  int l15 = lane & 15, lg = lane >> 4;
  int base = blockIdx.x * 16;
  int row = base + l15;
  f32x4 zero = {0.f, 0.f, 0.f, 0.f};

  f32x4 acc[8];
#pragma unroll
  for (int n = 0; n < 8; n++) acc[n] = zero;
#pragma unroll
  for (int ks = 0; ks < 8; ks++){
    int k0 = ks * 32 + lg * 8;
    bf16x8 af = (k0 < 128) ? load8f_bf(h + (size_t)row * HS + k0)
                           : load8f_bf(agg + (size_t)row * HS + (k0 - 128));
#pragma unroll
    for (int n = 0; n < 8; n++){
      acc[n] = __builtin_amdgcn_mfma_f32_16x16x32_bf16(af, load8bf(W1t + (size_t)(16 * n + l15) * 256 + k0), acc[n], 0, 0, 0);
    }
  }
#pragma unroll
  for (int n = 0; n < 8; n++){
    int col = 16 * n + l15;
    float bv = b1[col];
#pragma unroll
    for (int r = 0; r < 4; r++){
      int er = lg * 4 + r;
      T1[(er * 128 + col) ^ ((er & 7) << 3)] = f2bff(silu(acc[n][r] + bv));
    }
  }
#pragma unroll
  for (int n = 0; n < 8; n++) acc[n] = zero;
#pragma unroll
  for (int ks = 0; ks < 4; ks++){
    int k0 = ks * 32 + lg * 8;
    bf16x8 af = load8bf(&T1[(l15 * 128 + k0) ^ ((l15 & 7) << 3)]);
#pragma unroll
    for (int n = 0; n < 8; n++){
      acc[n] = __builtin_amdgcn_mfma_f32_16x16x32_bf16(af, load8bf(W2t + (size_t)(16 * n + l15) * HS + k0), acc[n], 0, 0, 0);
    }
  }
  // h_final = h + acc + b2 -> T1 (bf16)
#pragma unroll
  for (int n = 0; n < 8; n++){
    int col = 16 * n + l15;
    float bv = b2[col];
#pragma unroll
    for (int r = 0; r < 4; r++){
      int ro = base + lg * 4 + r;
      int er = lg * 4 + r;
      float hv = h[(size_t)ro * HS + col] + acc[n][r] + bv;
      T1[(er * 128 + col) ^ ((er & 7) << 3)] = f2bff(hv);
    }
  }
  // emb_out GEMM from T1
#pragma unroll
  for (int n = 0; n < 8; n++) acc[n] = zero;
#pragma unroll
  for (int ks = 0; ks < 4; ks++){
    int k0 = ks * 32 + lg * 8;
    bf16x8 af = load8bf(&T1[(l15 * 128 + k0) ^ ((l15 & 7) << 3)]);
#pragma unroll
    for (int n = 0; n < 8; n++){
      acc[n] = __builtin_amdgcn_mfma_f32_16x16x32_bf16(af, load8bf(Eoutt + (size_t)(16 * n + l15) * HS + k0), acc[n], 0, 0, 0);
    }
  }
#pragma unroll
  for (int n = 0; n < 8; n++){
    float bv = eob[16 * n + l15];
#pragma unroll
    for (int r = 0; r < 4; r++) acc[n][r] += bv;
  }
  float scl[4];
#pragma unroll
  for (int r = 0; r < 4; r++){
    float ss = 0.f;
#pragma unroll
    for (int n = 0; n < 8; n++) ss += acc[n][r] * acc[n][r];
#pragma unroll
    for (int o = 1; o < 16; o <<= 1) ss += __shfl_xor(ss, o, 64);
    scl[r] = 1.f / fmaxf(sqrtf(ss), 1e-12f);
  }
#pragma unroll
  for (int r = 0; r < 4; r++){
    int ro = base + lg * 4 + r;
    int g = batch_id[ro];
#pragma unroll
    for (int n = 0; n < 8; n++){
      int col = 16 * n + l15;
      float v = acc[n][r] * scl[r];
      brep[(size_t)ro * HS + col] = v;
      atomicAdd(&gsum[g * HS + col], v);
    }
  }
}

// ---- fused edge kernel v12: 8-wave chan-split with SINGLE 32KB LDS buffer
// (S1 m1 and S2 m aliased; extra barrier between last S1 read and m write).
// LDS ~40KB -> 4 WGs/CU allowance (was 2 at 73KB).
template<int COORD>
__global__ __launch_bounds__(512, 2) void edge_kernel(
    const int* __restrict__ srow, const int* __restrict__ scol,
    const ushortT* __restrict__ sattr,
    const float* __restrict__ x,
    const ushortT* __restrict__ Pbf, const ushortT* __restrict__ Qbf,
    const ushortT* __restrict__ W1ct, const ushortT* __restrict__ W2tp,
    const ushortT* __restrict__ CW1tp,
    const float* __restrict__ b2, const float* __restrict__ cb1,
    const float* __restrict__ cw3,
    float* __restrict__ xacc, float* __restrict__ agg){
  __shared__ float bias_l[3][128];
  __shared__ int   rid_s[128];
  __shared__ float dif_s[COORD ? 128 : 1][3];
  __shared__ float wall[COORD ? 8 : 1][COORD ? 128 : 1];
  __shared__ __align__(16) ushortT SM[128 * 128];   // m1 (phases A/B), then m (32 KB)

  const int t = threadIdx.x;
  const int lane = t & 63;
  const int wv = t >> 6;                    // 0..7 = chan group
  const int l15 = lane & 15, lg = lane >> 4;
  const f32x4 zero = {0.f, 0.f, 0.f, 0.f};

  if (t < 128){
    bias_l[0][t] = b2[t];
    if (COORD){ bias_l[1][t] = cb1[t]; bias_l[2][t] = cw3[t]; }
  }

  // ---------- phase A: m1 for this wave's 16 edges ----------
  const int erow = wv * 16 + l15;           // 0..127
  const int e = blockIdx.x * 128 + erow;
  const int r = srow[e], c = scol[e];
  const float dx = x[r * 3 + 0] - x[c * 3 + 0];
  const float dy = x[r * 3 + 1] - x[c * 3 + 1];
  const float dz = x[r * 3 + 2] - x[c * 3 + 2];
  const float rad = dx * dx + dy * dy + dz * dz;
  if (lg == 0){
    rid_s[erow] = r;
    if (COORD){ dif_s[erow][0] = dx; dif_s[erow][1] = dy; dif_s[erow][2] = dz; }
  }
  ushort8 at8 = __builtin_bit_cast(ushort8, load8bf(sattr + (size_t)e * 32 + lg * 8));
  if (lg == 0) at8[0] = f2bff(rad);
  const bf16x8 atb = __builtin_bit_cast(bf16x8, at8);

#pragma unroll
  for (int ks = 0; ks < 4; ks++){
    f32x4 a0 = __builtin_amdgcn_mfma_f32_16x16x32_bf16(
        load8bf(W1ct + (size_t)(16 * (2 * ks)     + l15) * 32 + lg * 8), atb, zero, 0, 0, 0);
    f32x4 a1 = __builtin_amdgcn_mfma_f32_16x16x32_bf16(
        load8bf(W1ct + (size_t)(16 * (2 * ks + 1) + l15) * 32 + lg * 8), atb, zero, 0, 0, 0);
    ushort8 pv = __builtin_bit_cast(ushort8, load8bf(Pbf + (size_t)r * HS + ks * 32 + lg * 8));
    ushort8 qv = __builtin_bit_cast(ushort8, load8bf(Qbf + (size_t)c * HS + ks * 32 + lg * 8));
    ushort8 af;
#pragma unroll
    for (int j = 0; j < 4; j++)
      af[j] = f2bff(silu(a0[j] + bf2f(pv[j]) + bf2f(qv[j])));
#pragma unroll
    for (int j = 4; j < 8; j++)
      af[j] = f2bff(silu(a1[j - 4] + bf2f(pv[j]) + bf2f(qv[j])));
    int byte = (erow * 256 + ks * 64 + lg * 16) ^ ((erow & 7) << 4);
    *reinterpret_cast<uint4*>(reinterpret_cast<char*>(SM) + byte) = __builtin_bit_cast(uint4, af);
  }
  __syncthreads();   // bar1: SM holds m1; rid/dif/biases ready

  // ---------- phase B: GEMM2, group wv for ALL 128 edges (8 et-tiles) ----------
  f32x4 acc2[8];
#pragma unroll
  for (int et = 0; et < 8; et++) acc2[et] = zero;
#pragma unroll
  for (int ks = 0; ks < 4; ks++){
    bf16x8 wf = load8bf(W2tp + (size_t)(16 * wv + l15) * HS + ks * 32 + lg * 8);
#pragma unroll
    for (int et = 0; et < 8; et++){
      int row2 = et * 16 + l15;
      int byte = (row2 * 256 + ks * 64 + lg * 16) ^ ((row2 & 7) << 4);
      bf16x8 mb = __builtin_bit_cast(bf16x8,
          *reinterpret_cast<const uint4*>(reinterpret_cast<const char*>(SM) + byte));
      acc2[et] = __builtin_amdgcn_mfma_f32_16x16x32_bf16(wf, mb, acc2[et], 0, 0, 0);
    }
  }
  __syncthreads();   // bar2a: all m1 reads complete; SM may be overwritten

  // m-epilogue: silu + b2 -> SM at pi positions for group wv (uint2 per et)
  {
    float4 bv = *reinterpret_cast<const float4*>(&bias_l[0][16 * wv + lg * 4]);
    int pbyte = ((wv >> 1) * 32 + lg * 8 + (wv & 1) * 4) * 2;
#pragma unroll
    for (int et = 0; et < 8; et++){
      ushortT mm[4];
#pragma unroll
      for (int rr = 0; rr < 4; rr++)
        mm[rr] = f2bff(silu(acc2[et][rr] + (&bv.x)[rr]));
      int row2 = et * 16 + l15;
      int byte = (row2 * 256 + pbyte) ^ ((row2 & 7) << 4);
      *reinterpret_cast<uint2*>(reinterpret_cast<char*>(SM) + byte) =
          *reinterpret_cast<uint2*>(mm);
    }
  }
  __syncthreads();   // bar2b: SM holds m

  // ---------- agg flush FIRST (depends only on SM=m): atomics drain under phase C ----------
  {
    const int c0 = c_of_p(2 * lane), c1 = c_of_p(2 * lane + 1);
    float run0 = 0.f, run1 = 0.f;
    int prev = __builtin_amdgcn_readfirstlane(rid_s[wv * 16]);
#pragma unroll
    for (int e2 = 0; e2 < 16; e2++){
      int re = __builtin_amdgcn_readfirstlane(rid_s[wv * 16 + e2]);
      if (re != prev){
        atomicAdd(&agg[(size_t)prev * HS + c0], run0);
        atomicAdd(&agg[(size_t)prev * HS + c1], run1);
        run0 = 0.f; run1 = 0.f; prev = re;
      }
      int row2 = wv * 16 + e2;
      int byte = (row2 * 256 + lane * 4) ^ ((row2 & 7) << 4);
      uint u = *reinterpret_cast<const uint*>(reinterpret_cast<const char*>(SM) + byte);
      run0 += bf2f((ushortT)(u & 0xFFFF));
      run1 += bf2f((ushortT)(u >> 16));
    }
    atomicAdd(&agg[(size_t)prev * HS + c0], run0);
    atomicAdd(&agg[(size_t)prev * HS + c1], run1);
  }

  if (COORD){
    // ---------- phase C: coord GEMM, group wv for ALL 128 edges ----------
    f32x4 acc3[8];
#pragma unroll
    for (int et = 0; et < 8; et++) acc3[et] = zero;
#pragma unroll
    for (int ks = 0; ks < 4; ks++){
      bf16x8 wf = load8bf(CW1tp + (size_t)(16 * wv + l15) * HS + ks * 32 + lg * 8);
#pragma unroll
      for (int et = 0; et < 8; et++){
        int row2 = et * 16 + l15;
        int byte = (row2 * 256 + ks * 64 + lg * 16) ^ ((row2 & 7) << 4);
        bf16x8 mb = __builtin_bit_cast(bf16x8,
            *reinterpret_cast<const uint4*>(reinterpret_cast<const char*>(SM) + byte));
        acc3[et] = __builtin_amdgcn_mfma_f32_16x16x32_bf16(wf, mb, acc3[et], 0, 0, 0);
      }
    }
    // per-wave partial w (16 chans of group wv) -> wall
    {
      float4 cbv = *reinterpret_cast<const float4*>(&bias_l[1][16 * wv + lg * 4]);
      float4 cwv = *reinterpret_cast<const float4*>(&bias_l[2][16 * wv + lg * 4]);
#pragma unroll
      for (int et = 0; et < 8; et++){
        float ws = 0.f;
#pragma unroll
        for (int rr = 0; rr < 4; rr++)
          ws += silu(acc3[et][rr] + (&cbv.x)[rr]) * (&cwv.x)[rr];
        ws += __shfl_xor(ws, 16, 64);
        ws += __shfl_xor(ws, 32, 64);
        if (lg == 0) wall[wv][et * 16 + l15] = ws;
      }
    }
    __syncthreads();   // bar3: wall complete
    // xacc: parallel scatter, per-WG summed w, one atomic per (edge,coord)
    if (t < 384){
      int e2 = t / 3, cd = t % 3;
      float w = 0.f;
#pragma unroll
      for (int wv2 = 0; wv2 < 8; wv2++) w += wall[wv2][e2];
      atomicAdd(&xacc[(size_t)rid_s[e2] * 3 + cd], dif_s[e2][cd] * w);
    }
  }
}

__global__ void norm_graph_kernel(const float* __restrict__ gsum, float* __restrict__ grep){
  int wv = threadIdx.x >> 6, lane = threadIdx.x & 63;
  int g = blockIdx.x * 4 + wv;
  if (g >= N_GRAPHS) return;
  float v0 = gsum[g * HS + lane];
  float v1 = gsum[g * HS + 64 + lane];
  float ss = v0 * v0 + v1 * v1;
#pragma unroll
  for (int o = 1; o < 64; o <<= 1) ss += __shfl_xor(ss, o, 64);
  float s = 1.f / fmaxf(sqrtf(ss), 1e-12f);
  grep[(size_t)g * HS + lane] = v0 * s;
  grep[(size_t)g * HS + 64 + lane] = v1 * s;
}

extern "C" void kernel_launch(void* const* d_in, const int* in_sizes, int n_in,
                              void* d_out, int out_size, void* d_ws, size_t ws_size,
                              hipStream_t stream){
  const float* H         = (const float*)d_in[0];
  const float* Z         = (const float*)d_in[1];
  const int*   block_id  = (const int*)d_in[2];
  const int*   batch_id  = (const int*)d_in[3];
  const int*   edges     = (const int*)d_in[4];
  const float* edge_attr = (const float*)d_in[5];
  const float* emb_in_w  = (const float*)d_in[6];
  const float* emb_in_b  = (const float*)d_in[7];
  const float* emb_out_w = (const float*)d_in[8];
  const float* emb_out_b = (const float*)d_in[9];
  const float* edge_w1   = (const float*)d_in[10];
  const float* edge_b1   = (const float*)d_in[11];
  const float* edge_w2   = (const float*)d_in[12];
  const float* edge_b2   = (const float*)d_in[13];
  const float* node_w1   = (const float*)d_in[14];
  const float* node_b1   = (const float*)d_in[15];
  const float* node_w2   = (const float*)d_in[16];
  const float* node_b2   = (const float*)d_in[17];
  const float* coord_w1  = (const float*)d_in[18];
  const float* coord_b1  = (const float*)d_in[19];
  const float* coord_w3  = (const float*)d_in[20];

  float* out  = (float*)d_out;
  float* Hm   = out;                               // [16000 x 128]
  float* brep = out + (size_t)N_BLOCKS * HS;       // [16000 x 128]
  float* grep = out + (size_t)2 * N_BLOCKS * HS;   // [128 x 128]

  char* base = (char*)d_ws;
  size_t off = 0;
  auto take = [&](size_t bytes) -> char* {
    char* p = base + off;
    off += (bytes + 255) & ~(size_t)255;
    return p;
  };
  float*   x     = (float*)  take((size_t)N_BLOCKS * 3 * 4);
  float*   xacc  = (float*)  take((size_t)N_BLOCKS * 3 * 4);
  float*   h     = (float*)  take((size_t)N_BLOCKS * HS * 4);
  float*   agg   = (float*)  take((size_t)N_BLOCKS * HS * 4);
  float*   gsum  = (float*)  take((size_t)N_GRAPHS * HS * 4);
  int*     bstart= (int*)    take((size_t)(N_BLOCKS + 1) * 4);
  int*     hist  = (int*)    take((size_t)N_BLOCKS * 4);
  int*     estart= (int*)    take((size_t)(N_BLOCKS + 1) * 4);
  int*     ecur  = (int*)    take((size_t)N_BLOCKS * 4);
  int*     srow  = (int*)    take((size_t)N_EDGES * 4);
  int*     scol  = (int*)    take((size_t)N_EDGES * 4);
  ushortT* sattr = (ushortT*)take((size_t)N_EDGES * 32 * 2);
  ushortT* Pbf   = (ushortT*)take((size_t)N_BLOCKS * HS * 2);
  ushortT* Qbf   = (ushortT*)take((size_t)N_BLOCKS * HS * 2);
  ushortT* W1atp = (ushortT*)take((size_t)3 * 128 * 128 * 2);
  ushortT* W1btp = (ushortT*)take((size_t)3 * 128 * 128 * 2);
  ushortT* W1ct  = (ushortT*)take((size_t)3 * 128 * 32 * 2);
  ushortT* W2tp  = (ushortT*)take((size_t)3 * 128 * 128 * 2);
  ushortT* CW1tp = (ushortT*)take((size_t)3 * 128 * 128 * 2);
  ushortT* NW1t  = (ushortT*)take((size_t)3 * 128 * 256 * 2);
  ushortT* NW2t  = (ushortT*)take((size_t)3 * 128 * 128 * 2);
  ushortT* Eint  = (ushortT*)take((size_t)128 * 128 * 2);
  ushortT* Eoutt = (ushortT*)take((size_t)128 * 128 * 2);
  float*   b1p   = (float*)  take((size_t)3 * 128 * 4);

  // merged prep (weights + bias perm + hist zero)
  PrepParams P;
  P.ew1 = edge_w1; P.ew2 = edge_w2; P.cw1 = coord_w1;
  P.nw1 = node_w1; P.nw2 = node_w2; P.ei = emb_in_w; P.eo = emb_out_w;
  P.eb1 = edge_b1;
  P.W1atp = W1atp; P.W1btp = W1btp; P.W1ct = W1ct; P.W2tp = W2tp; P.CW1tp = CW1tp;
  P.NW1t = NW1t; P.NW2t = NW2t; P.Eint = Eint; P.Eoutt = Eoutt;
  P.b1p = b1p; P.hist = hist;
  prep_kernel<<<(PREP_TOTAL + 255) / 256, 256, 0, stream>>>(P);

  hist_bstart_kernel<<<N_EDGES / 256 + (N_BLOCKS + 1 + 255) / 256, 256, 0, stream>>>(
      edges, hist, block_id, bstart);
  scan_kernel<<<1, 1024, 0, stream>>>(hist, estart, ecur);
  scatter_kernel<<<N_EDGES / 256, 256, 0, stream>>>(edges, edge_attr, ecur, srow, scol, sattr);
  pool_kernel<<<N_BLOCKS, 128, 0, stream>>>(H, Z, bstart, Hm, x, gsum);

  // h = Hm @ emb_in_w + b ; P/Q layer 0 ; zero agg/xacc
  gemm_pq_kernel<<<N_BLOCKS / 16, 64, 0, stream>>>(Hm, Eint, emb_in_b, h,
                                                   W1atp, W1btp, b1p, Pbf, Qbf, agg, xacc);

  for (int l = 0; l < 3; l++){
    if (l < 2){
      edge_kernel<1><<<N_EDGES / 128, 512, 0, stream>>>(
          srow, scol, sattr, x, Pbf, Qbf,
          W1ct + (size_t)l * 128 * 32, W2tp + (size_t)l * 128 * 128, CW1tp + (size_t)l * 128 * 128,
          edge_b2 + l * 128, coord_b1 + l * 128, coord_w3 + l * 128,
          xacc, agg);
      node_pq_kernel<<<N_BLOCKS / 16, 64, 0, stream>>>(
          h, agg, NW1t + (size_t)l * 128 * 256, NW2t + (size_t)l * 128 * 128,
          node_b1 + l * 128, node_b2 + l * 128,
          W1atp + (size_t)(l + 1) * 128 * 128, W1btp + (size_t)(l + 1) * 128 * 128,
          b1p + (l + 1) * 128, Pbf, Qbf, x, xacc, estart);
    } else {
      edge_kernel<0><<<N_EDGES / 128, 512, 0, stream>>>(
          srow, scol, sattr, x, Pbf, Qbf,
          W1ct + (size_t)l * 128 * 32, W2tp + (size_t)l * 128 * 128, CW1tp + (size_t)l * 128 * 128,
          edge_b2 + l * 128, coord_b1 + l * 128, coord_w3 + l * 128,
          xacc, agg);
      node_emb_kernel<<<N_BLOCKS / 16, 64, 0, stream>>>(
          h, agg, NW1t + (size_t)l * 128 * 256, NW2t + (size_t)l * 128 * 128,
          node_b1 + l * 128, node_b2 + l * 128,
          Eoutt, emb_out_b, batch_id, brep, gsum);
    }
  }

  norm_graph_kernel<<<N_GRAPHS / 4, 256, 0, stream>>>(gsum, grep);
}

// Round 17
// 471.217 us; speedup vs baseline: 1.1503x; 1.0184x over previous
//
#include <hip/hip_runtime.h>

#define N_ATOMS  80000
#define N_BLOCKS 16000
#define N_EDGES  320000
#define N_GRAPHS 128
#define HS       128

typedef unsigned short ushortT;
typedef __attribute__((ext_vector_type(8))) __bf16 bf16x8;
typedef __attribute__((ext_vector_type(8))) unsigned short ushort8;
typedef __attribute__((ext_vector_type(4))) float f32x4;

__device__ __forceinline__ unsigned short f2bf(float f){
  unsigned int u = __builtin_bit_cast(unsigned int, f);
  u = (u + 0x7FFFu + ((u >> 16) & 1u)) >> 16;
  return (unsigned short)u;
}
__device__ __forceinline__ ushortT f2bff(float f){
  __bf16 b = (__bf16)f;
  return __builtin_bit_cast(ushortT, b);
}
__device__ __forceinline__ float bf2f(ushortT u){
  unsigned int v = ((unsigned int)u) << 16;
  return __builtin_bit_cast(float, v);
}
__device__ __forceinline__ bf16x8 load8bf(const ushortT* p){
  uint4 u = *reinterpret_cast<const uint4*>(p);
  return __builtin_bit_cast(bf16x8, u);
}
__device__ __forceinline__ bf16x8 load8f_bf(const float* p){
  float4 a = *reinterpret_cast<const float4*>(p);
  float4 b = *reinterpret_cast<const float4*>(p + 4);
  ushort8 u = { f2bff(a.x), f2bff(a.y), f2bff(a.z), f2bff(a.w),
                f2bff(b.x), f2bff(b.y), f2bff(b.z), f2bff(b.w) };
  return __builtin_bit_cast(bf16x8, u);
}
// fast silu: v * rcp(1+exp(-v))
__device__ __forceinline__ float silu(float v){
  return v * __builtin_amdgcn_rcpf(1.f + __expf(-v));
}

// pi-permutation: C-fragment register (n,r) of lane-group lg holds natural col
// c = 16n + lg*4 + r; B-fragment position p = ks*32 + lg*8 + j, n = 2ks + (j>>2), r = j&3.
__device__ __forceinline__ int c_of_p(int p){
  int ks = p >> 5, lg = (p >> 3) & 3, j = p & 7;
  return 16 * (ks * 2 + (j >> 2)) + lg * 4 + (j & 3);
}

// ---- merged prep: all weight transposes + bias perm + hist zero
struct PrepParams {
  const float* ew1; const float* ew2; const float* cw1;
  const float* nw1; const float* nw2; const float* ei; const float* eo;
  const float* eb1;
  ushortT* W1atp; ushortT* W1btp; ushortT* W1ct; ushortT* W2tp; ushortT* CW1tp;
  ushortT* NW1t; ushortT* NW2t; ushortT* Eint; ushortT* Eoutt;
  float* b1p; int* hist;
};

__device__ __forceinline__ void tcvt(int idx, const float* __restrict__ src,
                                     ushortT* __restrict__ dst,
                                     int srcK, int row_off, int K, int N, int Kpad,
                                     int pn, int pk){
  int k = idx % Kpad;
  int rem = idx / Kpad;
  int n = rem % N;
  int l = rem / N;
  float v = 0.f;
  if (k < K){
    int kk = pk ? c_of_p(k) : k;
    int nn = pn ? c_of_p(n) : n;
    v = src[((size_t)l * srcK + row_off + kk) * N + nn];
  }
  dst[idx] = f2bf(v);
}

#define PREP_TOTAL (49152*5 + 12288 + 98304 + 16384*2 + 16000 + 384)

__global__ void prep_kernel(PrepParams P){
  int idx = blockIdx.x * 256 + threadIdx.x;
  if (idx < 49152){ tcvt(idx, P.ew1, P.W1atp, 273,   0, 128, 128, 128, 1, 0); return; }
  idx -= 49152;
  if (idx < 49152){ tcvt(idx, P.ew1, P.W1btp, 273, 128, 128, 128, 128, 1, 0); return; }
  idx -= 49152;
  if (idx < 12288){ tcvt(idx, P.ew1, P.W1ct,  273, 256,  17, 128,  32, 0, 0); return; }
  idx -= 12288;
  if (idx < 49152){ tcvt(idx, P.ew2, P.W2tp,  128,   0, 128, 128, 128, 0, 1); return; }
  idx -= 49152;
  if (idx < 49152){ tcvt(idx, P.cw1, P.CW1tp, 128,   0, 128, 128, 128, 0, 1); return; }
  idx -= 49152;
  if (idx < 98304){ tcvt(idx, P.nw1, P.NW1t,  256,   0, 256, 128, 256, 0, 0); return; }
  idx -= 98304;
  if (idx < 49152){ tcvt(idx, P.nw2, P.NW2t,  128,   0, 128, 128, 128, 0, 0); return; }
  idx -= 49152;
  if (idx < 16384){ tcvt(idx, P.ei,  P.Eint,  128,   0, 128, 128, 128, 0, 0); return; }
  idx -= 16384;
  if (idx < 16384){ tcvt(idx, P.eo,  P.Eoutt, 128,   0, 128, 128, 128, 0, 0); return; }
  idx -= 16384;
  if (idx < 16000){ P.hist[idx] = 0; return; }
  idx -= 16000;
  if (idx < 384){ int l = idx >> 7, p = idx & 127; P.b1p[idx] = P.eb1[l * 128 + c_of_p(p)]; }
}

// ---- hist + block_start merged
__global__ void hist_bstart_kernel(const int* __restrict__ edges, int* __restrict__ hist,
                                   const int* __restrict__ bid, int* __restrict__ bstart){
  int b = blockIdx.x;
  if (b < N_EDGES / 256){
    int e = b * 256 + threadIdx.x;
    atomicAdd(&hist[edges[e]], 1);
  } else {
    int i = (b - N_EDGES / 256) * 256 + threadIdx.x;
    if (i <= N_BLOCKS){
      int lo = 0, hi = N_ATOMS;
      while (lo < hi){ int mid = (lo + hi) >> 1; if (bid[mid] < i) lo = mid + 1; else hi = mid; }
      bstart[i] = lo;
    }
  }
}

__global__ __launch_bounds__(1024) void scan_kernel(const int* __restrict__ hist,
                                                    int* __restrict__ estart,
                                                    int* __restrict__ ecur){
  __shared__ int ps[1024];
  int t = threadIdx.x;
  const int chunk = (N_BLOCKS + 1023) / 1024;
  int lo = t * chunk, hi = lo + chunk;
  if (hi > N_BLOCKS) hi = N_BLOCKS;
  if (lo > N_BLOCKS) lo = N_BLOCKS;
  int s = 0;
  for (int i = lo; i < hi; i++) s += hist[i];
  ps[t] = s;
  __syncthreads();
  for (int off = 1; off < 1024; off <<= 1){
    int v = (t >= off) ? ps[t - off] : 0;
    __syncthreads();
    ps[t] += v;
    __syncthreads();
  }
  int base = (t == 0) ? 0 : ps[t - 1];
  for (int i = lo; i < hi; i++){ estart[i] = base; ecur[i] = base; base += hist[i]; }
  if (t == 1023) estart[N_BLOCKS] = base;
}

// scatter into sorted order; sedge packed int2; sattr padded 32 u16/edge
__global__ void scatter_kernel(const int* __restrict__ edges, const float* __restrict__ attr,
                               int* __restrict__ ecur,
                               int2* __restrict__ sedge,
                               ushortT* __restrict__ sattr){
  int e = blockIdx.x * 256 + threadIdx.x;
  if (e >= N_EDGES) return;
  int r = edges[e], c = edges[N_EDGES + e];
  int p = atomicAdd(&ecur[r], 1);
  sedge[p] = make_int2(r, c);
  ushortT buf[32];
  buf[0] = 0;
#pragma unroll
  for (int k = 0; k < 16; k++) buf[k + 1] = f2bf(attr[(size_t)e * 16 + k]);
#pragma unroll
  for (int k = 17; k < 32; k++) buf[k] = 0;
#pragma unroll
  for (int k = 0; k < 16; k++)
    reinterpret_cast<uint*>(sattr + (size_t)p * 32)[k] = reinterpret_cast<uint*>(buf)[k];
}

// x stored stride-4 (padded) for single-16B gathers
__global__ void pool_kernel(const float* __restrict__ H, const float* __restrict__ Z,
                            const int* __restrict__ start,
                            float* __restrict__ Hm, float* __restrict__ x,
                            float* __restrict__ gsum){
  int b = blockIdx.x;
  int t = threadIdx.x;            // 128 threads
  if (b < 128) gsum[b * 128 + t] = 0.f;
  int s = start[b], e = start[b + 1];
  float inv = 1.f / (float)((e - s) > 0 ? (e - s) : 1);
  float sum = 0.f;
  for (int a = s; a < e; a++) sum += H[(size_t)a * HS + t];
  Hm[(size_t)b * HS + t] = sum * inv;
  if (t < 4){
    float sz = 0.f;
    if (t < 3) for (int a = s; a < e; a++) sz += Z[a * 3 + t];
    x[b * 4 + t] = sz * inv;
  }
}

// ---- fused emb_in GEMM + layer-0 P/Q + zero agg/xacc slices (1-wave blocks, 1000)
__global__ __launch_bounds__(64) void gemm_pq_kernel(
    const float* __restrict__ A,
    const ushortT* __restrict__ Wt, const float* __restrict__ bias,
    float* __restrict__ Cf,
    const ushortT* __restrict__ Wa, const ushortT* __restrict__ Wb,
    const float* __restrict__ b1p,
    ushortT* __restrict__ Pbf, ushortT* __restrict__ Qbf,
    float* __restrict__ agg, float* __restrict__ xacc){
  __shared__ __align__(16) ushortT T1[2048];
  int lane = threadIdx.x;
  int l15 = lane & 15, lg = lane >> 4;
  int base = blockIdx.x * 16;
  int row = base + l15;
  {
    float4 z4 = {0.f, 0.f, 0.f, 0.f};
    float4* aggp = reinterpret_cast<float4*>(agg + (size_t)blockIdx.x * 16 * HS);
#pragma unroll
    for (int i = 0; i < 8; i++) aggp[lane + 64 * i] = z4;
    if (lane < 48) xacc[blockIdx.x * 48 + lane] = 0.f;
  }
  f32x4 zero = {0.f, 0.f, 0.f, 0.f};
  f32x4 acc[8];
#pragma unroll
  for (int n = 0; n < 8; n++) acc[n] = zero;
#pragma unroll
  for (int ks = 0; ks < 4; ks++){
    int k0 = ks * 32 + lg * 8;
    bf16x8 af = load8f_bf(A + (size_t)row * HS + k0);
#pragma unroll
    for (int n = 0; n < 8; n++){
      bf16x8 bf = load8bf(Wt + (size_t)(16 * n + l15) * HS + k0);
      acc[n] = __builtin_amdgcn_mfma_f32_16x16x32_bf16(af, bf, acc[n], 0, 0, 0);
    }
  }
#pragma unroll
  for (int n = 0; n < 8; n++){
    int col = 16 * n + l15;
    float bv = bias[col];
#pragma unroll
    for (int r = 0; r < 4; r++){
      int ro = base + lg * 4 + r;
      int er = lg * 4 + r;
      float hv = acc[n][r] + bv;
      Cf[(size_t)ro * HS + col] = hv;
      T1[(er * 128 + col) ^ ((er & 7) << 3)] = f2bff(hv);
    }
  }
  f32x4 accp[8], accq[8];
#pragma unroll
  for (int n = 0; n < 8; n++){ accp[n] = zero; accq[n] = zero; }
#pragma unroll
  for (int ks = 0; ks < 4; ks++){
    int k0 = ks * 32 + lg * 8;
    bf16x8 af = load8bf(&T1[(l15 * 128 + k0) ^ ((l15 & 7) << 3)]);
#pragma unroll
    for (int n = 0; n < 8; n++){
      accp[n] = __builtin_amdgcn_mfma_f32_16x16x32_bf16(af, load8bf(Wa + (size_t)(16 * n + l15) * HS + k0), accp[n], 0, 0, 0);
      accq[n] = __builtin_amdgcn_mfma_f32_16x16x32_bf16(af, load8bf(Wb + (size_t)(16 * n + l15) * HS + k0), accq[n], 0, 0, 0);
    }
  }
#pragma unroll
  for (int n = 0; n < 8; n++){
    int col = 16 * n + l15;
    float bv = b1p[col];
#pragma unroll
    for (int r = 0; r < 4; r++){
      int ro = base + lg * 4 + r;
      Pbf[(size_t)ro * HS + col] = f2bff(accp[n][r] + bv);
      Qbf[(size_t)ro * HS + col] = f2bff(accq[n][r]);
    }
  }
}

// ---- fused node MLP + x_update + zero-next + next-layer P/Q (1-wave blocks, 1000)
__global__ __launch_bounds__(64) void node_pq_kernel(
    float* __restrict__ h, float* __restrict__ agg,
    const ushortT* __restrict__ W1t, const ushortT* __restrict__ W2t,
    const float* __restrict__ b1, const float* __restrict__ b2,
    const ushortT* __restrict__ Wa, const ushortT* __restrict__ Wb,
    const float* __restrict__ b1p,
    ushortT* __restrict__ Pbf, ushortT* __restrict__ Qbf,
    float* __restrict__ x, float* __restrict__ xacc, const int* __restrict__ estart){
  __shared__ __align__(16) ushortT T1[2048];
  int lane = threadIdx.x;
  int l15 = lane & 15, lg = lane >> 4;
  int base = blockIdx.x * 16;
  int row = base + l15;
  f32x4 zero = {0.f, 0.f, 0.f, 0.f};

  if (lane < 48){
    int i = blockIdx.x * 48 + lane;
    int b = i / 3, cd = i % 3;
    int cnt = estart[b + 1] - estart[b];
    x[b * 4 + cd] += xacc[i] / (float)(cnt > 0 ? cnt : 1);
    xacc[i] = 0.f;
  }

  f32x4 acc[8];
#pragma unroll
  for (int n = 0; n < 8; n++) acc[n] = zero;
#pragma unroll
  for (int ks = 0; ks < 8; ks++){
    int k0 = ks * 32 + lg * 8;
    bf16x8 af = (k0 < 128) ? load8f_bf(h + (size_t)row * HS + k0)
                           : load8f_bf(agg + (size_t)row * HS + (k0 - 128));
#pragma unroll
    for (int n = 0; n < 8; n++){
      acc[n] = __builtin_amdgcn_mfma_f32_16x16x32_bf16(af, load8bf(W1t + (size_t)(16 * n + l15) * 256 + k0), acc[n], 0, 0, 0);
    }
  }
  // drain agg reads then zero this block's agg slice
  __syncthreads();
  {
    float4 z4 = {0.f, 0.f, 0.f, 0.f};
    float4* aggp = reinterpret_cast<float4*>(agg + (size_t)blockIdx.x * 16 * HS);
#pragma unroll
    for (int i = 0; i < 8; i++) aggp[lane + 64 * i] = z4;
  }
#pragma unroll
  for (int n = 0; n < 8; n++){
    int col = 16 * n + l15;
    float bv = b1[col];
#pragma unroll
    for (int r = 0; r < 4; r++){
      int er = lg * 4 + r;
      T1[(er * 128 + col) ^ ((er & 7) << 3)] = f2bff(silu(acc[n][r] + bv));
    }
  }
#pragma unroll
  for (int n = 0; n < 8; n++) acc[n] = zero;
#pragma unroll
  for (int ks = 0; ks < 4; ks++){
    int k0 = ks * 32 + lg * 8;
    bf16x8 af = load8bf(&T1[(l15 * 128 + k0) ^ ((l15 & 7) << 3)]);
#pragma unroll
    for (int n = 0; n < 8; n++){
      acc[n] = __builtin_amdgcn_mfma_f32_16x16x32_bf16(af, load8bf(W2t + (size_t)(16 * n + l15) * HS + k0), acc[n], 0, 0, 0);
    }
  }
#pragma unroll
  for (int n = 0; n < 8; n++){
    int col = 16 * n + l15;
    float bv = b2[col];
#pragma unroll
    for (int r = 0; r < 4; r++){
      int ro = base + lg * 4 + r;
      int er = lg * 4 + r;
      float hv = h[(size_t)ro * HS + col] + acc[n][r] + bv;
      h[(size_t)ro * HS + col] = hv;
      T1[(er * 128 + col) ^ ((er & 7) << 3)] = f2bff(hv);
    }
  }
  // next-layer P/Q from T1
  f32x4 accp[8], accq[8];
#pragma unroll
  for (int n = 0; n < 8; n++){ accp[n] = zero; accq[n] = zero; }
#pragma unroll
  for (int ks = 0; ks < 4; ks++){
    int k0 = ks * 32 + lg * 8;
    bf16x8 af = load8bf(&T1[(l15 * 128 + k0) ^ ((l15 & 7) << 3)]);
#pragma unroll
    for (int n = 0; n < 8; n++){
      accp[n] = __builtin_amdgcn_mfma_f32_16x16x32_bf16(af, load8bf(Wa + (size_t)(16 * n + l15) * HS + k0), accp[n], 0, 0, 0);
      accq[n] = __builtin_amdgcn_mfma_f32_16x16x32_bf16(af, load8bf(Wb + (size_t)(16 * n + l15) * HS + k0), accq[n], 0, 0, 0);
    }
  }
#pragma unroll
  for (int n = 0; n < 8; n++){
    int col = 16 * n + l15;
    float bv = b1p[col];
#pragma unroll
    for (int r = 0; r < 4; r++){
      int ro = base + lg * 4 + r;
      Pbf[(size_t)ro * HS + col] = f2bff(accp[n][r] + bv);
      Qbf[(size_t)ro * HS + col] = f2bff(accq[n][r]);
    }
  }
}

// ---- fused final node MLP + emb_out GEMM + normalize + graph accumulate (1-wave, 1000)
__global__ __launch_bounds__(64) void node_emb_kernel(
    const float* __restrict__ h, const float* __restrict__ agg,
    const ushortT* __restrict__ W1t, const ushortT* __restrict__ W2t,
    const float* __restrict__ b1, const float* __restrict__ b2,
    const ushortT* __restrict__ Eoutt, const float* __restrict__ eob,
    const int* __restrict__ batch_id,
    float* __restrict__ brep, float* __restrict__ gsum){
  __shared__ __align__(16) ushortT T1[2048];
  int lane = threadIdx.x;
  int l15 = lane & 15, lg = lane >> 4;
  int base = blockIdx.x * 16;
  int row = base + l15;
  f32x4 zero = {0.f, 0.f, 0.f, 0.f};

  f32x4 acc[8];
#pragma unroll
  for (int n = 0; n < 8; n++) acc[n] = zero;
#pragma unroll
  for (int ks = 0; ks < 8; ks++){
    int k0 = ks * 32 + lg * 8;
    bf16x8 af = (k0 < 128) ? load8f_bf(h + (size_t)row * HS + k0)
                           : load8f_bf(agg + (size_t)row * HS + (k0 - 128));
#pragma unroll
    for (int n = 0; n < 8; n++){
      acc[n] = __builtin_amdgcn_mfma_f32_16x16x32_bf16(af, load8bf(W1t + (size_t)(16 * n + l15) * 256 + k0), acc[n], 0, 0, 0);
    }
  }
#pragma unroll
  for (int n = 0; n < 8; n++){
    int col = 16 * n + l15;
    float bv = b1[col];
#pragma unroll
    for (int r = 0; r < 4; r++){
      int er = lg * 4 + r;
      T1[(er * 128 + col) ^ ((er & 7) << 3)] = f2bff(silu(acc[n][r] + bv));
    }
  }
#pragma unroll
  for (int n = 0; n < 8; n++) acc[n] = zero;
#pragma unroll
  for (int ks = 0; ks < 4; ks++){
    int k0 = ks * 32 + lg * 8;
    bf16x8 af = load8bf(&T1[(l15 * 128 + k0) ^ ((l15 & 7) << 3)]);
#pragma unroll
    for (int n = 0; n < 8; n++){
      acc[n] = __builtin_amdgcn_mfma_f32_16x16x32_bf16(af, load8bf(W2t + (size_t)(16 * n + l15) * HS + k0), acc[n], 0, 0, 0);
    }
  }
  // h_final = h + acc + b2 -> T1 (bf16)
#pragma unroll
  for (int n = 0; n < 8; n++){
    int col = 16 * n + l15;
    float bv = b2[col];
#pragma unroll
    for (int r = 0; r < 4; r++){
      int ro = base + lg * 4 + r;
      int er = lg * 4 + r;
      float hv = h[(size_t)ro * HS + col] + acc[n][r] + bv;
      T1[(er * 128 + col) ^ ((er & 7) << 3)] = f2bff(hv);
    }
  }
  // emb_out GEMM from T1
#pragma unroll
  for (int n = 0; n < 8; n++) acc[n] = zero;
#pragma unroll
  for (int ks = 0; ks < 4; ks++){
    int k0 = ks * 32 + lg * 8;
    bf16x8 af = load8bf(&T1[(l15 * 128 + k0) ^ ((l15 & 7) << 3)]);
#pragma unroll
    for (int n = 0; n < 8; n++){
      acc[n] = __builtin_amdgcn_mfma_f32_16x16x32_bf16(af, load8bf(Eoutt + (size_t)(16 * n + l15) * HS + k0), acc[n], 0, 0, 0);
    }
  }
#pragma unroll
  for (int n = 0; n < 8; n++){
    float bv = eob[16 * n + l15];
#pragma unroll
    for (int r = 0; r < 4; r++) acc[n][r] += bv;
  }
  float scl[4];
#pragma unroll
  for (int r = 0; r < 4; r++){
    float ss = 0.f;
#pragma unroll
    for (int n = 0; n < 8; n++) ss += acc[n][r] * acc[n][r];
#pragma unroll
    for (int o = 1; o < 16; o <<= 1) ss += __shfl_xor(ss, o, 64);
    scl[r] = 1.f / fmaxf(sqrtf(ss), 1e-12f);
  }
#pragma unroll
  for (int r = 0; r < 4; r++){
    int ro = base + lg * 4 + r;
    int g = batch_id[ro];
#pragma unroll
    for (int n = 0; n < 8; n++){
      int col = 16 * n + l15;
      float v = acc[n][r] * scl[r];
      brep[(size_t)ro * HS + col] = v;
      atomicAdd(&gsum[g * HS + col], v);
    }
  }
}

// ---- fused edge kernel v13: 8-wave chan-split, aliased LDS, packed int2 edges +
// stride-4 x (phase-A dependent VMEM chain 10 -> 5 ops/lane).
template<int COORD>
__global__ __launch_bounds__(512, 2) void edge_kernel(
    const int2* __restrict__ sedge,
    const ushortT* __restrict__ sattr,
    const float* __restrict__ x,
    const ushortT* __restrict__ Pbf, const ushortT* __restrict__ Qbf,
    const ushortT* __restrict__ W1ct, const ushortT* __restrict__ W2tp,
    const ushortT* __restrict__ CW1tp,
    const float* __restrict__ b2, const float* __restrict__ cb1,
    const float* __restrict__ cw3,
    float* __restrict__ xacc, float* __restrict__ agg){
  __shared__ float bias_l[3][128];
  __shared__ int   rid_s[128];
  __shared__ float dif_s[COORD ? 128 : 1][3];
  __shared__ float wall[COORD ? 8 : 1][COORD ? 128 : 1];
  __shared__ __align__(16) ushortT SM[128 * 128];   // m1 (phases A/B), then m (32 KB)

  const int t = threadIdx.x;
  const int lane = t & 63;
  const int wv = t >> 6;                    // 0..7 = chan group
  const int l15 = lane & 15, lg = lane >> 4;
  const f32x4 zero = {0.f, 0.f, 0.f, 0.f};

  if (t < 128){
    bias_l[0][t] = b2[t];
    if (COORD){ bias_l[1][t] = cb1[t]; bias_l[2][t] = cw3[t]; }
  }

  // ---------- phase A: m1 for this wave's 16 edges ----------
  const int erow = wv * 16 + l15;           // 0..127
  const int e = blockIdx.x * 128 + erow;
  const int2 rc = sedge[e];
  const int r = rc.x, c = rc.y;
  const float4 xr = *reinterpret_cast<const float4*>(x + r * 4);
  const float4 xc = *reinterpret_cast<const float4*>(x + c * 4);
  const float dx = xr.x - xc.x;
  const float dy = xr.y - xc.y;
  const float dz = xr.z - xc.z;
  const float rad = dx * dx + dy * dy + dz * dz;
  if (lg == 0){
    rid_s[erow] = r;
    if (COORD){ dif_s[erow][0] = dx; dif_s[erow][1] = dy; dif_s[erow][2] = dz; }
  }
  ushort8 at8 = __builtin_bit_cast(ushort8, load8bf(sattr + (size_t)e * 32 + lg * 8));
  if (lg == 0) at8[0] = f2bff(rad);
  const bf16x8 atb = __builtin_bit_cast(bf16x8, at8);

#pragma unroll
  for (int ks = 0; ks < 4; ks++){
    f32x4 a0 = __builtin_amdgcn_mfma_f32_16x16x32_bf16(
        load8bf(W1ct + (size_t)(16 * (2 * ks)     + l15) * 32 + lg * 8), atb, zero, 0, 0, 0);
    f32x4 a1 = __builtin_amdgcn_mfma_f32_16x16x32_bf16(
        load8bf(W1ct + (size_t)(16 * (2 * ks + 1) + l15) * 32 + lg * 8), atb, zero, 0, 0, 0);
    ushort8 pv = __builtin_bit_cast(ushort8, load8bf(Pbf + (size_t)r * HS + ks * 32 + lg * 8));
    ushort8 qv = __builtin_bit_cast(ushort8, load8bf(Qbf + (size_t)c * HS + ks * 32 + lg * 8));
    ushort8 af;
#pragma unroll
    for (int j = 0; j < 4; j++)
      af[j] = f2bff(silu(a0[j] + bf2f(pv[j]) + bf2f(qv[j])));
#pragma unroll
    for (int j = 4; j < 8; j++)
      af[j] = f2bff(silu(a1[j - 4] + bf2f(pv[j]) + bf2f(qv[j])));
    int byte = (erow * 256 + ks * 64 + lg * 16) ^ ((erow & 7) << 4);
    *reinterpret_cast<uint4*>(reinterpret_cast<char*>(SM) + byte) = __builtin_bit_cast(uint4, af);
  }
  __syncthreads();   // bar1: SM holds m1; rid/dif/biases ready

  // ---------- phase B: GEMM2, group wv for ALL 128 edges (8 et-tiles) ----------
  f32x4 acc2[8];
#pragma unroll
  for (int et = 0; et < 8; et++) acc2[et] = zero;
#pragma unroll
  for (int ks = 0; ks < 4; ks++){
    bf16x8 wf = load8bf(W2tp + (size_t)(16 * wv + l15) * HS + ks * 32 + lg * 8);
#pragma unroll
    for (int et = 0; et < 8; et++){
      int row2 = et * 16 + l15;
      int byte = (row2 * 256 + ks * 64 + lg * 16) ^ ((row2 & 7) << 4);
      bf16x8 mb = __builtin_bit_cast(bf16x8,
          *reinterpret_cast<const uint4*>(reinterpret_cast<const char*>(SM) + byte));
      acc2[et] = __builtin_amdgcn_mfma_f32_16x16x32_bf16(wf, mb, acc2[et], 0, 0, 0);
    }
  }
  __syncthreads();   // bar2a: all m1 reads complete; SM may be overwritten

  // m-epilogue: silu + b2 -> SM at pi positions for group wv (uint2 per et)
  {
    float4 bv = *reinterpret_cast<const float4*>(&bias_l[0][16 * wv + lg * 4]);
    int pbyte = ((wv >> 1) * 32 + lg * 8 + (wv & 1) * 4) * 2;
#pragma unroll
    for (int et = 0; et < 8; et++){
      ushortT mm[4];
#pragma unroll
      for (int rr = 0; rr < 4; rr++)
        mm[rr] = f2bff(silu(acc2[et][rr] + (&bv.x)[rr]));
      int row2 = et * 16 + l15;
      int byte = (row2 * 256 + pbyte) ^ ((row2 & 7) << 4);
      *reinterpret_cast<uint2*>(reinterpret_cast<char*>(SM) + byte) =
          *reinterpret_cast<uint2*>(mm);
    }
  }
  __syncthreads();   // bar2b: SM holds m

  // ---------- agg flush FIRST (depends only on SM=m): atomics drain under phase C ----------
  {
    const int c0 = c_of_p(2 * lane), c1 = c_of_p(2 * lane + 1);
    float run0 = 0.f, run1 = 0.f;
    int prev = __builtin_amdgcn_readfirstlane(rid_s[wv * 16]);
#pragma unroll
    for (int e2 = 0; e2 < 16; e2++){
      int re = __builtin_amdgcn_readfirstlane(rid_s[wv * 16 + e2]);
      if (re != prev){
        atomicAdd(&agg[(size_t)prev * HS + c0], run0);
        atomicAdd(&agg[(size_t)prev * HS + c1], run1);
        run0 = 0.f; run1 = 0.f; prev = re;
      }
      int row2 = wv * 16 + e2;
      int byte = (row2 * 256 + lane * 4) ^ ((row2 & 7) << 4);
      uint u = *reinterpret_cast<const uint*>(reinterpret_cast<const char*>(SM) + byte);
      run0 += bf2f((ushortT)(u & 0xFFFF));
      run1 += bf2f((ushortT)(u >> 16));
    }
    atomicAdd(&agg[(size_t)prev * HS + c0], run0);
    atomicAdd(&agg[(size_t)prev * HS + c1], run1);
  }

  if (COORD){
    // ---------- phase C: coord GEMM, group wv for ALL 128 edges ----------
    f32x4 acc3[8];
#pragma unroll
    for (int et = 0; et < 8; et++) acc3[et] = zero;
#pragma unroll
    for (int ks = 0; ks < 4; ks++){
      bf16x8 wf = load8bf(CW1tp + (size_t)(16 * wv + l15) * HS + ks * 32 + lg * 8);
#pragma unroll
      for (int et = 0; et < 8; et++){
        int row2 = et * 16 + l15;
        int byte = (row2 * 256 + ks * 64 + lg * 16) ^ ((row2 & 7) << 4);
        bf16x8 mb = __builtin_bit_cast(bf16x8,
            *reinterpret_cast<const uint4*>(reinterpret_cast<const char*>(SM) + byte));
        acc3[et] = __builtin_amdgcn_mfma_f32_16x16x32_bf16(wf, mb, acc3[et], 0, 0, 0);
      }
    }
    // per-wave partial w (16 chans of group wv) -> wall
    {
      float4 cbv = *reinterpret_cast<const float4*>(&bias_l[1][16 * wv + lg * 4]);
      float4 cwv = *reinterpret_cast<const float4*>(&bias_l[2][16 * wv + lg * 4]);
#pragma unroll
      for (int et = 0; et < 8; et++){
        float ws = 0.f;
#pragma unroll
        for (int rr = 0; rr < 4; rr++)
          ws += silu(acc3[et][rr] + (&cbv.x)[rr]) * (&cwv.x)[rr];
        ws += __shfl_xor(ws, 16, 64);
        ws += __shfl_xor(ws, 32, 64);
        if (lg == 0) wall[wv][et * 16 + l15] = ws;
      }
    }
    __syncthreads();   // bar3: wall complete
    // xacc: parallel scatter, per-WG summed w, one atomic per (edge,coord)
    if (t < 384){
      int e2 = t / 3, cd = t % 3;
      float w = 0.f;
#pragma unroll
      for (int wv2 = 0; wv2 < 8; wv2++) w += wall[wv2][e2];
      atomicAdd(&xacc[(size_t)rid_s[e2] * 3 + cd], dif_s[e2][cd] * w);
    }
  }
}

__global__ void norm_graph_kernel(const float* __restrict__ gsum, float* __restrict__ grep){
  int wv = threadIdx.x >> 6, lane = threadIdx.x & 63;
  int g = blockIdx.x * 4 + wv;
  if (g >= N_GRAPHS) return;
  float v0 = gsum[g * HS + lane];
  float v1 = gsum[g * HS + 64 + lane];
  float ss = v0 * v0 + v1 * v1;
#pragma unroll
  for (int o = 1; o < 64; o <<= 1) ss += __shfl_xor(ss, o, 64);
  float s = 1.f / fmaxf(sqrtf(ss), 1e-12f);
  grep[(size_t)g * HS + lane] = v0 * s;
  grep[(size_t)g * HS + 64 + lane] = v1 * s;
}

extern "C" void kernel_launch(void* const* d_in, const int* in_sizes, int n_in,
                              void* d_out, int out_size, void* d_ws, size_t ws_size,
                              hipStream_t stream){
  const float* H         = (const float*)d_in[0];
  const float* Z         = (const float*)d_in[1];
  const int*   block_id  = (const int*)d_in[2];
  const int*   batch_id  = (const int*)d_in[3];
  const int*   edges     = (const int*)d_in[4];
  const float* edge_attr = (const float*)d_in[5];
  const float* emb_in_w  = (const float*)d_in[6];
  const float* emb_in_b  = (const float*)d_in[7];
  const float* emb_out_w = (const float*)d_in[8];
  const float* emb_out_b = (const float*)d_in[9];
  const float* edge_w1   = (const float*)d_in[10];
  const float* edge_b1   = (const float*)d_in[11];
  const float* edge_w2   = (const float*)d_in[12];
  const float* edge_b2   = (const float*)d_in[13];
  const float* node_w1   = (const float*)d_in[14];
  const float* node_b1   = (const float*)d_in[15];
  const float* node_w2   = (const float*)d_in[16];
  const float* node_b2   = (const float*)d_in[17];
  const float* coord_w1  = (const float*)d_in[18];
  const float* coord_b1  = (const float*)d_in[19];
  const float* coord_w3  = (const float*)d_in[20];

  float* out  = (float*)d_out;
  float* Hm   = out;                               // [16000 x 128]
  float* brep = out + (size_t)N_BLOCKS * HS;       // [16000 x 128]
  float* grep = out + (size_t)2 * N_BLOCKS * HS;   // [128 x 128]

  char* base = (char*)d_ws;
  size_t off = 0;
  auto take = [&](size_t bytes) -> char* {
    char* p = base + off;
    off += (bytes + 255) & ~(size_t)255;
    return p;
  };
  float*   x     = (float*)  take((size_t)N_BLOCKS * 4 * 4);   // stride-4 padded
  float*   xacc  = (float*)  take((size_t)N_BLOCKS * 3 * 4);
  float*   h     = (float*)  take((size_t)N_BLOCKS * HS * 4);
  float*   agg   = (float*)  take((size_t)N_BLOCKS * HS * 4);
  float*   gsum  = (float*)  take((size_t)N_GRAPHS * HS * 4);
  int*     bstart= (int*)    take((size_t)(N_BLOCKS + 1) * 4);
  int*     hist  = (int*)    take((size_t)N_BLOCKS * 4);
  int*     estart= (int*)    take((size_t)(N_BLOCKS + 1) * 4);
  int*     ecur  = (int*)    take((size_t)N_BLOCKS * 4);
  int2*    sedge = (int2*)   take((size_t)N_EDGES * 8);
  ushortT* sattr = (ushortT*)take((size_t)N_EDGES * 32 * 2);
  ushortT* Pbf   = (ushortT*)take((size_t)N_BLOCKS * HS * 2);
  ushortT* Qbf   = (ushortT*)take((size_t)N_BLOCKS * HS * 2);
  ushortT* W1atp = (ushortT*)take((size_t)3 * 128 * 128 * 2);
  ushortT* W1btp = (ushortT*)take((size_t)3 * 128 * 128 * 2);
  ushortT* W1ct  = (ushortT*)take((size_t)3 * 128 * 32 * 2);
  ushortT* W2tp  = (ushortT*)take((size_t)3 * 128 * 128 * 2);
  ushortT* CW1tp = (ushortT*)take((size_t)3 * 128 * 128 * 2);
  ushortT* NW1t  = (ushortT*)take((size_t)3 * 128 * 256 * 2);
  ushortT* NW2t  = (ushortT*)take((size_t)3 * 128 * 128 * 2);
  ushortT* Eint  = (ushortT*)take((size_t)128 * 128 * 2);
  ushortT* Eoutt = (ushortT*)take((size_t)128 * 128 * 2);
  float*   b1p   = (float*)  take((size_t)3 * 128 * 4);

  // merged prep (weights + bias perm + hist zero)
  PrepParams P;
  P.ew1 = edge_w1; P.ew2 = edge_w2; P.cw1 = coord_w1;
  P.nw1 = node_w1; P.nw2 = node_w2; P.ei = emb_in_w; P.eo = emb_out_w;
  P.eb1 = edge_b1;
  P.W1atp = W1atp; P.W1btp = W1btp; P.W1ct = W1ct; P.W2tp = W2tp; P.CW1tp = CW1tp;
  P.NW1t = NW1t; P.NW2t = NW2t; P.Eint = Eint; P.Eoutt = Eoutt;
  P.b1p = b1p; P.hist = hist;
  prep_kernel<<<(PREP_TOTAL + 255) / 256, 256, 0, stream>>>(P);

  hist_bstart_kernel<<<N_EDGES / 256 + (N_BLOCKS + 1 + 255) / 256, 256, 0, stream>>>(
      edges, hist, block_id, bstart);
  scan_kernel<<<1, 1024, 0, stream>>>(hist, estart, ecur);
  scatter_kernel<<<N_EDGES / 256, 256, 0, stream>>>(edges, edge_attr, ecur, sedge, sattr);
  pool_kernel<<<N_BLOCKS, 128, 0, stream>>>(H, Z, bstart, Hm, x, gsum);

  // h = Hm @ emb_in_w + b ; P/Q layer 0 ; zero agg/xacc
  gemm_pq_kernel<<<N_BLOCKS / 16, 64, 0, stream>>>(Hm, Eint, emb_in_b, h,
                                                   W1atp, W1btp, b1p, Pbf, Qbf, agg, xacc);

  for (int l = 0; l < 3; l++){
    if (l < 2){
      edge_kernel<1><<<N_EDGES / 128, 512, 0, stream>>>(
          sedge, sattr, x, Pbf, Qbf,
          W1ct + (size_t)l * 128 * 32, W2tp + (size_t)l * 128 * 128, CW1tp + (size_t)l * 128 * 128,
          edge_b2 + l * 128, coord_b1 + l * 128, coord_w3 + l * 128,
          xacc, agg);
      node_pq_kernel<<<N_BLOCKS / 16, 64, 0, stream>>>(
          h, agg, NW1t + (size_t)l * 128 * 256, NW2t + (size_t)l * 128 * 128,
          node_b1 + l * 128, node_b2 + l * 128,
          W1atp + (size_t)(l + 1) * 128 * 128, W1btp + (size_t)(l + 1) * 128 * 128,
          b1p + (l + 1) * 128, Pbf, Qbf, x, xacc, estart);
    } else {
      edge_kernel<0><<<N_EDGES / 128, 512, 0, stream>>>(
          sedge, sattr, x, Pbf, Qbf,
          W1ct + (size_t)l * 128 * 32, W2tp + (size_t)l * 128 * 128, CW1tp + (size_t)l * 128 * 128,
          edge_b2 + l * 128, coord_b1 + l * 128, coord_w3 + l * 128,
          xacc, agg);
      node_emb_kernel<<<N_BLOCKS / 16, 64, 0, stream>>>(
          h, agg, NW1t + (size_t)l * 128 * 256, NW2t + (size_t)l * 128 * 128,
          node_b1 + l * 128, node_b2 + l * 128,
          Eoutt, emb_out_b, batch_id, brep, gsum);
    }
  }

  norm_graph_kernel<<<N_GRAPHS / 4, 256, 0, stream>>>(gsum, grep);
}